// Round 8
// baseline (2617.341 us; speedup 1.0000x reference)
//
#include <hip/hip_runtime.h>
#include <hip/hip_fp16.h>

#define N_ 50000
#define E_ 800000
#define T_ 800000
#define G_ 64
#define H_ 128

typedef __attribute__((ext_vector_type(8))) short bf16x8;
typedef __attribute__((ext_vector_type(4))) float f32x4;
typedef _Float16 f16x2 __attribute__((ext_vector_type(2)));

__device__ __forceinline__ float siluf(float v) {
    return __fdividef(v, 1.0f + __expf(-v));
}

// bf16 helpers
__device__ __forceinline__ unsigned short f2bf(float f) {
    unsigned int u = __float_as_uint(f);
    u += 0x7fffu + ((u >> 16) & 1u);
    return (unsigned short)(u >> 16);
}
__device__ __forceinline__ unsigned int f2bf2(float a, float b) {
    return (unsigned int)f2bf(a) | ((unsigned int)f2bf(b) << 16);
}
__device__ __forceinline__ float bf2f(unsigned short h) {
    return __uint_as_float(((unsigned int)h) << 16);
}
__device__ __forceinline__ float2 bf2x2(unsigned int p) {
    return make_float2(__uint_as_float(p << 16), __uint_as_float(p & 0xffff0000u));
}
__device__ __forceinline__ float fdot2f(f16x2 a, f16x2 b, float c) {
    return __builtin_amdgcn_fdot2(a, b, c, false);
}

// ---------------- CSR build ----------------
__global__ __launch_bounds__(256) void k_count(const int* __restrict__ col, int* deg, int n) {
    int e = blockIdx.x * 256 + threadIdx.x;
    if (e < n) atomicAdd(&deg[col[e]], 1);
}

__global__ __launch_bounds__(256) void k_countT(const int* __restrict__ trip, int* deg, int n) {
    int t = blockIdx.x * 256 + threadIdx.x;
    if (t < n) atomicAdd(&deg[trip[3 * t + 1]], 1);
}

__global__ __launch_bounds__(1024) void k_scan(const int* __restrict__ deg, int* rowptr, int* cur, int n) {
    __shared__ int wsum[16];
    __shared__ int s_carry;
    int tid = threadIdx.x, lane = tid & 63, w = tid >> 6;
    if (tid == 0) s_carry = 0;
    __syncthreads();
    for (int base = 0; base < n; base += 1024) {
        int i = base + tid;
        int v = (i < n) ? deg[i] : 0;
        int incl = v;
        #pragma unroll
        for (int s = 1; s < 64; s <<= 1) {
            int t = __shfl_up(incl, (unsigned)s, 64);
            if (lane >= s) incl += t;
        }
        if (lane == 63) wsum[w] = incl;
        __syncthreads();
        int carry0 = s_carry;
        int wexcl = 0;
        for (int j = 0; j < w; ++j) wexcl += wsum[j];
        int excl = carry0 + wexcl + (incl - v);
        if (i < n) { rowptr[i] = excl; cur[i] = excl; }
        __syncthreads();
        if (tid == 1023) s_carry = carry0 + wexcl + incl;
        __syncthreads();
    }
    if (tid == 0) rowptr[n] = s_carry;
}

__global__ __launch_bounds__(256) void k_fill(const int* __restrict__ col, const int* __restrict__ row,
                                              int* cur, int* elist, int* slist, int n) {
    int e = blockIdx.x * 256 + threadIdx.x;
    if (e < n) {
        int pos = atomicAdd(&cur[col[e]], 1);
        elist[pos] = e;
        slist[pos] = row[e];
    }
}

__global__ __launch_bounds__(256) void k_fillT(const int* __restrict__ trip, int* cur,
                                               const float* __restrict__ dist_trip, const float* __restrict__ angle,
                                               float* __restrict__ dsort, float* __restrict__ asort, int n) {
    int t = blockIdx.x * 256 + threadIdx.x;
    if (t < n) {
        int pos = atomicAdd(&cur[trip[3 * t + 1]], 1);
        dsort[pos] = dist_trip[t];
        asort[pos] = angle[t];
    }
}

// ---------------- weight prep: fp32 (k,n) -> bf16 transposed (n,k), 27 matrices ----------------
__global__ __launch_bounds__(256) void k_wprep(const float* __restrict__ emb_w2, const float* __restrict__ iw_down,
                                               const float* __restrict__ iw_t1, const float* __restrict__ iw_t2,
                                               const float* __restrict__ iw_up, const float* __restrict__ ow0,
                                               const float* __restrict__ ow1, unsigned short* __restrict__ Wt) {
    int mat = blockIdx.x >> 3;
    int part = blockIdx.x & 7;
    const float* src;
    if (mat == 0) src = emb_w2;
    else if (mat < 5) src = iw_down + (size_t)(mat - 1) * 16384;
    else if (mat < 9) src = iw_t1 + (size_t)(mat - 5) * 16384;
    else if (mat < 13) src = iw_t2 + (size_t)(mat - 9) * 16384;
    else if (mat < 17) src = iw_up + (size_t)(mat - 13) * 16384;
    else if (mat < 22) src = ow0 + (size_t)(mat - 17) * 16384;
    else src = ow1 + (size_t)(mat - 22) * 16384;
    unsigned short* dst = Wt + (size_t)mat * 16384;
    int base = part * 2048;
    for (int i = base + threadIdx.x; i < base + 2048; i += 256) {
        int k = i >> 7, n = i & 127;
        dst[n * 128 + k] = f2bf(src[i]);
    }
}

// ---------------- rbf in CSR (segment) order ----------------
__global__ __launch_bounds__(256) void k_rbfS(const int* __restrict__ elist, const float* __restrict__ dist,
                                              const float* __restrict__ freq, float* __restrict__ rbfS, int n) {
    int p = blockIdx.x * 256 + threadIdx.x;
    if (p >= n) return;
    int e = elist[p];
    float d = dist[e] * 0.2f;
    float d2 = d * d, d4 = d2 * d2, d5 = d4 * d;
    float env = __fdividef(1.0f, d) - 28.0f * d5 + 48.0f * d5 * d - 21.0f * d5 * d2;
    #pragma unroll
    for (int r = 0; r < 6; ++r) rbfS[p * 6 + r] = env * __sinf(freq[r] * d);
}

// ---------------- per-block edge factors: s8h[p][k] = silu(rbfS[p] . W1[:,k]), fp16 ----------------
__global__ __launch_bounds__(256) void k_s8h(const float* __restrict__ rbfS, const float* __restrict__ W1,
                                             __half* __restrict__ s8, int n) {
    __shared__ float W1s[48];
    int tid = threadIdx.x;
    if (tid < 48) W1s[tid] = W1[tid];
    __syncthreads();
    int p = blockIdx.x * 256 + tid;
    if (p >= n) return;
    const float2* r2 = (const float2*)&rbfS[(size_t)p * 6];
    float2 ra = r2[0], rbx = r2[1], rc = r2[2];
    float rb[6] = {ra.x, ra.y, rbx.x, rbx.y, rc.x, rc.y};
    __half out[8];
    #pragma unroll
    for (int k = 0; k < 8; ++k) {
        float u = 0.f;
        #pragma unroll
        for (int r = 0; r < 6; ++r) u += rb[r] * W1s[r * 8 + k];
        out[k] = __float2half(siluf(u));
    }
    *(uint4*)&s8[(size_t)p * 8] = *(uint4*)out;
}

// ---------------- x = atom_table[z] ----------------
__global__ __launch_bounds__(256) void k_init_x(const float* __restrict__ atab, const int* __restrict__ z,
                                                float* __restrict__ x, int n) {
    int t = blockIdx.x * 256 + threadIdx.x;
    if (t >= n * 32) return;
    int node = t >> 5, q = t & 31;
    ((float4*)x)[t] = ((const float4*)atab)[z[node] * 32 + q];
}

// ---------------- SS[n] = sum_{e in n} silu(rbf_e @ w1 + b1) ----------------
__global__ __launch_bounds__(256) void k_embS(const int* __restrict__ rowptr, const float* __restrict__ rbfS,
                                              const float* __restrict__ w1, const float* __restrict__ b1,
                                              float* __restrict__ SS, int n) {
    int node = blockIdx.x * 4 + (threadIdx.x >> 6);
    int lane = threadIdx.x & 63;
    if (node >= n) return;
    int c = lane * 2;
    float wc0[6], wc1[6];
    #pragma unroll
    for (int r = 0; r < 6; ++r) { wc0[r] = w1[r * 128 + c]; wc1[r] = w1[r * 128 + c + 1]; }
    float bb0 = b1[c], bb1 = b1[c + 1];
    float a0 = 0.f, a1 = 0.f;
    int p0 = rowptr[node], p1 = rowptr[node + 1];
    for (int p = p0; p < p1; ++p) {
        const float2* r2 = (const float2*)&rbfS[(size_t)p * 6];
        float2 ra = r2[0], rbx = r2[1], rc = r2[2];
        float u0 = bb0 + ra.x * wc0[0] + ra.y * wc0[1] + rbx.x * wc0[2] + rbx.y * wc0[3] + rc.x * wc0[4] + rc.y * wc0[5];
        float u1 = bb1 + ra.x * wc1[0] + ra.y * wc1[1] + rbx.x * wc1[2] + rbx.y * wc1[3] + rc.x * wc1[4] + rc.y * wc1[5];
        a0 += siluf(u0);
        a1 += siluf(u1);
    }
    SS[node * 128 + c] = a0;
    SS[node * 128 + c + 1] = a1;
}

// ---------------- MFMA GEMM (R6-proven) ----------------
template <int BIAS_MODE, bool SILU, bool ACC, bool WBF>
__global__ __launch_bounds__(256, 4) void k_gemm_mfma(const float* __restrict__ A,
                                                      const unsigned short* __restrict__ Wt,
                                                      const float* __restrict__ bias, const int* __restrict__ deg,
                                                      float* __restrict__ C, unsigned short* __restrict__ Ch, int M) {
    int tid = threadIdx.x;
    int wave = tid >> 6, lane = tid & 63;
    int m15 = lane & 15, quad = lane >> 4;
    int row0 = blockIdx.x * 64 + wave * 16;
    int arow = row0 + m15;
    if (arow > M - 1) arow = M - 1;
    const float* Arow = A + (size_t)arow * 128;

    f32x4 acc[8];
    #pragma unroll
    for (int nt = 0; nt < 8; ++nt) acc[nt] = (f32x4){0.f, 0.f, 0.f, 0.f};

    #pragma unroll
    for (int kt = 0; kt < 4; ++kt) {
        int ks = kt * 32 + quad * 8;
        float4 a0 = *(const float4*)(Arow + ks);
        float4 a1 = *(const float4*)(Arow + ks + 4);
        union { bf16x8 v; unsigned int u[4]; } af;
        af.u[0] = f2bf2(a0.x, a0.y);
        af.u[1] = f2bf2(a0.z, a0.w);
        af.u[2] = f2bf2(a1.x, a1.y);
        af.u[3] = f2bf2(a1.z, a1.w);
        #pragma unroll
        for (int nt = 0; nt < 8; ++nt) {
            bf16x8 bf = *(const bf16x8*)(Wt + (size_t)(nt * 16 + m15) * 128 + ks);
            acc[nt] = __builtin_amdgcn_mfma_f32_16x16x32_bf16(af.v, bf, acc[nt], 0, 0, 0);
        }
    }

    #pragma unroll
    for (int nt = 0; nt < 8; ++nt) {
        int col = nt * 16 + m15;
        float bc = 0.f;
        if constexpr (BIAS_MODE != 0) bc = bias[col];
        #pragma unroll
        for (int reg = 0; reg < 4; ++reg) {
            int row = row0 + quad * 4 + reg;
            if (row < M) {
                float v = acc[nt][reg];
                if constexpr (BIAS_MODE == 1) v += bc;
                if constexpr (BIAS_MODE == 2) v += bc * (float)deg[row];
                if constexpr (SILU) v = siluf(v);
                float* cp = &C[(size_t)row * 128 + col];
                if constexpr (ACC) v += *cp;
                *cp = v;
                if constexpr (WBF) Ch[(size_t)row * 128 + col] = f2bf(v);
            }
        }
    }
}

// ---------------- out_block gather: 2 waves/node, 1 channel/lane ----------------
__global__ __launch_bounds__(256) void k_out_gather(const int* __restrict__ rowptr, const int* __restrict__ slist,
                                                    const float* __restrict__ rbfS,
                                                    const unsigned short* __restrict__ xh,
                                                    const float* __restrict__ wrbf, float* __restrict__ h, int n) {
    int node = blockIdx.x * 2 + (threadIdx.x >> 7);
    int c = threadIdx.x & 127;
    if (node >= n) return;
    float wc[6];
    #pragma unroll
    for (int r = 0; r < 6; ++r) wc[r] = wrbf[r * 128 + c];
    float a = 0.f;
    int p0 = rowptr[node], p1 = rowptr[node + 1];
    int p = p0;
    for (; p + 4 <= p1; p += 4) {
        int ss[4];
        #pragma unroll
        for (int u = 0; u < 4; ++u) ss[u] = slist[p + u];
        unsigned short xs[4];
        #pragma unroll
        for (int u = 0; u < 4; ++u) xs[u] = xh[(size_t)ss[u] * 128 + c];
        #pragma unroll
        for (int u = 0; u < 4; ++u) {
            const float2* r2 = (const float2*)&rbfS[(size_t)(p + u) * 6];
            float2 ra = r2[0], rbx = r2[1], rc = r2[2];
            float e = ra.x * wc[0] + ra.y * wc[1] + rbx.x * wc[2] + rbx.y * wc[3] + rc.x * wc[4] + rc.y * wc[5];
            a += bf2f(xs[u]) * e;
        }
    }
    for (; p < p1; ++p) {
        int src = slist[p];
        const float2* r2 = (const float2*)&rbfS[(size_t)p * 6];
        float2 ra = r2[0], rbx = r2[1], rc = r2[2];
        float e = ra.x * wc[0] + ra.y * wc[1] + rbx.x * wc[2] + rbx.y * wc[3] + rc.x * wc[4] + rc.y * wc[5];
        a += bf2f(xh[(size_t)src * 128 + c]) * e;
    }
    h[(size_t)node * 128 + c] = a;
}

// ---------------- P accumulate ----------------
template <bool ACC>
__global__ __launch_bounds__(256) void k_p_acc(const float* __restrict__ h, const float* __restrict__ w2col,
                                               const float* __restrict__ ob2p, float* __restrict__ P, int n) {
    int node = blockIdx.x * 4 + (threadIdx.x >> 6);
    int lane = threadIdx.x & 63;
    if (node >= n) return;
    int c = lane * 2;
    float2 hv = *(const float2*)&h[(size_t)node * 128 + c];
    float s = hv.x * w2col[c] + hv.y * w2col[c + 1];
    #pragma unroll
    for (int off = 32; off > 0; off >>= 1) s += __shfl_xor(s, off, 64);
    if (lane == 0) {
        float r = s + ob2p[0];
        if (ACC) r += P[node];
        P[node] = r;
    }
}

// ---------------- triplet SV via sorted CSR gather ----------------
__global__ __launch_bounds__(256) void k_trip_sv(const int* __restrict__ rowptrT, const float* __restrict__ dsort,
                                                 const float* __restrict__ asort, const float* __restrict__ sfreq,
                                                 const float* __restrict__ W1, float* __restrict__ SV, int n) {
    int grp = (blockIdx.x * 256 + threadIdx.x) >> 3;
    int k = threadIdx.x & 7;
    if (grp >= n) return;
    float w[24];
    #pragma unroll
    for (int i = 0; i < 24; ++i) w[i] = W1[i * 8 + k];
    float f0 = sfreq[0], f1 = sfreq[1], f2 = sfreq[2], f3 = sfreq[3], f4 = sfreq[4], f5 = sfreq[5];
    float acc = 0.f;
    int p0 = rowptrT[grp], p1 = rowptrT[grp + 1];
    for (int p = p0; p < p1; ++p) {
        float d = dsort[p] * 0.2f;
        float a = asort[p];
        float d2 = d * d, d4 = d2 * d2, d5 = d4 * d;
        float env = __fdividef(1.0f, d) - 28.0f * d5 + 48.0f * d5 * d - 21.0f * d5 * d2;
        float rb0 = env * __sinf(f0 * d), rb1 = env * __sinf(f1 * d), rb2 = env * __sinf(f2 * d);
        float rb3 = env * __sinf(f3 * d), rb4 = env * __sinf(f4 * d), rb5 = env * __sinf(f5 * d);
        float s1 = a, s2 = 1.5f * a * a - 0.5f, s3 = 2.5f * a * a * a - 1.5f * a;
        float u = rb0 * w[0] + rb1 * w[1] + rb2 * w[2] + rb3 * w[3] + rb4 * w[4] + rb5 * w[5];
        u += s1 * (rb0 * w[6] + rb1 * w[7] + rb2 * w[8] + rb3 * w[9] + rb4 * w[10] + rb5 * w[11]);
        u += s2 * (rb0 * w[12] + rb1 * w[13] + rb2 * w[14] + rb3 * w[15] + rb4 * w[16] + rb5 * w[17]);
        u += s3 * (rb0 * w[18] + rb1 * w[19] + rb2 * w[20] + rb3 * w[21] + rb4 * w[22] + rb5 * w[23]);
        acc += siluf(u);
    }
    SV[grp * 8 + k] = acc;
}

// ---------------- e2 = SV @ iw_sbf2 ----------------
__global__ __launch_bounds__(256) void k_sv_gemm(const float* __restrict__ SV, const float* __restrict__ W2,
                                                 float* __restrict__ e2, int n) {
    __shared__ float W2s[8 * 128];
    int tid = threadIdx.x;
    for (int i = tid; i < 1024; i += 256) W2s[i] = W2[i];
    __syncthreads();
    int t = blockIdx.x * 256 + tid;
    if (t >= n * 32) return;
    int node = t >> 5, q = t & 31;
    const float* sv = &SV[node * 8];
    int c = q * 4;
    float out[4] = {0.f, 0.f, 0.f, 0.f};
    #pragma unroll
    for (int k = 0; k < 8; ++k) {
        float s = sv[k];
        #pragma unroll
        for (int i = 0; i < 4; ++i) out[i] += s * W2s[k * 128 + c + i];
    }
    *(float4*)&e2[(size_t)node * 128 + c] = make_float4(out[0], out[1], out[2], out[3]);
}

// ---------------- extra[c] = sum_n t_mat[n][c] * e2[n][c] ----------------
__global__ __launch_bounds__(256) void k_extra_reduce(const float* __restrict__ Tm, const float* __restrict__ E2,
                                                      float* __restrict__ extra, int n) {
    const float4* t4 = (const float4*)Tm;
    const float4* e4 = (const float4*)E2;
    int tid = threadIdx.x;
    int q = tid & 31, rl = tid >> 5;
    float ax = 0.f, ay = 0.f, az = 0.f, aw = 0.f;
    for (int nn = blockIdx.x * 8 + rl; nn < n; nn += 1024) {
        float4 a = t4[(size_t)nn * 32 + q];
        float4 b = e4[(size_t)nn * 32 + q];
        ax += a.x * b.x; ay += a.y * b.y; az += a.z * b.z; aw += a.w * b.w;
    }
    __shared__ float4 red[256];
    red[tid] = make_float4(ax, ay, az, aw);
    __syncthreads();
    if (tid < 128) {
        float4 o = red[tid + 128];
        red[tid].x += o.x; red[tid].y += o.y; red[tid].z += o.z; red[tid].w += o.w;
    }
    __syncthreads();
    if (tid < 64) {
        float4 o = red[tid + 64];
        red[tid].x += o.x; red[tid].y += o.y; red[tid].z += o.z; red[tid].w += o.w;
    }
    __syncthreads();
    if (tid < 32) {
        float4 r = red[tid];
        float4 o = red[tid + 32];
        r.x += o.x; r.y += o.y; r.z += o.z; r.w += o.w;
        atomicAdd(&extra[tid * 4 + 0], r.x);
        atomicAdd(&extra[tid * 4 + 1], r.y);
        atomicAdd(&extra[tid * 4 + 2], r.z);
        atomicAdd(&extra[tid * 4 + 3], r.w);
    }
}

// ---------------- interaction: 2 waves/node, 1 channel/lane, fdot2 MLP ----------------
__global__ __launch_bounds__(256) void k_interact(const int* __restrict__ rowptr, const int* __restrict__ slist,
                                                  const __half* __restrict__ s8, const float* __restrict__ W2,
                                                  const float* __restrict__ extra,
                                                  const unsigned short* __restrict__ xuph,
                                                  float* __restrict__ x, unsigned short* __restrict__ xh, int n) {
    int node = blockIdx.x * 2 + (threadIdx.x >> 7);
    int c = threadIdx.x & 127;
    if (node >= n) return;
    f16x2 w2h[4];
    #pragma unroll
    for (int j = 0; j < 4; ++j) {
        f16x2 w;
        w.x = (_Float16)W2[(2 * j) * 128 + c];
        w.y = (_Float16)W2[(2 * j + 1) * 128 + c];
        w2h[j] = w;
    }
    int p0 = rowptr[node], p1 = rowptr[node + 1];
    float cntf = (float)(p1 - p0);
    float a = cntf * extra[c];
    int p = p0;
    for (; p + 4 <= p1; p += 4) {
        int ss[4];
        #pragma unroll
        for (int u = 0; u < 4; ++u) ss[u] = slist[p + u];
        unsigned short xs[4];
        #pragma unroll
        for (int u = 0; u < 4; ++u) xs[u] = xuph[(size_t)ss[u] * 128 + c];
        #pragma unroll
        for (int u = 0; u < 4; ++u) {
            union { uint4 q; f16x2 h[4]; } sv;
            sv.q = *(const uint4*)(s8 + (size_t)(p + u) * 8);
            float e = fdot2f(sv.h[0], w2h[0], 0.f);
            e = fdot2f(sv.h[1], w2h[1], e);
            e = fdot2f(sv.h[2], w2h[2], e);
            e = fdot2f(sv.h[3], w2h[3], e);
            a += bf2f(xs[u]) * e;
        }
    }
    for (; p < p1; ++p) {
        int src = slist[p];
        union { uint4 q; f16x2 h[4]; } sv;
        sv.q = *(const uint4*)(s8 + (size_t)p * 8);
        float e = fdot2f(sv.h[0], w2h[0], 0.f);
        e = fdot2f(sv.h[1], w2h[1], e);
        e = fdot2f(sv.h[2], w2h[2], e);
        e = fdot2f(sv.h[3], w2h[3], e);
        a += bf2f(xuph[(size_t)src * 128 + c]) * e;
    }
    float nx = x[(size_t)node * 128 + c] + a;
    x[(size_t)node * 128 + c] = nx;
    xh[(size_t)node * 128 + c] = f2bf(nx);
}

// ---------------- pooling ----------------
__global__ __launch_bounds__(256) void k_pool(const float* __restrict__ P, const int* __restrict__ batch,
                                              float* __restrict__ pool, float* __restrict__ cnt, int n) {
    int i = blockIdx.x * 256 + threadIdx.x;
    int lane = threadIdx.x & 63;
    int b = (i < n) ? batch[i] : -1;
    float p = (i < n) ? P[i] : 0.f;
    int b0 = __shfl(b, 0, 64);
    int b63 = __shfl(b, 63, 64);
    if (b0 == b63 && b0 >= 0) {
        float s = p;
        #pragma unroll
        for (int off = 32; off > 0; off >>= 1) s += __shfl_xor(s, off, 64);
        if (lane == 0) {
            atomicAdd(&pool[b0], s);
            atomicAdd(&cnt[b0], 64.0f);
        }
    } else {
        if (i < n) {
            atomicAdd(&pool[b], p);
            atomicAdd(&cnt[b], 1.0f);
        }
    }
}

__global__ __launch_bounds__(64) void k_final(const float* __restrict__ pool, const float* __restrict__ cnt,
                                              float* __restrict__ out) {
    int g = threadIdx.x;
    if (g < G_) out[g] = __fdividef(pool[g], fmaxf(cnt[g], 1.0f));
}

extern "C" void kernel_launch(void* const* d_in, const int* in_sizes, int n_in,
                              void* d_out, int out_size, void* d_ws, size_t ws_size,
                              hipStream_t stream) {
    (void)in_sizes; (void)n_in; (void)out_size; (void)ws_size;
    const int* z = (const int*)d_in[0];
    const float* dist = (const float*)d_in[1];
    const float* dist_trip = (const float*)d_in[2];
    const float* angle = (const float*)d_in[3];
    const int* edge_index = (const int*)d_in[4];
    const int* triplets = (const int*)d_in[5];
    const int* batch = (const int*)d_in[6];
    const float* atom_table = (const float*)d_in[7];
    const float* rbf_freq = (const float*)d_in[8];
    const float* sbf_freq = (const float*)d_in[9];
    const float* emb_w1 = (const float*)d_in[10];
    const float* emb_b1 = (const float*)d_in[11];
    const float* emb_w2 = (const float*)d_in[12];
    const float* emb_b2 = (const float*)d_in[13];
    const float* iw_rbf1 = (const float*)d_in[14];
    const float* iw_rbf2 = (const float*)d_in[15];
    const float* iw_sbf1 = (const float*)d_in[16];
    const float* iw_sbf2 = (const float*)d_in[17];
    const float* iw_t1 = (const float*)d_in[18];
    const float* iw_t2 = (const float*)d_in[19];
    const float* ib_t2 = (const float*)d_in[20];
    const float* iw_up = (const float*)d_in[21];
    const float* ib_up = (const float*)d_in[22];
    const float* iw_down = (const float*)d_in[23];
    const float* ib_down = (const float*)d_in[24];
    const float* ow_rbf = (const float*)d_in[25];
    const float* ow0 = (const float*)d_in[26];
    const float* ob0 = (const float*)d_in[27];
    const float* ow1 = (const float*)d_in[28];
    const float* ob1 = (const float*)d_in[29];
    const float* ow2 = (const float*)d_in[30];
    const float* ob2 = (const float*)d_in[31];

    const int* erow = edge_index;
    const int* ecol = edge_index + E_;

    // workspace layout
    float* ws = (float*)d_ws;
    float* x = ws;                             // N*128
    float* bufA = x + (size_t)N_ * H_;         // N*128
    float* bufB = bufA + (size_t)N_ * H_;      // N*128
    float* P = bufB + (size_t)N_ * H_;         // N
    float* rbfS = P + N_;                      // E*6 (CSR order)
    float* SV = rbfS + (size_t)E_ * 6;         // N*8
    float* extra = SV + (size_t)N_ * 8;        // 128
    float* pool = extra + 128;                 // G
    float* cnt = pool + G_;                    // G
    int* deg = (int*)(cnt + G_);               // N
    int* rowptr = deg + N_;                    // N+1
    int* cur = rowptr + N_ + 1;                // N
    int* elist = cur + N_;                     // E
    int* slist = elist + E_;                   // E
    int* rowptrT = slist + E_;                 // N+1
    int* degT = rowptrT + N_ + 1;              // N
    float* dsort = (float*)(degT + N_);        // T
    float* asort = dsort + T_;                 // T
    __half* s8h = (__half*)(asort + T_);       // E*8 halves
    unsigned short* xh = (unsigned short*)(s8h + (size_t)E_ * 8);   // N*128 bf16 shadow of x
    unsigned short* xuph = xh + (size_t)N_ * H_;                    // N*128 bf16 shadow of x_up
    unsigned short* Wt = xuph + (size_t)N_ * H_;                    // 27*16384 bf16 transposed weights

    const int EG = (E_ + 255) / 256;
    const int TG = (T_ + 255) / 256;
    const int NG4 = (N_ + 3) / 4;
    const int NG2 = (N_ + 1) / 2;
    const int GEMMG = (N_ + 63) / 64;

    hipMemsetAsync(deg, 0, N_ * sizeof(int), stream);
    hipMemsetAsync(degT, 0, N_ * sizeof(int), stream);
    k_wprep<<<27 * 8, 256, 0, stream>>>(emb_w2, iw_down, iw_t1, iw_t2, iw_up, ow0, ow1, Wt);
    k_count<<<EG, 256, 0, stream>>>(ecol, deg, E_);
    k_countT<<<TG, 256, 0, stream>>>(triplets, degT, T_);
    k_scan<<<1, 1024, 0, stream>>>(deg, rowptr, cur, N_);
    k_fill<<<EG, 256, 0, stream>>>(ecol, erow, cur, elist, slist, E_);
    k_scan<<<1, 1024, 0, stream>>>(degT, rowptrT, cur, N_);
    k_fillT<<<TG, 256, 0, stream>>>(triplets, cur, dist_trip, angle, dsort, asort, T_);

    k_rbfS<<<EG, 256, 0, stream>>>(elist, dist, rbf_freq, rbfS, E_);
    k_init_x<<<(N_ * 32) / 256, 256, 0, stream>>>(atom_table, z, x, N_);

    k_embS<<<NG4, 256, 0, stream>>>(rowptr, rbfS, emb_w1, emb_b1, bufA, N_);
    k_gemm_mfma<2, false, true, true><<<GEMMG, 256, 0, stream>>>(bufA, Wt, emb_b2, deg, x, xh, N_);

    auto out_block = [&](int k, bool first) {
        k_out_gather<<<NG2, 256, 0, stream>>>(rowptr, slist, rbfS, xh,
                                              ow_rbf + (size_t)k * 6 * 128, bufA, N_);
        k_gemm_mfma<1, true, false, false><<<GEMMG, 256, 0, stream>>>(bufA, Wt + (size_t)(17 + k) * 16384,
                                                                      ob0 + k * 128, nullptr, bufB, nullptr, N_);
        k_gemm_mfma<1, true, false, false><<<GEMMG, 256, 0, stream>>>(bufB, Wt + (size_t)(22 + k) * 16384,
                                                                      ob1 + k * 128, nullptr, bufA, nullptr, N_);
        if (first)
            k_p_acc<false><<<NG4, 256, 0, stream>>>(bufA, ow2 + k * 128, ob2 + k, P, N_);
        else
            k_p_acc<true><<<NG4, 256, 0, stream>>>(bufA, ow2 + k * 128, ob2 + k, P, N_);
    };

    out_block(0, true);

    for (int b = 0; b < 4; ++b) {
        k_gemm_mfma<1, false, false, false><<<GEMMG, 256, 0, stream>>>(x, Wt + (size_t)(1 + b) * 16384,
                                                                       ib_down + b * 128, nullptr, bufA, nullptr, N_);
        k_gemm_mfma<0, true, false, false><<<GEMMG, 256, 0, stream>>>(bufA, Wt + (size_t)(5 + b) * 16384,
                                                                      nullptr, nullptr, bufB, nullptr, N_);
        k_gemm_mfma<1, false, false, false><<<GEMMG, 256, 0, stream>>>(bufB, Wt + (size_t)(9 + b) * 16384,
                                                                       ib_t2 + b * 128, nullptr, bufA, nullptr, N_);
        k_trip_sv<<<(N_ * 8 + 255) / 256, 256, 0, stream>>>(rowptrT, dsort, asort, sbf_freq,
                                                            iw_sbf1 + (size_t)b * 192, SV, N_);
        k_sv_gemm<<<(N_ * 32) / 256, 256, 0, stream>>>(SV, iw_sbf2 + (size_t)b * 1024, bufB, N_);
        hipMemsetAsync(extra, 0, 128 * sizeof(float), stream);
        k_extra_reduce<<<128, 256, 0, stream>>>(bufA, bufB, extra, N_);
        k_s8h<<<EG, 256, 0, stream>>>(rbfS, iw_rbf1 + (size_t)b * 48, s8h, E_);
        k_gemm_mfma<1, false, false, true><<<GEMMG, 256, 0, stream>>>(x, Wt + (size_t)(13 + b) * 16384,
                                                                      ib_up + b * 128, nullptr, bufB, xuph, N_);
        k_interact<<<NG2, 256, 0, stream>>>(rowptr, slist, s8h, iw_rbf2 + (size_t)b * 1024, extra,
                                            xuph, x, xh, N_);
        out_block(b + 1, false);
    }

    hipMemsetAsync(pool, 0, 2 * G_ * sizeof(float), stream);
    k_pool<<<(N_ + 255) / 256, 256, 0, stream>>>(P, batch, pool, cnt, N_);
    k_final<<<1, 64, 0, stream>>>(pool, cnt, (float*)d_out);
}

// Round 9
// 2203.901 us; speedup vs baseline: 1.1876x; 1.1876x over previous
//
#include <hip/hip_runtime.h>
#include <hip/hip_fp16.h>

#define N_ 50000
#define E_ 800000
#define T_ 800000
#define G_ 64
#define H_ 128

typedef __attribute__((ext_vector_type(8))) short bf16x8;
typedef __attribute__((ext_vector_type(4))) float f32x4;
typedef _Float16 f16x2 __attribute__((ext_vector_type(2)));

__device__ __forceinline__ float siluf(float v) {
    return __fdividef(v, 1.0f + __expf(-v));
}

// bf16 helpers
__device__ __forceinline__ unsigned short f2bf(float f) {
    unsigned int u = __float_as_uint(f);
    u += 0x7fffu + ((u >> 16) & 1u);
    return (unsigned short)(u >> 16);
}
__device__ __forceinline__ unsigned int f2bf2(float a, float b) {
    return (unsigned int)f2bf(a) | ((unsigned int)f2bf(b) << 16);
}
__device__ __forceinline__ float bf2f(unsigned short h) {
    return __uint_as_float(((unsigned int)h) << 16);
}
__device__ __forceinline__ float2 bf2x2(unsigned int p) {
    return make_float2(__uint_as_float(p << 16), __uint_as_float(p & 0xffff0000u));
}
__device__ __forceinline__ float fdot2f(f16x2 a, f16x2 b, float c) {
    return __builtin_amdgcn_fdot2(a, b, c, false);
}

// ---------------- CSR build ----------------
__global__ __launch_bounds__(256) void k_count(const int* __restrict__ col, int* deg, int n) {
    int e = blockIdx.x * 256 + threadIdx.x;
    if (e < n) atomicAdd(&deg[col[e]], 1);
}

__global__ __launch_bounds__(256) void k_countT(const int* __restrict__ trip, int* deg, int n) {
    int t = blockIdx.x * 256 + threadIdx.x;
    if (t < n) atomicAdd(&deg[trip[3 * t + 1]], 1);
}

__global__ __launch_bounds__(1024) void k_scan(const int* __restrict__ deg, int* rowptr, int* cur, int n) {
    __shared__ int wsum[16];
    __shared__ int s_carry;
    int tid = threadIdx.x, lane = tid & 63, w = tid >> 6;
    if (tid == 0) s_carry = 0;
    __syncthreads();
    for (int base = 0; base < n; base += 1024) {
        int i = base + tid;
        int v = (i < n) ? deg[i] : 0;
        int incl = v;
        #pragma unroll
        for (int s = 1; s < 64; s <<= 1) {
            int t = __shfl_up(incl, (unsigned)s, 64);
            if (lane >= s) incl += t;
        }
        if (lane == 63) wsum[w] = incl;
        __syncthreads();
        int carry0 = s_carry;
        int wexcl = 0;
        for (int j = 0; j < w; ++j) wexcl += wsum[j];
        int excl = carry0 + wexcl + (incl - v);
        if (i < n) { rowptr[i] = excl; cur[i] = excl; }
        __syncthreads();
        if (tid == 1023) s_carry = carry0 + wexcl + incl;
        __syncthreads();
    }
    if (tid == 0) rowptr[n] = s_carry;
}

__global__ __launch_bounds__(256) void k_fill(const int* __restrict__ col, const int* __restrict__ row,
                                              int* cur, int* elist, int* slist, int n) {
    int e = blockIdx.x * 256 + threadIdx.x;
    if (e < n) {
        int pos = atomicAdd(&cur[col[e]], 1);
        elist[pos] = e;
        slist[pos] = row[e];
    }
}

__global__ __launch_bounds__(256) void k_fillT(const int* __restrict__ trip, int* cur,
                                               const float* __restrict__ dist_trip, const float* __restrict__ angle,
                                               float* __restrict__ dsort, float* __restrict__ asort, int n) {
    int t = blockIdx.x * 256 + threadIdx.x;
    if (t < n) {
        int pos = atomicAdd(&cur[trip[3 * t + 1]], 1);
        dsort[pos] = dist_trip[t];
        asort[pos] = angle[t];
    }
}

// ---------------- weight prep: fp32 (k,n) -> bf16 transposed (n,k), 27 matrices ----------------
__global__ __launch_bounds__(256) void k_wprep(const float* __restrict__ emb_w2, const float* __restrict__ iw_down,
                                               const float* __restrict__ iw_t1, const float* __restrict__ iw_t2,
                                               const float* __restrict__ iw_up, const float* __restrict__ ow0,
                                               const float* __restrict__ ow1, unsigned short* __restrict__ Wt) {
    int mat = blockIdx.x >> 3;
    int part = blockIdx.x & 7;
    const float* src;
    if (mat == 0) src = emb_w2;
    else if (mat < 5) src = iw_down + (size_t)(mat - 1) * 16384;
    else if (mat < 9) src = iw_t1 + (size_t)(mat - 5) * 16384;
    else if (mat < 13) src = iw_t2 + (size_t)(mat - 9) * 16384;
    else if (mat < 17) src = iw_up + (size_t)(mat - 13) * 16384;
    else if (mat < 22) src = ow0 + (size_t)(mat - 17) * 16384;
    else src = ow1 + (size_t)(mat - 22) * 16384;
    unsigned short* dst = Wt + (size_t)mat * 16384;
    int base = part * 2048;
    for (int i = base + threadIdx.x; i < base + 2048; i += 256) {
        int k = i >> 7, n = i & 127;
        dst[n * 128 + k] = f2bf(src[i]);
    }
}

// ---------------- rbf in CSR (segment) order ----------------
__global__ __launch_bounds__(256) void k_rbfS(const int* __restrict__ elist, const float* __restrict__ dist,
                                              const float* __restrict__ freq, float* __restrict__ rbfS, int n) {
    int p = blockIdx.x * 256 + threadIdx.x;
    if (p >= n) return;
    int e = elist[p];
    float d = dist[e] * 0.2f;
    float d2 = d * d, d4 = d2 * d2, d5 = d4 * d;
    float env = __fdividef(1.0f, d) - 28.0f * d5 + 48.0f * d5 * d - 21.0f * d5 * d2;
    #pragma unroll
    for (int r = 0; r < 6; ++r) rbfS[p * 6 + r] = env * __sinf(freq[r] * d);
}

// ---------------- per-block edge factors: s8h[p][k] = silu(rbfS[p] . W1[:,k]), fp16 ----------------
__global__ __launch_bounds__(256) void k_s8h(const float* __restrict__ rbfS, const float* __restrict__ W1,
                                             __half* __restrict__ s8, int n) {
    __shared__ float W1s[48];
    int tid = threadIdx.x;
    if (tid < 48) W1s[tid] = W1[tid];
    __syncthreads();
    int p = blockIdx.x * 256 + tid;
    if (p >= n) return;
    const float2* r2 = (const float2*)&rbfS[(size_t)p * 6];
    float2 ra = r2[0], rbx = r2[1], rc = r2[2];
    float rb[6] = {ra.x, ra.y, rbx.x, rbx.y, rc.x, rc.y};
    __half out[8];
    #pragma unroll
    for (int k = 0; k < 8; ++k) {
        float u = 0.f;
        #pragma unroll
        for (int r = 0; r < 6; ++r) u += rb[r] * W1s[r * 8 + k];
        out[k] = __float2half(siluf(u));
    }
    *(uint4*)&s8[(size_t)p * 8] = *(uint4*)out;
}

// ---------------- xh = bf16(atom_table[z]) ----------------
__global__ __launch_bounds__(256) void k_init_x(const float* __restrict__ atab, const int* __restrict__ z,
                                                unsigned short* __restrict__ xh, int n) {
    int t = blockIdx.x * 256 + threadIdx.x;
    if (t >= n * 16) return;
    int node = t >> 4, q = t & 15;
    const float4* a4 = (const float4*)atab;
    float4 v0 = a4[(size_t)z[node] * 32 + q * 2];
    float4 v1 = a4[(size_t)z[node] * 32 + q * 2 + 1];
    uint4 pk;
    pk.x = f2bf2(v0.x, v0.y);
    pk.y = f2bf2(v0.z, v0.w);
    pk.z = f2bf2(v1.x, v1.y);
    pk.w = f2bf2(v1.z, v1.w);
    ((uint4*)xh)[t] = pk;
}

// ---------------- SS[n] = sum_{e in n} silu(rbf_e @ w1 + b1) ----------------
__global__ __launch_bounds__(256) void k_embS(const int* __restrict__ rowptr, const float* __restrict__ rbfS,
                                              const float* __restrict__ w1, const float* __restrict__ b1,
                                              float* __restrict__ SS, int n) {
    int node = blockIdx.x * 4 + (threadIdx.x >> 6);
    int lane = threadIdx.x & 63;
    if (node >= n) return;
    int c = lane * 2;
    float wc0[6], wc1[6];
    #pragma unroll
    for (int r = 0; r < 6; ++r) { wc0[r] = w1[r * 128 + c]; wc1[r] = w1[r * 128 + c + 1]; }
    float bb0 = b1[c], bb1 = b1[c + 1];
    float a0 = 0.f, a1 = 0.f;
    int p0 = rowptr[node], p1 = rowptr[node + 1];
    for (int p = p0; p < p1; ++p) {
        const float2* r2 = (const float2*)&rbfS[(size_t)p * 6];
        float2 ra = r2[0], rbx = r2[1], rc = r2[2];
        float u0 = bb0 + ra.x * wc0[0] + ra.y * wc0[1] + rbx.x * wc0[2] + rbx.y * wc0[3] + rc.x * wc0[4] + rc.y * wc0[5];
        float u1 = bb1 + ra.x * wc1[0] + ra.y * wc1[1] + rbx.x * wc1[2] + rbx.y * wc1[3] + rc.x * wc1[4] + rc.y * wc1[5];
        a0 += siluf(u0);
        a1 += siluf(u1);
    }
    SS[node * 128 + c] = a0;
    SS[node * 128 + c + 1] = a1;
}

// ---------------- MFMA GEMM: flexible IO ----------------
// ABF: A is bf16 (ushort row-major) else fp32. ACCBF: += bf16 Ch before write.
// WF32: write fp32 C. WBF: write bf16 Ch.
template <int BIAS_MODE, bool SILU, bool ACCBF, bool ABF, bool WF32, bool WBF>
__global__ __launch_bounds__(256, 4) void k_gemm_mfma(const void* __restrict__ Ap,
                                                      const unsigned short* __restrict__ Wt,
                                                      const float* __restrict__ bias, const int* __restrict__ deg,
                                                      float* __restrict__ C, unsigned short* __restrict__ Ch, int M) {
    int tid = threadIdx.x;
    int wave = tid >> 6, lane = tid & 63;
    int m15 = lane & 15, quad = lane >> 4;
    int row0 = blockIdx.x * 64 + wave * 16;
    int arow = row0 + m15;
    if (arow > M - 1) arow = M - 1;

    f32x4 acc[8];
    #pragma unroll
    for (int nt = 0; nt < 8; ++nt) acc[nt] = (f32x4){0.f, 0.f, 0.f, 0.f};

    #pragma unroll
    for (int kt = 0; kt < 4; ++kt) {
        int ks = kt * 32 + quad * 8;
        bf16x8 av;
        if constexpr (ABF) {
            av = *(const bf16x8*)((const unsigned short*)Ap + (size_t)arow * 128 + ks);
        } else {
            const float* Arow = (const float*)Ap + (size_t)arow * 128;
            float4 a0 = *(const float4*)(Arow + ks);
            float4 a1 = *(const float4*)(Arow + ks + 4);
            union { bf16x8 v; unsigned int u[4]; } af;
            af.u[0] = f2bf2(a0.x, a0.y);
            af.u[1] = f2bf2(a0.z, a0.w);
            af.u[2] = f2bf2(a1.x, a1.y);
            af.u[3] = f2bf2(a1.z, a1.w);
            av = af.v;
        }
        #pragma unroll
        for (int nt = 0; nt < 8; ++nt) {
            bf16x8 bf = *(const bf16x8*)(Wt + (size_t)(nt * 16 + m15) * 128 + ks);
            acc[nt] = __builtin_amdgcn_mfma_f32_16x16x32_bf16(av, bf, acc[nt], 0, 0, 0);
        }
    }

    #pragma unroll
    for (int nt = 0; nt < 8; ++nt) {
        int col = nt * 16 + m15;
        float bc = 0.f;
        if constexpr (BIAS_MODE != 0) bc = bias[col];
        #pragma unroll
        for (int reg = 0; reg < 4; ++reg) {
            int row = row0 + quad * 4 + reg;
            if (row < M) {
                float v = acc[nt][reg];
                if constexpr (BIAS_MODE == 1) v += bc;
                if constexpr (BIAS_MODE == 2) v += bc * (float)deg[row];
                if constexpr (SILU) v = siluf(v);
                if constexpr (ACCBF) v += bf2f(Ch[(size_t)row * 128 + col]);
                if constexpr (WF32) C[(size_t)row * 128 + col] = v;
                if constexpr (WBF) Ch[(size_t)row * 128 + col] = f2bf(v);
            }
        }
    }
}

// ---------------- out_block gather (R6-proven shape: 2 ch/lane, 4-deep) ----------------
__global__ __launch_bounds__(256) void k_out_gather(const int* __restrict__ rowptr, const int* __restrict__ slist,
                                                    const float* __restrict__ rbfS,
                                                    const unsigned short* __restrict__ xh,
                                                    const float* __restrict__ wrbf, float* __restrict__ h, int n) {
    int node = blockIdx.x * 4 + (threadIdx.x >> 6);
    int lane = threadIdx.x & 63;
    if (node >= n) return;
    int c = lane * 2;
    float wc0[6], wc1[6];
    #pragma unroll
    for (int r = 0; r < 6; ++r) { wc0[r] = wrbf[r * 128 + c]; wc1[r] = wrbf[r * 128 + c + 1]; }
    float a0 = 0.f, a1 = 0.f;
    int p0 = rowptr[node], p1 = rowptr[node + 1];
    int p = p0;
    for (; p + 4 <= p1; p += 4) {
        int s0 = slist[p], s1 = slist[p + 1], s2 = slist[p + 2], s3 = slist[p + 3];
        float2 rb[4][3];
        #pragma unroll
        for (int u = 0; u < 4; ++u) {
            const float2* r2 = (const float2*)&rbfS[(size_t)(p + u) * 6];
            rb[u][0] = r2[0]; rb[u][1] = r2[1]; rb[u][2] = r2[2];
        }
        unsigned int xv0 = *(const unsigned int*)&xh[(size_t)s0 * 128 + c];
        unsigned int xv1 = *(const unsigned int*)&xh[(size_t)s1 * 128 + c];
        unsigned int xv2 = *(const unsigned int*)&xh[(size_t)s2 * 128 + c];
        unsigned int xv3 = *(const unsigned int*)&xh[(size_t)s3 * 128 + c];
        #pragma unroll
        for (int u = 0; u < 4; ++u) {
            float e0 = rb[u][0].x * wc0[0] + rb[u][0].y * wc0[1] + rb[u][1].x * wc0[2] +
                       rb[u][1].y * wc0[3] + rb[u][2].x * wc0[4] + rb[u][2].y * wc0[5];
            float e1 = rb[u][0].x * wc1[0] + rb[u][0].y * wc1[1] + rb[u][1].x * wc1[2] +
                       rb[u][1].y * wc1[3] + rb[u][2].x * wc1[4] + rb[u][2].y * wc1[5];
            float2 xf = bf2x2((u == 0) ? xv0 : (u == 1) ? xv1 : (u == 2) ? xv2 : xv3);
            a0 += xf.x * e0;
            a1 += xf.y * e1;
        }
    }
    for (; p < p1; ++p) {
        int src = slist[p];
        const float2* r2 = (const float2*)&rbfS[(size_t)p * 6];
        float2 ra = r2[0], rbx = r2[1], rc = r2[2];
        float e0 = ra.x * wc0[0] + ra.y * wc0[1] + rbx.x * wc0[2] + rbx.y * wc0[3] + rc.x * wc0[4] + rc.y * wc0[5];
        float e1 = ra.x * wc1[0] + ra.y * wc1[1] + rbx.x * wc1[2] + rbx.y * wc1[3] + rc.x * wc1[4] + rc.y * wc1[5];
        float2 xf = bf2x2(*(const unsigned int*)&xh[(size_t)src * 128 + c]);
        a0 += xf.x * e0;
        a1 += xf.y * e1;
    }
    h[(size_t)node * 128 + c] = a0;
    h[(size_t)node * 128 + c + 1] = a1;
}

// ---------------- P accumulate ----------------
template <bool ACC>
__global__ __launch_bounds__(256) void k_p_acc(const float* __restrict__ h, const float* __restrict__ w2col,
                                               const float* __restrict__ ob2p, float* __restrict__ P, int n) {
    int node = blockIdx.x * 4 + (threadIdx.x >> 6);
    int lane = threadIdx.x & 63;
    if (node >= n) return;
    int c = lane * 2;
    float2 hv = *(const float2*)&h[(size_t)node * 128 + c];
    float s = hv.x * w2col[c] + hv.y * w2col[c + 1];
    #pragma unroll
    for (int off = 32; off > 0; off >>= 1) s += __shfl_xor(s, off, 64);
    if (lane == 0) {
        float r = s + ob2p[0];
        if (ACC) r += P[node];
        P[node] = r;
    }
}

// ---------------- triplet SV via sorted CSR gather ----------------
__global__ __launch_bounds__(256) void k_trip_sv(const int* __restrict__ rowptrT, const float* __restrict__ dsort,
                                                 const float* __restrict__ asort, const float* __restrict__ sfreq,
                                                 const float* __restrict__ W1, float* __restrict__ SV, int n) {
    int grp = (blockIdx.x * 256 + threadIdx.x) >> 3;
    int k = threadIdx.x & 7;
    if (grp >= n) return;
    float w[24];
    #pragma unroll
    for (int i = 0; i < 24; ++i) w[i] = W1[i * 8 + k];
    float f0 = sfreq[0], f1 = sfreq[1], f2 = sfreq[2], f3 = sfreq[3], f4 = sfreq[4], f5 = sfreq[5];
    float acc = 0.f;
    int p0 = rowptrT[grp], p1 = rowptrT[grp + 1];
    for (int p = p0; p < p1; ++p) {
        float d = dsort[p] * 0.2f;
        float a = asort[p];
        float d2 = d * d, d4 = d2 * d2, d5 = d4 * d;
        float env = __fdividef(1.0f, d) - 28.0f * d5 + 48.0f * d5 * d - 21.0f * d5 * d2;
        float rb0 = env * __sinf(f0 * d), rb1 = env * __sinf(f1 * d), rb2 = env * __sinf(f2 * d);
        float rb3 = env * __sinf(f3 * d), rb4 = env * __sinf(f4 * d), rb5 = env * __sinf(f5 * d);
        float s1 = a, s2 = 1.5f * a * a - 0.5f, s3 = 2.5f * a * a * a - 1.5f * a;
        float u = rb0 * w[0] + rb1 * w[1] + rb2 * w[2] + rb3 * w[3] + rb4 * w[4] + rb5 * w[5];
        u += s1 * (rb0 * w[6] + rb1 * w[7] + rb2 * w[8] + rb3 * w[9] + rb4 * w[10] + rb5 * w[11]);
        u += s2 * (rb0 * w[12] + rb1 * w[13] + rb2 * w[14] + rb3 * w[15] + rb4 * w[16] + rb5 * w[17]);
        u += s3 * (rb0 * w[18] + rb1 * w[19] + rb2 * w[20] + rb3 * w[21] + rb4 * w[22] + rb5 * w[23]);
        acc += siluf(u);
    }
    SV[grp * 8 + k] = acc;
}

// ---------------- e2 = SV @ iw_sbf2 ----------------
__global__ __launch_bounds__(256) void k_sv_gemm(const float* __restrict__ SV, const float* __restrict__ W2,
                                                 float* __restrict__ e2, int n) {
    __shared__ float W2s[8 * 128];
    int tid = threadIdx.x;
    for (int i = tid; i < 1024; i += 256) W2s[i] = W2[i];
    __syncthreads();
    int t = blockIdx.x * 256 + tid;
    if (t >= n * 32) return;
    int node = t >> 5, q = t & 31;
    const float* sv = &SV[node * 8];
    int c = q * 4;
    float out[4] = {0.f, 0.f, 0.f, 0.f};
    #pragma unroll
    for (int k = 0; k < 8; ++k) {
        float s = sv[k];
        #pragma unroll
        for (int i = 0; i < 4; ++i) out[i] += s * W2s[k * 128 + c + i];
    }
    *(float4*)&e2[(size_t)node * 128 + c] = make_float4(out[0], out[1], out[2], out[3]);
}

// ---------------- extra[c] = sum_n t_mat[n][c] * e2[n][c] ----------------
__global__ __launch_bounds__(256) void k_extra_reduce(const float* __restrict__ Tm, const float* __restrict__ E2,
                                                      float* __restrict__ extra, int n) {
    const float4* t4 = (const float4*)Tm;
    const float4* e4 = (const float4*)E2;
    int tid = threadIdx.x;
    int q = tid & 31, rl = tid >> 5;
    float ax = 0.f, ay = 0.f, az = 0.f, aw = 0.f;
    for (int nn = blockIdx.x * 8 + rl; nn < n; nn += 1024) {
        float4 a = t4[(size_t)nn * 32 + q];
        float4 b = e4[(size_t)nn * 32 + q];
        ax += a.x * b.x; ay += a.y * b.y; az += a.z * b.z; aw += a.w * b.w;
    }
    __shared__ float4 red[256];
    red[tid] = make_float4(ax, ay, az, aw);
    __syncthreads();
    if (tid < 128) {
        float4 o = red[tid + 128];
        red[tid].x += o.x; red[tid].y += o.y; red[tid].z += o.z; red[tid].w += o.w;
    }
    __syncthreads();
    if (tid < 64) {
        float4 o = red[tid + 64];
        red[tid].x += o.x; red[tid].y += o.y; red[tid].z += o.z; red[tid].w += o.w;
    }
    __syncthreads();
    if (tid < 32) {
        float4 r = red[tid];
        float4 o = red[tid + 32];
        r.x += o.x; r.y += o.y; r.z += o.z; r.w += o.w;
        atomicAdd(&extra[tid * 4 + 0], r.x);
        atomicAdd(&extra[tid * 4 + 1], r.y);
        atomicAdd(&extra[tid * 4 + 2], r.z);
        atomicAdd(&extra[tid * 4 + 3], r.w);
    }
}

// ---------------- interaction (R6 shape + fdot2 + bf16 x state) ----------------
__global__ __launch_bounds__(256) void k_interact(const int* __restrict__ rowptr, const int* __restrict__ slist,
                                                  const __half* __restrict__ s8, const float* __restrict__ W2,
                                                  const float* __restrict__ extra,
                                                  const unsigned short* __restrict__ xuph,
                                                  unsigned short* __restrict__ xh, int n) {
    int node = blockIdx.x * 4 + (threadIdx.x >> 6);
    int lane = threadIdx.x & 63;
    if (node >= n) return;
    int c = lane * 2;
    f16x2 w2a[4], w2b[4];
    #pragma unroll
    for (int j = 0; j < 4; ++j) {
        f16x2 wa, wb;
        wa.x = (_Float16)W2[(2 * j) * 128 + c];
        wa.y = (_Float16)W2[(2 * j + 1) * 128 + c];
        wb.x = (_Float16)W2[(2 * j) * 128 + c + 1];
        wb.y = (_Float16)W2[(2 * j + 1) * 128 + c + 1];
        w2a[j] = wa;
        w2b[j] = wb;
    }
    int p0 = rowptr[node], p1 = rowptr[node + 1];
    float cntf = (float)(p1 - p0);
    float a0 = cntf * extra[c], a1 = cntf * extra[c + 1];
    int p = p0;
    for (; p + 4 <= p1; p += 4) {
        int s0 = slist[p], s1 = slist[p + 1], s2 = slist[p + 2], s3 = slist[p + 3];
        uint4 sv[4];
        #pragma unroll
        for (int u = 0; u < 4; ++u) sv[u] = *(const uint4*)(s8 + (size_t)(p + u) * 8);
        unsigned int xv0 = *(const unsigned int*)&xuph[(size_t)s0 * 128 + c];
        unsigned int xv1 = *(const unsigned int*)&xuph[(size_t)s1 * 128 + c];
        unsigned int xv2 = *(const unsigned int*)&xuph[(size_t)s2 * 128 + c];
        unsigned int xv3 = *(const unsigned int*)&xuph[(size_t)s3 * 128 + c];
        #pragma unroll
        for (int u = 0; u < 4; ++u) {
            union { uint4 q; f16x2 h[4]; } s;
            s.q = sv[u];
            float e0 = fdot2f(s.h[0], w2a[0], 0.f);
            e0 = fdot2f(s.h[1], w2a[1], e0);
            e0 = fdot2f(s.h[2], w2a[2], e0);
            e0 = fdot2f(s.h[3], w2a[3], e0);
            float e1 = fdot2f(s.h[0], w2b[0], 0.f);
            e1 = fdot2f(s.h[1], w2b[1], e1);
            e1 = fdot2f(s.h[2], w2b[2], e1);
            e1 = fdot2f(s.h[3], w2b[3], e1);
            float2 xf = bf2x2((u == 0) ? xv0 : (u == 1) ? xv1 : (u == 2) ? xv2 : xv3);
            a0 += xf.x * e0;
            a1 += xf.y * e1;
        }
    }
    for (; p < p1; ++p) {
        int src = slist[p];
        float2 xf = bf2x2(*(const unsigned int*)&xuph[(size_t)src * 128 + c]);
        union { uint4 q; f16x2 h[4]; } s;
        s.q = *(const uint4*)(s8 + (size_t)p * 8);
        float e0 = fdot2f(s.h[0], w2a[0], 0.f);
        e0 = fdot2f(s.h[1], w2a[1], e0);
        e0 = fdot2f(s.h[2], w2a[2], e0);
        e0 = fdot2f(s.h[3], w2a[3], e0);
        float e1 = fdot2f(s.h[0], w2b[0], 0.f);
        e1 = fdot2f(s.h[1], w2b[1], e1);
        e1 = fdot2f(s.h[2], w2b[2], e1);
        e1 = fdot2f(s.h[3], w2b[3], e1);
        a0 += xf.x * e0;
        a1 += xf.y * e1;
    }
    unsigned int cur = *(unsigned int*)&xh[(size_t)node * 128 + c];
    float2 xc = bf2x2(cur);
    *(unsigned int*)&xh[(size_t)node * 128 + c] = f2bf2(xc.x + a0, xc.y + a1);
}

// ---------------- pooling ----------------
__global__ __launch_bounds__(256) void k_pool(const float* __restrict__ P, const int* __restrict__ batch,
                                              float* __restrict__ pool, float* __restrict__ cnt, int n) {
    int i = blockIdx.x * 256 + threadIdx.x;
    int lane = threadIdx.x & 63;
    int b = (i < n) ? batch[i] : -1;
    float p = (i < n) ? P[i] : 0.f;
    int b0 = __shfl(b, 0, 64);
    int b63 = __shfl(b, 63, 64);
    if (b0 == b63 && b0 >= 0) {
        float s = p;
        #pragma unroll
        for (int off = 32; off > 0; off >>= 1) s += __shfl_xor(s, off, 64);
        if (lane == 0) {
            atomicAdd(&pool[b0], s);
            atomicAdd(&cnt[b0], 64.0f);
        }
    } else {
        if (i < n) {
            atomicAdd(&pool[b], p);
            atomicAdd(&cnt[b], 1.0f);
        }
    }
}

__global__ __launch_bounds__(64) void k_final(const float* __restrict__ pool, const float* __restrict__ cnt,
                                              float* __restrict__ out) {
    int g = threadIdx.x;
    if (g < G_) out[g] = __fdividef(pool[g], fmaxf(cnt[g], 1.0f));
}

extern "C" void kernel_launch(void* const* d_in, const int* in_sizes, int n_in,
                              void* d_out, int out_size, void* d_ws, size_t ws_size,
                              hipStream_t stream) {
    (void)in_sizes; (void)n_in; (void)out_size; (void)ws_size;
    const int* z = (const int*)d_in[0];
    const float* dist = (const float*)d_in[1];
    const float* dist_trip = (const float*)d_in[2];
    const float* angle = (const float*)d_in[3];
    const int* edge_index = (const int*)d_in[4];
    const int* triplets = (const int*)d_in[5];
    const int* batch = (const int*)d_in[6];
    const float* atom_table = (const float*)d_in[7];
    const float* rbf_freq = (const float*)d_in[8];
    const float* sbf_freq = (const float*)d_in[9];
    const float* emb_w1 = (const float*)d_in[10];
    const float* emb_b1 = (const float*)d_in[11];
    const float* emb_w2 = (const float*)d_in[12];
    const float* emb_b2 = (const float*)d_in[13];
    const float* iw_rbf1 = (const float*)d_in[14];
    const float* iw_rbf2 = (const float*)d_in[15];
    const float* iw_sbf1 = (const float*)d_in[16];
    const float* iw_sbf2 = (const float*)d_in[17];
    const float* iw_t1 = (const float*)d_in[18];
    const float* iw_t2 = (const float*)d_in[19];
    const float* ib_t2 = (const float*)d_in[20];
    const float* iw_up = (const float*)d_in[21];
    const float* ib_up = (const float*)d_in[22];
    const float* iw_down = (const float*)d_in[23];
    const float* ib_down = (const float*)d_in[24];
    const float* ow_rbf = (const float*)d_in[25];
    const float* ow0 = (const float*)d_in[26];
    const float* ob0 = (const float*)d_in[27];
    const float* ow1 = (const float*)d_in[28];
    const float* ob1 = (const float*)d_in[29];
    const float* ow2 = (const float*)d_in[30];
    const float* ob2 = (const float*)d_in[31];

    const int* erow = edge_index;
    const int* ecol = edge_index + E_;

    // workspace layout (no fp32 x — node state is bf16 xh)
    float* ws = (float*)d_ws;
    float* bufA = ws;                          // N*128
    float* bufB = bufA + (size_t)N_ * H_;      // N*128
    float* P = bufB + (size_t)N_ * H_;         // N
    float* rbfS = P + N_;                      // E*6 (CSR order)
    float* SV = rbfS + (size_t)E_ * 6;         // N*8
    float* extra = SV + (size_t)N_ * 8;        // 128
    float* pool = extra + 128;                 // G
    float* cnt = pool + G_;                    // G
    int* deg = (int*)(cnt + G_);               // N
    int* rowptr = deg + N_;                    // N+1
    int* cur = rowptr + N_ + 1;                // N
    int* elist = cur + N_;                     // E
    int* slist = elist + E_;                   // E
    int* rowptrT = slist + E_;                 // N+1
    int* degT = rowptrT + N_ + 1;              // N
    float* dsort = (float*)(degT + N_);        // T
    float* asort = dsort + T_;                 // T
    __half* s8h = (__half*)(asort + T_);       // E*8 halves
    unsigned short* xh = (unsigned short*)(s8h + (size_t)E_ * 8);   // N*128 bf16 node state
    unsigned short* xuph = xh + (size_t)N_ * H_;                    // N*128 bf16 x_up
    unsigned short* Wt = xuph + (size_t)N_ * H_;                    // 27*16384 bf16 transposed weights

    const int EG = (E_ + 255) / 256;
    const int TG = (T_ + 255) / 256;
    const int NG4 = (N_ + 3) / 4;
    const int GEMMG = (N_ + 63) / 64;

    hipMemsetAsync(deg, 0, N_ * sizeof(int), stream);
    hipMemsetAsync(degT, 0, N_ * sizeof(int), stream);
    k_wprep<<<27 * 8, 256, 0, stream>>>(emb_w2, iw_down, iw_t1, iw_t2, iw_up, ow0, ow1, Wt);
    k_count<<<EG, 256, 0, stream>>>(ecol, deg, E_);
    k_countT<<<TG, 256, 0, stream>>>(triplets, degT, T_);
    k_scan<<<1, 1024, 0, stream>>>(deg, rowptr, cur, N_);
    k_fill<<<EG, 256, 0, stream>>>(ecol, erow, cur, elist, slist, E_);
    k_scan<<<1, 1024, 0, stream>>>(degT, rowptrT, cur, N_);
    k_fillT<<<TG, 256, 0, stream>>>(triplets, cur, dist_trip, angle, dsort, asort, T_);

    k_rbfS<<<EG, 256, 0, stream>>>(elist, dist, rbf_freq, rbfS, E_);
    k_init_x<<<(N_ * 16 + 255) / 256, 256, 0, stream>>>(atom_table, z, xh, N_);

    // embedding: xh = bf16( xh + SS @ w2 + deg*b2 )
    k_embS<<<NG4, 256, 0, stream>>>(rowptr, rbfS, emb_w1, emb_b1, bufA, N_);
    k_gemm_mfma<2, false, true, false, false, true><<<GEMMG, 256, 0, stream>>>(bufA, Wt, emb_b2, deg,
                                                                               nullptr, xh, N_);

    auto out_block = [&](int k, bool first) {
        k_out_gather<<<NG4, 256, 0, stream>>>(rowptr, slist, rbfS, xh,
                                              ow_rbf + (size_t)k * 6 * 128, bufA, N_);
        k_gemm_mfma<1, true, false, false, true, false><<<GEMMG, 256, 0, stream>>>(bufA, Wt + (size_t)(17 + k) * 16384,
                                                                                   ob0 + k * 128, nullptr, bufB, nullptr, N_);
        k_gemm_mfma<1, true, false, false, true, false><<<GEMMG, 256, 0, stream>>>(bufB, Wt + (size_t)(22 + k) * 16384,
                                                                                   ob1 + k * 128, nullptr, bufA, nullptr, N_);
        if (first)
            k_p_acc<false><<<NG4, 256, 0, stream>>>(bufA, ow2 + k * 128, ob2 + k, P, N_);
        else
            k_p_acc<true><<<NG4, 256, 0, stream>>>(bufA, ow2 + k * 128, ob2 + k, P, N_);
    };

    out_block(0, true);

    for (int b = 0; b < 4; ++b) {
        // t-chain: bufA = xh @ down (bf16 A); bufB = silu(bufA@t1); bufA = bufB@t2 + b
        k_gemm_mfma<1, false, false, true, true, false><<<GEMMG, 256, 0, stream>>>(xh, Wt + (size_t)(1 + b) * 16384,
                                                                                   ib_down + b * 128, nullptr, bufA, nullptr, N_);
        k_gemm_mfma<0, true, false, false, true, false><<<GEMMG, 256, 0, stream>>>(bufA, Wt + (size_t)(5 + b) * 16384,
                                                                                   nullptr, nullptr, bufB, nullptr, N_);
        k_gemm_mfma<1, false, false, false, true, false><<<GEMMG, 256, 0, stream>>>(bufB, Wt + (size_t)(9 + b) * 16384,
                                                                                    ib_t2 + b * 128, nullptr, bufA, nullptr, N_);
        k_trip_sv<<<(N_ * 8 + 255) / 256, 256, 0, stream>>>(rowptrT, dsort, asort, sbf_freq,
                                                            iw_sbf1 + (size_t)b * 192, SV, N_);
        k_sv_gemm<<<(N_ * 32) / 256, 256, 0, stream>>>(SV, iw_sbf2 + (size_t)b * 1024, bufB, N_);
        hipMemsetAsync(extra, 0, 128 * sizeof(float), stream);
        k_extra_reduce<<<128, 256, 0, stream>>>(bufA, bufB, extra, N_);
        k_s8h<<<EG, 256, 0, stream>>>(rbfS, iw_rbf1 + (size_t)b * 48, s8h, E_);
        // x_up: bf16 in, bf16 out only (no fp32 write)
        k_gemm_mfma<1, false, false, true, false, true><<<GEMMG, 256, 0, stream>>>(xh, Wt + (size_t)(13 + b) * 16384,
                                                                                   ib_up + b * 128, nullptr, nullptr, xuph, N_);
        k_interact<<<NG4, 256, 0, stream>>>(rowptr, slist, s8h, iw_rbf2 + (size_t)b * 1024, extra,
                                            xuph, xh, N_);
        out_block(b + 1, false);
    }

    hipMemsetAsync(pool, 0, 2 * G_ * sizeof(float), stream);
    k_pool<<<(N_ + 255) / 256, 256, 0, stream>>>(P, batch, pool, cnt, N_);
    k_final<<<1, 64, 0, stream>>>(pool, cnt, (float*)d_out);
}

// Round 11
// 2067.915 us; speedup vs baseline: 1.2657x; 1.0658x over previous
//
#include <hip/hip_runtime.h>
#include <hip/hip_fp16.h>

#define N_ 50000
#define E_ 800000
#define T_ 800000
#define G_ 64
#define H_ 128

typedef __attribute__((ext_vector_type(8))) short bf16x8;
typedef __attribute__((ext_vector_type(4))) float f32x4;
typedef _Float16 f16x2 __attribute__((ext_vector_type(2)));

__device__ __forceinline__ float siluf(float v) {
    return __fdividef(v, 1.0f + __expf(-v));
}

// bf16 helpers
__device__ __forceinline__ unsigned short f2bf(float f) {
    unsigned int u = __float_as_uint(f);
    u += 0x7fffu + ((u >> 16) & 1u);
    return (unsigned short)(u >> 16);
}
__device__ __forceinline__ unsigned int f2bf2(float a, float b) {
    return (unsigned int)f2bf(a) | ((unsigned int)f2bf(b) << 16);
}
__device__ __forceinline__ float bf2f(unsigned short h) {
    return __uint_as_float(((unsigned int)h) << 16);
}
__device__ __forceinline__ float2 bf2x2(unsigned int p) {
    return make_float2(__uint_as_float(p << 16), __uint_as_float(p & 0xffff0000u));
}
__device__ __forceinline__ float fdot2f(f16x2 a, f16x2 b, float c) {
    return __builtin_amdgcn_fdot2(a, b, c, false);
}

// ---------------- CSR build ----------------
__global__ __launch_bounds__(256) void k_count(const int* __restrict__ col, int* deg, int n) {
    int e = blockIdx.x * 256 + threadIdx.x;
    if (e < n) atomicAdd(&deg[col[e]], 1);
}

__global__ __launch_bounds__(256) void k_countT(const int* __restrict__ trip, int* deg, int n) {
    int t = blockIdx.x * 256 + threadIdx.x;
    if (t < n) atomicAdd(&deg[trip[3 * t + 1]], 1);
}

__global__ __launch_bounds__(1024) void k_scan(const int* __restrict__ deg, int* rowptr, int* cur, int n) {
    __shared__ int wsum[16];
    __shared__ int s_carry;
    int tid = threadIdx.x, lane = tid & 63, w = tid >> 6;
    if (tid == 0) s_carry = 0;
    __syncthreads();
    for (int base = 0; base < n; base += 1024) {
        int i = base + tid;
        int v = (i < n) ? deg[i] : 0;
        int incl = v;
        #pragma unroll
        for (int s = 1; s < 64; s <<= 1) {
            int t = __shfl_up(incl, (unsigned)s, 64);
            if (lane >= s) incl += t;
        }
        if (lane == 63) wsum[w] = incl;
        __syncthreads();
        int carry0 = s_carry;
        int wexcl = 0;
        for (int j = 0; j < w; ++j) wexcl += wsum[j];
        int excl = carry0 + wexcl + (incl - v);
        if (i < n) { rowptr[i] = excl; cur[i] = excl; }
        __syncthreads();
        if (tid == 1023) s_carry = carry0 + wexcl + incl;
        __syncthreads();
    }
    if (tid == 0) rowptr[n] = s_carry;
}

__global__ __launch_bounds__(256) void k_fill(const int* __restrict__ col, const int* __restrict__ row,
                                              int* cur, int* elist, int* slist, int n) {
    int e = blockIdx.x * 256 + threadIdx.x;
    if (e < n) {
        int pos = atomicAdd(&cur[col[e]], 1);
        elist[pos] = e;
        slist[pos] = row[e];
    }
}

__global__ __launch_bounds__(256) void k_fillT(const int* __restrict__ trip, int* cur,
                                               const float* __restrict__ dist_trip, const float* __restrict__ angle,
                                               float* __restrict__ dsort, float* __restrict__ asort, int n) {
    int t = blockIdx.x * 256 + threadIdx.x;
    if (t < n) {
        int pos = atomicAdd(&cur[trip[3 * t + 1]], 1);
        dsort[pos] = dist_trip[t];
        asort[pos] = angle[t];
    }
}

// ---------------- weight prep: fp32 (k,n) -> bf16 transposed (n,k), 27 matrices ----------------
__global__ __launch_bounds__(256) void k_wprep(const float* __restrict__ emb_w2, const float* __restrict__ iw_down,
                                               const float* __restrict__ iw_t1, const float* __restrict__ iw_t2,
                                               const float* __restrict__ iw_up, const float* __restrict__ ow0,
                                               const float* __restrict__ ow1, unsigned short* __restrict__ Wt) {
    int mat = blockIdx.x >> 3;
    int part = blockIdx.x & 7;
    const float* src;
    if (mat == 0) src = emb_w2;
    else if (mat < 5) src = iw_down + (size_t)(mat - 1) * 16384;
    else if (mat < 9) src = iw_t1 + (size_t)(mat - 5) * 16384;
    else if (mat < 13) src = iw_t2 + (size_t)(mat - 9) * 16384;
    else if (mat < 17) src = iw_up + (size_t)(mat - 13) * 16384;
    else if (mat < 22) src = ow0 + (size_t)(mat - 17) * 16384;
    else src = ow1 + (size_t)(mat - 22) * 16384;
    unsigned short* dst = Wt + (size_t)mat * 16384;
    int base = part * 2048;
    for (int i = base + threadIdx.x; i < base + 2048; i += 256) {
        int k = i >> 7, n = i & 127;
        dst[n * 128 + k] = f2bf(src[i]);
    }
}

// ---------------- rbf in CSR (segment) order ----------------
__global__ __launch_bounds__(256) void k_rbfS(const int* __restrict__ elist, const float* __restrict__ dist,
                                              const float* __restrict__ freq, float* __restrict__ rbfS, int n) {
    int p = blockIdx.x * 256 + threadIdx.x;
    if (p >= n) return;
    int e = elist[p];
    float d = dist[e] * 0.2f;
    float d2 = d * d, d4 = d2 * d2, d5 = d4 * d;
    float env = __fdividef(1.0f, d) - 28.0f * d5 + 48.0f * d5 * d - 21.0f * d5 * d2;
    #pragma unroll
    for (int r = 0; r < 6; ++r) rbfS[p * 6 + r] = env * __sinf(freq[r] * d);
}

// ---------------- edge factors for ALL 4 blocks: s8all[b][p][k] = silu(rbfS[p] . W1_b[:,k]) ----------------
__global__ __launch_bounds__(256) void k_s8h_all(const float* __restrict__ rbfS, const float* __restrict__ iw_rbf1,
                                                 __half* __restrict__ s8all, int n) {
    __shared__ float W1s[4][48];
    int tid = threadIdx.x;
    if (tid < 192) W1s[tid / 48][tid % 48] = iw_rbf1[tid];
    __syncthreads();
    int p = blockIdx.x * 256 + tid;
    if (p >= n) return;
    const float2* r2 = (const float2*)&rbfS[(size_t)p * 6];
    float2 ra = r2[0], rbx = r2[1], rc = r2[2];
    float rb[6] = {ra.x, ra.y, rbx.x, rbx.y, rc.x, rc.y};
    #pragma unroll
    for (int b = 0; b < 4; ++b) {
        __half out[8];
        #pragma unroll
        for (int k = 0; k < 8; ++k) {
            float u = 0.f;
            #pragma unroll
            for (int r = 0; r < 6; ++r) u += rb[r] * W1s[b][r * 8 + k];
            out[k] = __float2half(siluf(u));
        }
        *(uint4*)&s8all[((size_t)b * n + p) * 8] = *(uint4*)out;
    }
}

// ---------------- xh = bf16(atom_table[z]) ----------------
__global__ __launch_bounds__(256) void k_init_x(const float* __restrict__ atab, const int* __restrict__ z,
                                                unsigned short* __restrict__ xh, int n) {
    int t = blockIdx.x * 256 + threadIdx.x;
    if (t >= n * 16) return;
    int node = t >> 4, q = t & 15;
    const float4* a4 = (const float4*)atab;
    float4 v0 = a4[(size_t)z[node] * 32 + q * 2];
    float4 v1 = a4[(size_t)z[node] * 32 + q * 2 + 1];
    uint4 pk;
    pk.x = f2bf2(v0.x, v0.y);
    pk.y = f2bf2(v0.z, v0.w);
    pk.z = f2bf2(v1.x, v1.y);
    pk.w = f2bf2(v1.z, v1.w);
    ((uint4*)xh)[t] = pk;
}

// ---------------- SS[n] = sum_{e in n} silu(rbf_e @ w1 + b1) ----------------
__global__ __launch_bounds__(256) void k_embS(const int* __restrict__ rowptr, const float* __restrict__ rbfS,
                                              const float* __restrict__ w1, const float* __restrict__ b1,
                                              float* __restrict__ SS, int n) {
    int node = blockIdx.x * 4 + (threadIdx.x >> 6);
    int lane = threadIdx.x & 63;
    if (node >= n) return;
    int c = lane * 2;
    float wc0[6], wc1[6];
    #pragma unroll
    for (int r = 0; r < 6; ++r) { wc0[r] = w1[r * 128 + c]; wc1[r] = w1[r * 128 + c + 1]; }
    float bb0 = b1[c], bb1 = b1[c + 1];
    float a0 = 0.f, a1 = 0.f;
    int p0 = rowptr[node], p1 = rowptr[node + 1];
    for (int p = p0; p < p1; ++p) {
        const float2* r2 = (const float2*)&rbfS[(size_t)p * 6];
        float2 ra = r2[0], rbx = r2[1], rc = r2[2];
        float u0 = bb0 + ra.x * wc0[0] + ra.y * wc0[1] + rbx.x * wc0[2] + rbx.y * wc0[3] + rc.x * wc0[4] + rc.y * wc0[5];
        float u1 = bb1 + ra.x * wc1[0] + ra.y * wc1[1] + rbx.x * wc1[2] + rbx.y * wc1[3] + rc.x * wc1[4] + rc.y * wc1[5];
        a0 += siluf(u0);
        a1 += siluf(u1);
    }
    SS[node * 128 + c] = a0;
    SS[node * 128 + c + 1] = a1;
}

// ---------------- MFMA GEMM: flexible IO + fused P-accumulate ----------------
// ABF: A bf16. ACCBF: += bf16 Ch. WF32/WBF: write fp32 C / bf16 Ch.
// PACC: 0 none, 1 P[row] = dot+ob2, 2 P[row] += dot+ob2 (skips C stores).
template <int BIAS_MODE, bool SILU, bool ACCBF, bool ABF, bool WF32, bool WBF, int PACC>
__global__ __launch_bounds__(256, 4) void k_gemm_mfma(const void* __restrict__ Ap,
                                                      const unsigned short* __restrict__ Wt,
                                                      const float* __restrict__ bias, const int* __restrict__ deg,
                                                      float* __restrict__ C, unsigned short* __restrict__ Ch,
                                                      const float* __restrict__ w2col, const float* __restrict__ ob2p,
                                                      float* __restrict__ Pout, int M) {
    int tid = threadIdx.x;
    int wave = tid >> 6, lane = tid & 63;
    int m15 = lane & 15, quad = lane >> 4;
    int row0 = blockIdx.x * 64 + wave * 16;
    int arow = row0 + m15;
    if (arow > M - 1) arow = M - 1;

    f32x4 acc[8];
    #pragma unroll
    for (int nt = 0; nt < 8; ++nt) acc[nt] = (f32x4){0.f, 0.f, 0.f, 0.f};

    #pragma unroll
    for (int kt = 0; kt < 4; ++kt) {
        int ks = kt * 32 + quad * 8;
        bf16x8 av;
        if constexpr (ABF) {
            av = *(const bf16x8*)((const unsigned short*)Ap + (size_t)arow * 128 + ks);
        } else {
            const float* Arow = (const float*)Ap + (size_t)arow * 128;
            float4 a0 = *(const float4*)(Arow + ks);
            float4 a1 = *(const float4*)(Arow + ks + 4);
            union { bf16x8 v; unsigned int u[4]; } af;
            af.u[0] = f2bf2(a0.x, a0.y);
            af.u[1] = f2bf2(a0.z, a0.w);
            af.u[2] = f2bf2(a1.x, a1.y);
            af.u[3] = f2bf2(a1.z, a1.w);
            av = af.v;
        }
        #pragma unroll
        for (int nt = 0; nt < 8; ++nt) {
            bf16x8 bf = *(const bf16x8*)(Wt + (size_t)(nt * 16 + m15) * 128 + ks);
            acc[nt] = __builtin_amdgcn_mfma_f32_16x16x32_bf16(av, bf, acc[nt], 0, 0, 0);
        }
    }

    float w2c[8];
    float pp[4];
    if constexpr (PACC != 0) {
        #pragma unroll
        for (int nt = 0; nt < 8; ++nt) w2c[nt] = w2col[nt * 16 + m15];
        #pragma unroll
        for (int reg = 0; reg < 4; ++reg) pp[reg] = 0.f;
    }

    #pragma unroll
    for (int nt = 0; nt < 8; ++nt) {
        int col = nt * 16 + m15;
        float bc = 0.f;
        if constexpr (BIAS_MODE != 0) bc = bias[col];
        #pragma unroll
        for (int reg = 0; reg < 4; ++reg) {
            int row = row0 + quad * 4 + reg;
            if (row < M) {
                float v = acc[nt][reg];
                if constexpr (BIAS_MODE == 1) v += bc;
                if constexpr (BIAS_MODE == 2) v += bc * (float)deg[row];
                if constexpr (SILU) v = siluf(v);
                if constexpr (ACCBF) v += bf2f(Ch[(size_t)row * 128 + col]);
                if constexpr (WF32) C[(size_t)row * 128 + col] = v;
                if constexpr (WBF) Ch[(size_t)row * 128 + col] = f2bf(v);
                if constexpr (PACC != 0) pp[reg] += v * w2c[nt];
            }
        }
    }

    if constexpr (PACC != 0) {
        #pragma unroll
        for (int reg = 0; reg < 4; ++reg) {
            float s = pp[reg];
            s += __shfl_xor(s, 1, 64);
            s += __shfl_xor(s, 2, 64);
            s += __shfl_xor(s, 4, 64);
            s += __shfl_xor(s, 8, 64);
            if (m15 == 0) {
                int row = row0 + quad * 4 + reg;
                if (row < M) {
                    float r = s + ob2p[0];
                    if constexpr (PACC == 2) r += Pout[row];
                    Pout[row] = r;
                }
            }
        }
    }
}

// ---------------- out_block gather (R6-proven shape: 2 ch/lane, 4-deep) ----------------
__global__ __launch_bounds__(256) void k_out_gather(const int* __restrict__ rowptr, const int* __restrict__ slist,
                                                    const float* __restrict__ rbfS,
                                                    const unsigned short* __restrict__ xh,
                                                    const float* __restrict__ wrbf, float* __restrict__ h, int n) {
    int node = blockIdx.x * 4 + (threadIdx.x >> 6);
    int lane = threadIdx.x & 63;
    if (node >= n) return;
    int c = lane * 2;
    float wc0[6], wc1[6];
    #pragma unroll
    for (int r = 0; r < 6; ++r) { wc0[r] = wrbf[r * 128 + c]; wc1[r] = wrbf[r * 128 + c + 1]; }
    float a0 = 0.f, a1 = 0.f;
    int p0 = rowptr[node], p1 = rowptr[node + 1];
    int p = p0;
    for (; p + 4 <= p1; p += 4) {
        int s0 = slist[p], s1 = slist[p + 1], s2 = slist[p + 2], s3 = slist[p + 3];
        float2 rb[4][3];
        #pragma unroll
        for (int u = 0; u < 4; ++u) {
            const float2* r2 = (const float2*)&rbfS[(size_t)(p + u) * 6];
            rb[u][0] = r2[0]; rb[u][1] = r2[1]; rb[u][2] = r2[2];
        }
        unsigned int xv0 = *(const unsigned int*)&xh[(size_t)s0 * 128 + c];
        unsigned int xv1 = *(const unsigned int*)&xh[(size_t)s1 * 128 + c];
        unsigned int xv2 = *(const unsigned int*)&xh[(size_t)s2 * 128 + c];
        unsigned int xv3 = *(const unsigned int*)&xh[(size_t)s3 * 128 + c];
        #pragma unroll
        for (int u = 0; u < 4; ++u) {
            float e0 = rb[u][0].x * wc0[0] + rb[u][0].y * wc0[1] + rb[u][1].x * wc0[2] +
                       rb[u][1].y * wc0[3] + rb[u][2].x * wc0[4] + rb[u][2].y * wc0[5];
            float e1 = rb[u][0].x * wc1[0] + rb[u][0].y * wc1[1] + rb[u][1].x * wc1[2] +
                       rb[u][1].y * wc1[3] + rb[u][2].x * wc1[4] + rb[u][2].y * wc1[5];
            float2 xf = bf2x2((u == 0) ? xv0 : (u == 1) ? xv1 : (u == 2) ? xv2 : xv3);
            a0 += xf.x * e0;
            a1 += xf.y * e1;
        }
    }
    for (; p < p1; ++p) {
        int src = slist[p];
        const float2* r2 = (const float2*)&rbfS[(size_t)p * 6];
        float2 ra = r2[0], rbx = r2[1], rc = r2[2];
        float e0 = ra.x * wc0[0] + ra.y * wc0[1] + rbx.x * wc0[2] + rbx.y * wc0[3] + rc.x * wc0[4] + rc.y * wc0[5];
        float e1 = ra.x * wc1[0] + ra.y * wc1[1] + rbx.x * wc1[2] + rbx.y * wc1[3] + rc.x * wc1[4] + rc.y * wc1[5];
        float2 xf = bf2x2(*(const unsigned int*)&xh[(size_t)src * 128 + c]);
        a0 += xf.x * e0;
        a1 += xf.y * e1;
    }
    h[(size_t)node * 128 + c] = a0;
    h[(size_t)node * 128 + c + 1] = a1;
}

// ---------------- triplet SV via sorted CSR gather ----------------
__global__ __launch_bounds__(256) void k_trip_sv(const int* __restrict__ rowptrT, const float* __restrict__ dsort,
                                                 const float* __restrict__ asort, const float* __restrict__ sfreq,
                                                 const float* __restrict__ W1, float* __restrict__ SV, int n) {
    int grp = (blockIdx.x * 256 + threadIdx.x) >> 3;
    int k = threadIdx.x & 7;
    if (grp >= n) return;
    float w[24];
    #pragma unroll
    for (int i = 0; i < 24; ++i) w[i] = W1[i * 8 + k];
    float f0 = sfreq[0], f1 = sfreq[1], f2 = sfreq[2], f3 = sfreq[3], f4 = sfreq[4], f5 = sfreq[5];
    float acc = 0.f;
    int p0 = rowptrT[grp], p1 = rowptrT[grp + 1];
    for (int p = p0; p < p1; ++p) {
        float d = dsort[p] * 0.2f;
        float a = asort[p];
        float d2 = d * d, d4 = d2 * d2, d5 = d4 * d;
        float env = __fdividef(1.0f, d) - 28.0f * d5 + 48.0f * d5 * d - 21.0f * d5 * d2;
        float rb0 = env * __sinf(f0 * d), rb1 = env * __sinf(f1 * d), rb2 = env * __sinf(f2 * d);
        float rb3 = env * __sinf(f3 * d), rb4 = env * __sinf(f4 * d), rb5 = env * __sinf(f5 * d);
        float s1 = a, s2 = 1.5f * a * a - 0.5f, s3 = 2.5f * a * a * a - 1.5f * a;
        float u = rb0 * w[0] + rb1 * w[1] + rb2 * w[2] + rb3 * w[3] + rb4 * w[4] + rb5 * w[5];
        u += s1 * (rb0 * w[6] + rb1 * w[7] + rb2 * w[8] + rb3 * w[9] + rb4 * w[10] + rb5 * w[11]);
        u += s2 * (rb0 * w[12] + rb1 * w[13] + rb2 * w[14] + rb3 * w[15] + rb4 * w[16] + rb5 * w[17]);
        u += s3 * (rb0 * w[18] + rb1 * w[19] + rb2 * w[20] + rb3 * w[21] + rb4 * w[22] + rb5 * w[23]);
        acc += siluf(u);
    }
    SV[grp * 8 + k] = acc;
}

// ---------------- fused: extra[c] = sum_k W2[k][c] * (sum_n Tm[n][c]*SV[n][k]) ----------------
__global__ __launch_bounds__(256) void k_extra_fused(const float* __restrict__ Tm, const float* __restrict__ SV,
                                                     const float* __restrict__ W2, float* __restrict__ extra, int n) {
    int tid = threadIdx.x;
    int c = tid & 127, half = tid >> 7;
    float acc[8];
    #pragma unroll
    for (int k = 0; k < 8; ++k) acc[k] = 0.f;
    for (int nn = blockIdx.x * 2 + half; nn < n; nn += gridDim.x * 2) {
        const float4* sv4 = (const float4*)&SV[(size_t)nn * 8];
        float4 s0 = sv4[0], s1 = sv4[1];
        float t = Tm[(size_t)nn * 128 + c];
        acc[0] += t * s0.x; acc[1] += t * s0.y; acc[2] += t * s0.z; acc[3] += t * s0.w;
        acc[4] += t * s1.x; acc[5] += t * s1.y; acc[6] += t * s1.z; acc[7] += t * s1.w;
    }
    float e = 0.f;
    #pragma unroll
    for (int k = 0; k < 8; ++k) e += acc[k] * W2[k * 128 + c];
    __shared__ float red[256];
    red[tid] = e;
    __syncthreads();
    if (tid < 128) atomicAdd(&extra[c], red[tid] + red[tid + 128]);
}

// ---------------- interaction (R8-proven: 2 ch/lane, 4-deep, fdot2, bf16 state) ----------------
__global__ __launch_bounds__(256) void k_interact(const int* __restrict__ rowptr, const int* __restrict__ slist,
                                                  const __half* __restrict__ s8, const float* __restrict__ W2,
                                                  const float* __restrict__ extra,
                                                  const unsigned short* __restrict__ xuph,
                                                  unsigned short* __restrict__ xh, int n) {
    int node = blockIdx.x * 4 + (threadIdx.x >> 6);
    int lane = threadIdx.x & 63;
    if (node >= n) return;
    int c = lane * 2;
    f16x2 w2a[4], w2b[4];
    #pragma unroll
    for (int j = 0; j < 4; ++j) {
        f16x2 wa, wb;
        wa.x = (_Float16)W2[(2 * j) * 128 + c];
        wa.y = (_Float16)W2[(2 * j + 1) * 128 + c];
        wb.x = (_Float16)W2[(2 * j) * 128 + c + 1];
        wb.y = (_Float16)W2[(2 * j + 1) * 128 + c + 1];
        w2a[j] = wa;
        w2b[j] = wb;
    }
    int p0 = rowptr[node], p1 = rowptr[node + 1];
    float cntf = (float)(p1 - p0);
    float a0 = cntf * extra[c], a1 = cntf * extra[c + 1];
    int p = p0;
    for (; p + 4 <= p1; p += 4) {
        int s0 = slist[p], s1 = slist[p + 1], s2 = slist[p + 2], s3 = slist[p + 3];
        uint4 sv[4];
        #pragma unroll
        for (int u = 0; u < 4; ++u) sv[u] = *(const uint4*)(s8 + (size_t)(p + u) * 8);
        unsigned int xv0 = *(const unsigned int*)&xuph[(size_t)s0 * 128 + c];
        unsigned int xv1 = *(const unsigned int*)&xuph[(size_t)s1 * 128 + c];
        unsigned int xv2 = *(const unsigned int*)&xuph[(size_t)s2 * 128 + c];
        unsigned int xv3 = *(const unsigned int*)&xuph[(size_t)s3 * 128 + c];
        #pragma unroll
        for (int u = 0; u < 4; ++u) {
            union { uint4 q; f16x2 h[4]; } s;
            s.q = sv[u];
            float e0 = fdot2f(s.h[0], w2a[0], 0.f);
            e0 = fdot2f(s.h[1], w2a[1], e0);
            e0 = fdot2f(s.h[2], w2a[2], e0);
            e0 = fdot2f(s.h[3], w2a[3], e0);
            float e1 = fdot2f(s.h[0], w2b[0], 0.f);
            e1 = fdot2f(s.h[1], w2b[1], e1);
            e1 = fdot2f(s.h[2], w2b[2], e1);
            e1 = fdot2f(s.h[3], w2b[3], e1);
            float2 xf = bf2x2((u == 0) ? xv0 : (u == 1) ? xv1 : (u == 2) ? xv2 : xv3);
            a0 += xf.x * e0;
            a1 += xf.y * e1;
        }
    }
    for (; p < p1; ++p) {
        int src = slist[p];
        float2 xf = bf2x2(*(const unsigned int*)&xuph[(size_t)src * 128 + c]);
        union { uint4 q; f16x2 h[4]; } s;
        s.q = *(const uint4*)(s8 + (size_t)p * 8);
        float e0 = fdot2f(s.h[0], w2a[0], 0.f);
        e0 = fdot2f(s.h[1], w2a[1], e0);
        e0 = fdot2f(s.h[2], w2a[2], e0);
        e0 = fdot2f(s.h[3], w2a[3], e0);
        float e1 = fdot2f(s.h[0], w2b[0], 0.f);
        e1 = fdot2f(s.h[1], w2b[1], e1);
        e1 = fdot2f(s.h[2], w2b[2], e1);
        e1 = fdot2f(s.h[3], w2b[3], e1);
        a0 += xf.x * e0;
        a1 += xf.y * e1;
    }
    unsigned int cur = *(unsigned int*)&xh[(size_t)node * 128 + c];
    float2 xc = bf2x2(cur);
    *(unsigned int*)&xh[(size_t)node * 128 + c] = f2bf2(xc.x + a0, xc.y + a1);
}

// ---------------- pooling ----------------
__global__ __launch_bounds__(256) void k_pool(const float* __restrict__ P, const int* __restrict__ batch,
                                              float* __restrict__ pool, float* __restrict__ cnt, int n) {
    int i = blockIdx.x * 256 + threadIdx.x;
    int lane = threadIdx.x & 63;
    int b = (i < n) ? batch[i] : -1;
    float p = (i < n) ? P[i] : 0.f;
    int b0 = __shfl(b, 0, 64);
    int b63 = __shfl(b, 63, 64);
    if (b0 == b63 && b0 >= 0) {
        float s = p;
        #pragma unroll
        for (int off = 32; off > 0; off >>= 1) s += __shfl_xor(s, off, 64);
        if (lane == 0) {
            atomicAdd(&pool[b0], s);
            atomicAdd(&cnt[b0], 64.0f);
        }
    } else {
        if (i < n) {
            atomicAdd(&pool[b], p);
            atomicAdd(&cnt[b], 1.0f);
        }
    }
}

__global__ __launch_bounds__(64) void k_final(const float* __restrict__ pool, const float* __restrict__ cnt,
                                              float* __restrict__ out) {
    int g = threadIdx.x;
    if (g < G_) out[g] = __fdividef(pool[g], fmaxf(cnt[g], 1.0f));
}

extern "C" void kernel_launch(void* const* d_in, const int* in_sizes, int n_in,
                              void* d_out, int out_size, void* d_ws, size_t ws_size,
                              hipStream_t stream) {
    (void)in_sizes; (void)n_in; (void)out_size; (void)ws_size;
    const int* z = (const int*)d_in[0];
    const float* dist = (const float*)d_in[1];
    const float* dist_trip = (const float*)d_in[2];
    const float* angle = (const float*)d_in[3];
    const int* edge_index = (const int*)d_in[4];
    const int* triplets = (const int*)d_in[5];
    const int* batch = (const int*)d_in[6];
    const float* atom_table = (const float*)d_in[7];
    const float* rbf_freq = (const float*)d_in[8];
    const float* sbf_freq = (const float*)d_in[9];
    const float* emb_w1 = (const float*)d_in[10];
    const float* emb_b1 = (const float*)d_in[11];
    const float* emb_w2 = (const float*)d_in[12];
    const float* emb_b2 = (const float*)d_in[13];
    const float* iw_rbf1 = (const float*)d_in[14];
    const float* iw_rbf2 = (const float*)d_in[15];
    const float* iw_sbf1 = (const float*)d_in[16];
    const float* iw_sbf2 = (const float*)d_in[17];
    const float* iw_t1 = (const float*)d_in[18];
    const float* iw_t2 = (const float*)d_in[19];
    const float* ib_t2 = (const float*)d_in[20];
    const float* iw_up = (const float*)d_in[21];
    const float* ib_up = (const float*)d_in[22];
    const float* iw_down = (const float*)d_in[23];
    const float* ib_down = (const float*)d_in[24];
    const float* ow_rbf = (const float*)d_in[25];
    const float* ow0 = (const float*)d_in[26];
    const float* ob0 = (const float*)d_in[27];
    const float* ow1 = (const float*)d_in[28];
    const float* ob1 = (const float*)d_in[29];
    const float* ow2 = (const float*)d_in[30];
    const float* ob2 = (const float*)d_in[31];

    const int* erow = edge_index;
    const int* ecol = edge_index + E_;

    // workspace layout
    float* ws = (float*)d_ws;
    float* bufA = ws;                          // N*128
    float* bufB = bufA + (size_t)N_ * H_;      // N*128
    float* P = bufB + (size_t)N_ * H_;         // N
    float* rbfS = P + N_;                      // E*6 (CSR order)
    float* SV = rbfS + (size_t)E_ * 6;         // N*8
    float* extra4 = SV + (size_t)N_ * 8;       // 4*128 (per-block extra)
    float* pool = extra4 + 512;                // G
    float* cnt = pool + G_;                    // G
    int* deg = (int*)(cnt + G_);               // N   (deg, degT adjacent for one memset)
    int* degT = deg + N_;                      // N
    int* rowptr = degT + N_;                   // N+1
    int* cur = rowptr + N_ + 1;                // N
    int* elist = cur + N_;                     // E
    int* slist = elist + E_;                   // E
    int* rowptrT = slist + E_;                 // N+1
    float* dsort = (float*)(rowptrT + N_ + 1); // T
    float* asort = dsort + T_;                 // T
    __half* s8all = (__half*)(asort + T_);     // 4*E*8 halves
    unsigned short* xh = (unsigned short*)(s8all + (size_t)4 * E_ * 8);  // N*128 bf16 node state
    unsigned short* xuph = xh + (size_t)N_ * H_;                          // N*128 bf16 x_up
    unsigned short* Wt = xuph + (size_t)N_ * H_;                          // 27*16384 bf16 weights

    const int EG = (E_ + 255) / 256;
    const int TG = (T_ + 255) / 256;
    const int NG4 = (N_ + 3) / 4;
    const int GEMMG = (N_ + 63) / 64;

    hipMemsetAsync(deg, 0, 2 * N_ * sizeof(int), stream);                  // deg + degT
    hipMemsetAsync(extra4, 0, (512 + 2 * G_) * sizeof(float), stream);     // extra4 + pool + cnt
    k_wprep<<<27 * 8, 256, 0, stream>>>(emb_w2, iw_down, iw_t1, iw_t2, iw_up, ow0, ow1, Wt);
    k_count<<<EG, 256, 0, stream>>>(ecol, deg, E_);
    k_countT<<<TG, 256, 0, stream>>>(triplets, degT, T_);
    k_scan<<<1, 1024, 0, stream>>>(deg, rowptr, cur, N_);
    k_fill<<<EG, 256, 0, stream>>>(ecol, erow, cur, elist, slist, E_);
    k_scan<<<1, 1024, 0, stream>>>(degT, rowptrT, cur, N_);
    k_fillT<<<TG, 256, 0, stream>>>(triplets, cur, dist_trip, angle, dsort, asort, T_);

    k_rbfS<<<EG, 256, 0, stream>>>(elist, dist, rbf_freq, rbfS, E_);
    k_s8h_all<<<EG, 256, 0, stream>>>(rbfS, iw_rbf1, s8all, E_);
    k_init_x<<<(N_ * 16 + 255) / 256, 256, 0, stream>>>(atom_table, z, xh, N_);

    // embedding: xh = bf16( xh + SS @ w2 + deg*b2 )
    k_embS<<<NG4, 256, 0, stream>>>(rowptr, rbfS, emb_w1, emb_b1, bufA, N_);
    k_gemm_mfma<2, false, true, false, false, true, 0><<<GEMMG, 256, 0, stream>>>(
        bufA, Wt, emb_b2, deg, nullptr, xh, nullptr, nullptr, nullptr, N_);

    auto out_block = [&](int k, bool first) {
        k_out_gather<<<NG4, 256, 0, stream>>>(rowptr, slist, rbfS, xh,
                                              ow_rbf + (size_t)k * 6 * 128, bufA, N_);
        k_gemm_mfma<1, true, false, false, true, false, 0><<<GEMMG, 256, 0, stream>>>(
            bufA, Wt + (size_t)(17 + k) * 16384, ob0 + k * 128, nullptr, bufB, nullptr,
            nullptr, nullptr, nullptr, N_);
        if (first)
            k_gemm_mfma<1, true, false, false, false, false, 1><<<GEMMG, 256, 0, stream>>>(
                bufB, Wt + (size_t)(22 + k) * 16384, ob1 + k * 128, nullptr, nullptr, nullptr,
                ow2 + k * 128, ob2 + k, P, N_);
        else
            k_gemm_mfma<1, true, false, false, false, false, 2><<<GEMMG, 256, 0, stream>>>(
                bufB, Wt + (size_t)(22 + k) * 16384, ob1 + k * 128, nullptr, nullptr, nullptr,
                ow2 + k * 128, ob2 + k, P, N_);
    };

    out_block(0, true);

    for (int b = 0; b < 4; ++b) {
        // t-chain
        k_gemm_mfma<1, false, false, true, true, false, 0><<<GEMMG, 256, 0, stream>>>(
            xh, Wt + (size_t)(1 + b) * 16384, ib_down + b * 128, nullptr, bufA, nullptr,
            nullptr, nullptr, nullptr, N_);
        k_gemm_mfma<0, true, false, false, true, false, 0><<<GEMMG, 256, 0, stream>>>(
            bufA, Wt + (size_t)(5 + b) * 16384, nullptr, nullptr, bufB, nullptr,
            nullptr, nullptr, nullptr, N_);
        k_gemm_mfma<1, false, false, false, true, false, 0><<<GEMMG, 256, 0, stream>>>(
            bufB, Wt + (size_t)(9 + b) * 16384, ib_t2 + b * 128, nullptr, bufA, nullptr,
            nullptr, nullptr, nullptr, N_);
        k_trip_sv<<<(N_ * 8 + 255) / 256, 256, 0, stream>>>(rowptrT, dsort, asort, sbf_freq,
                                                            iw_sbf1 + (size_t)b * 192, SV, N_);
        k_extra_fused<<<256, 256, 0, stream>>>(bufA, SV, iw_sbf2 + (size_t)b * 1024, extra4 + b * 128, N_);
        // x_up: bf16 in, bf16 out
        k_gemm_mfma<1, false, false, true, false, true, 0><<<GEMMG, 256, 0, stream>>>(
            xh, Wt + (size_t)(13 + b) * 16384, ib_up + b * 128, nullptr, nullptr, xuph,
            nullptr, nullptr, nullptr, N_);
        k_interact<<<NG4, 256, 0, stream>>>(rowptr, slist, s8all + (size_t)b * E_ * 8,
                                            iw_rbf2 + (size_t)b * 1024, extra4 + b * 128,
                                            xuph, xh, N_);
        out_block(b + 1, false);
    }

    k_pool<<<(N_ + 255) / 256, 256, 0, stream>>>(P, batch, pool, cnt, N_);
    k_final<<<1, 64, 0, stream>>>(pool, cnt, (float*)d_out);
}

// Round 12
// 1914.759 us; speedup vs baseline: 1.3669x; 1.0800x over previous
//
#include <hip/hip_runtime.h>
#include <hip/hip_fp16.h>

#define N_ 50000
#define E_ 800000
#define T_ 800000
#define G_ 64
#define H_ 128

typedef __attribute__((ext_vector_type(8))) short bf16x8;
typedef __attribute__((ext_vector_type(4))) float f32x4;
typedef _Float16 f16x2 __attribute__((ext_vector_type(2)));

__device__ __forceinline__ float siluf(float v) {
    return __fdividef(v, 1.0f + __expf(-v));
}

// bf16 helpers
__device__ __forceinline__ unsigned short f2bf(float f) {
    unsigned int u = __float_as_uint(f);
    u += 0x7fffu + ((u >> 16) & 1u);
    return (unsigned short)(u >> 16);
}
__device__ __forceinline__ unsigned int f2bf2(float a, float b) {
    return (unsigned int)f2bf(a) | ((unsigned int)f2bf(b) << 16);
}
__device__ __forceinline__ float bf2f(unsigned short h) {
    return __uint_as_float(((unsigned int)h) << 16);
}
__device__ __forceinline__ float2 bf2x2(unsigned int p) {
    return make_float2(__uint_as_float(p << 16), __uint_as_float(p & 0xffff0000u));
}
__device__ __forceinline__ float fdot2f(f16x2 a, f16x2 b, float c) {
    return __builtin_amdgcn_fdot2(a, b, c, false);
}

// ---------------- CSR build ----------------
__global__ __launch_bounds__(256) void k_count(const int* __restrict__ col, int* deg, int n) {
    int e = blockIdx.x * 256 + threadIdx.x;
    if (e < n) atomicAdd(&deg[col[e]], 1);
}

__global__ __launch_bounds__(256) void k_countT(const int* __restrict__ trip, int* deg, int n) {
    int t = blockIdx.x * 256 + threadIdx.x;
    if (t < n) atomicAdd(&deg[trip[3 * t + 1]], 1);
}

__global__ __launch_bounds__(1024) void k_scan(const int* __restrict__ deg, int* rowptr, int* cur, int n) {
    __shared__ int wsum[16];
    __shared__ int s_carry;
    int tid = threadIdx.x, lane = tid & 63, w = tid >> 6;
    if (tid == 0) s_carry = 0;
    __syncthreads();
    for (int base = 0; base < n; base += 1024) {
        int i = base + tid;
        int v = (i < n) ? deg[i] : 0;
        int incl = v;
        #pragma unroll
        for (int s = 1; s < 64; s <<= 1) {
            int t = __shfl_up(incl, (unsigned)s, 64);
            if (lane >= s) incl += t;
        }
        if (lane == 63) wsum[w] = incl;
        __syncthreads();
        int carry0 = s_carry;
        int wexcl = 0;
        for (int j = 0; j < w; ++j) wexcl += wsum[j];
        int excl = carry0 + wexcl + (incl - v);
        if (i < n) { rowptr[i] = excl; cur[i] = excl; }
        __syncthreads();
        if (tid == 1023) s_carry = carry0 + wexcl + incl;
        __syncthreads();
    }
    if (tid == 0) rowptr[n] = s_carry;
}

__global__ __launch_bounds__(256) void k_fill(const int* __restrict__ col, const int* __restrict__ row,
                                              int* cur, int* elist, int* slist, int n) {
    int e = blockIdx.x * 256 + threadIdx.x;
    if (e < n) {
        int pos = atomicAdd(&cur[col[e]], 1);
        elist[pos] = e;
        slist[pos] = row[e];
    }
}

__global__ __launch_bounds__(256) void k_fillT(const int* __restrict__ trip, int* cur,
                                               const float* __restrict__ dist_trip, const float* __restrict__ angle,
                                               float* __restrict__ dsort, float* __restrict__ asort, int n) {
    int t = blockIdx.x * 256 + threadIdx.x;
    if (t < n) {
        int pos = atomicAdd(&cur[trip[3 * t + 1]], 1);
        dsort[pos] = dist_trip[t];
        asort[pos] = angle[t];
    }
}

// ---------------- weight prep: fp32 (k,n) -> bf16 transposed (n,k), 27 matrices ----------------
__global__ __launch_bounds__(256) void k_wprep(const float* __restrict__ emb_w2, const float* __restrict__ iw_down,
                                               const float* __restrict__ iw_t1, const float* __restrict__ iw_t2,
                                               const float* __restrict__ iw_up, const float* __restrict__ ow0,
                                               const float* __restrict__ ow1, unsigned short* __restrict__ Wt) {
    int mat = blockIdx.x >> 3;
    int part = blockIdx.x & 7;
    const float* src;
    if (mat == 0) src = emb_w2;
    else if (mat < 5) src = iw_down + (size_t)(mat - 1) * 16384;
    else if (mat < 9) src = iw_t1 + (size_t)(mat - 5) * 16384;
    else if (mat < 13) src = iw_t2 + (size_t)(mat - 9) * 16384;
    else if (mat < 17) src = iw_up + (size_t)(mat - 13) * 16384;
    else if (mat < 22) src = ow0 + (size_t)(mat - 17) * 16384;
    else src = ow1 + (size_t)(mat - 22) * 16384;
    unsigned short* dst = Wt + (size_t)mat * 16384;
    int base = part * 2048;
    for (int i = base + threadIdx.x; i < base + 2048; i += 256) {
        int k = i >> 7, n = i & 127;
        dst[n * 128 + k] = f2bf(src[i]);
    }
}

// ---------------- rbf in CSR (segment) order ----------------
__global__ __launch_bounds__(256) void k_rbfS(const int* __restrict__ elist, const float* __restrict__ dist,
                                              const float* __restrict__ freq, float* __restrict__ rbfS, int n) {
    int p = blockIdx.x * 256 + threadIdx.x;
    if (p >= n) return;
    int e = elist[p];
    float d = dist[e] * 0.2f;
    float d2 = d * d, d4 = d2 * d2, d5 = d4 * d;
    float env = __fdividef(1.0f, d) - 28.0f * d5 + 48.0f * d5 * d - 21.0f * d5 * d2;
    #pragma unroll
    for (int r = 0; r < 6; ++r) rbfS[p * 6 + r] = env * __sinf(freq[r] * d);
}

// ---------------- edge factors for ALL 4 blocks ----------------
__global__ __launch_bounds__(256) void k_s8h_all(const float* __restrict__ rbfS, const float* __restrict__ iw_rbf1,
                                                 __half* __restrict__ s8all, int n) {
    __shared__ float W1s[4][48];
    int tid = threadIdx.x;
    if (tid < 192) W1s[tid / 48][tid % 48] = iw_rbf1[tid];
    __syncthreads();
    int p = blockIdx.x * 256 + tid;
    if (p >= n) return;
    const float2* r2 = (const float2*)&rbfS[(size_t)p * 6];
    float2 ra = r2[0], rbx = r2[1], rc = r2[2];
    float rb[6] = {ra.x, ra.y, rbx.x, rbx.y, rc.x, rc.y};
    #pragma unroll
    for (int b = 0; b < 4; ++b) {
        __half out[8];
        #pragma unroll
        for (int k = 0; k < 8; ++k) {
            float u = 0.f;
            #pragma unroll
            for (int r = 0; r < 6; ++r) u += rb[r] * W1s[b][r * 8 + k];
            out[k] = __float2half(siluf(u));
        }
        *(uint4*)&s8all[((size_t)b * n + p) * 8] = *(uint4*)out;
    }
}

// ---------------- xh = bf16(atom_table[z]) ----------------
__global__ __launch_bounds__(256) void k_init_x(const float* __restrict__ atab, const int* __restrict__ z,
                                                unsigned short* __restrict__ xh, int n) {
    int t = blockIdx.x * 256 + threadIdx.x;
    if (t >= n * 16) return;
    int node = t >> 4, q = t & 15;
    const float4* a4 = (const float4*)atab;
    float4 v0 = a4[(size_t)z[node] * 32 + q * 2];
    float4 v1 = a4[(size_t)z[node] * 32 + q * 2 + 1];
    uint4 pk;
    pk.x = f2bf2(v0.x, v0.y);
    pk.y = f2bf2(v0.z, v0.w);
    pk.z = f2bf2(v1.x, v1.y);
    pk.w = f2bf2(v1.z, v1.w);
    ((uint4*)xh)[t] = pk;
}

// ---------------- SS[n] = sum_{e in n} silu(rbf_e @ w1 + b1) ----------------
__global__ __launch_bounds__(256) void k_embS(const int* __restrict__ rowptr, const float* __restrict__ rbfS,
                                              const float* __restrict__ w1, const float* __restrict__ b1,
                                              float* __restrict__ SS, int n) {
    int node = blockIdx.x * 4 + (threadIdx.x >> 6);
    int lane = threadIdx.x & 63;
    if (node >= n) return;
    int c = lane * 2;
    float wc0[6], wc1[6];
    #pragma unroll
    for (int r = 0; r < 6; ++r) { wc0[r] = w1[r * 128 + c]; wc1[r] = w1[r * 128 + c + 1]; }
    float bb0 = b1[c], bb1 = b1[c + 1];
    float a0 = 0.f, a1 = 0.f;
    int p0 = rowptr[node], p1 = rowptr[node + 1];
    for (int p = p0; p < p1; ++p) {
        const float2* r2 = (const float2*)&rbfS[(size_t)p * 6];
        float2 ra = r2[0], rbx = r2[1], rc = r2[2];
        float u0 = bb0 + ra.x * wc0[0] + ra.y * wc0[1] + rbx.x * wc0[2] + rbx.y * wc0[3] + rc.x * wc0[4] + rc.y * wc0[5];
        float u1 = bb1 + ra.x * wc1[0] + ra.y * wc1[1] + rbx.x * wc1[2] + rbx.y * wc1[3] + rc.x * wc1[4] + rc.y * wc1[5];
        a0 += siluf(u0);
        a1 += siluf(u1);
    }
    SS[node * 128 + c] = a0;
    SS[node * 128 + c + 1] = a1;
}

// ---------------- MFMA GEMM (emb / up paths) ----------------
template <int BIAS_MODE, bool SILU, bool ACCBF, bool ABF, bool WF32, bool WBF>
__global__ __launch_bounds__(256, 4) void k_gemm_mfma(const void* __restrict__ Ap,
                                                      const unsigned short* __restrict__ Wt,
                                                      const float* __restrict__ bias, const int* __restrict__ deg,
                                                      float* __restrict__ C, unsigned short* __restrict__ Ch, int M) {
    int tid = threadIdx.x;
    int wave = tid >> 6, lane = tid & 63;
    int m15 = lane & 15, quad = lane >> 4;
    int row0 = blockIdx.x * 64 + wave * 16;
    int arow = row0 + m15;
    if (arow > M - 1) arow = M - 1;

    f32x4 acc[8];
    #pragma unroll
    for (int nt = 0; nt < 8; ++nt) acc[nt] = (f32x4){0.f, 0.f, 0.f, 0.f};

    #pragma unroll
    for (int kt = 0; kt < 4; ++kt) {
        int ks = kt * 32 + quad * 8;
        bf16x8 av;
        if constexpr (ABF) {
            av = *(const bf16x8*)((const unsigned short*)Ap + (size_t)arow * 128 + ks);
        } else {
            const float* Arow = (const float*)Ap + (size_t)arow * 128;
            float4 a0 = *(const float4*)(Arow + ks);
            float4 a1 = *(const float4*)(Arow + ks + 4);
            union { bf16x8 v; unsigned int u[4]; } af;
            af.u[0] = f2bf2(a0.x, a0.y);
            af.u[1] = f2bf2(a0.z, a0.w);
            af.u[2] = f2bf2(a1.x, a1.y);
            af.u[3] = f2bf2(a1.z, a1.w);
            av = af.v;
        }
        #pragma unroll
        for (int nt = 0; nt < 8; ++nt) {
            bf16x8 bf = *(const bf16x8*)(Wt + (size_t)(nt * 16 + m15) * 128 + ks);
            acc[nt] = __builtin_amdgcn_mfma_f32_16x16x32_bf16(av, bf, acc[nt], 0, 0, 0);
        }
    }

    #pragma unroll
    for (int nt = 0; nt < 8; ++nt) {
        int col = nt * 16 + m15;
        float bc = 0.f;
        if constexpr (BIAS_MODE != 0) bc = bias[col];
        #pragma unroll
        for (int reg = 0; reg < 4; ++reg) {
            int row = row0 + quad * 4 + reg;
            if (row < M) {
                float v = acc[nt][reg];
                if constexpr (BIAS_MODE == 1) v += bc;
                if constexpr (BIAS_MODE == 2) v += bc * (float)deg[row];
                if constexpr (SILU) v = siluf(v);
                if constexpr (ACCBF) v += bf2f(Ch[(size_t)row * 128 + col]);
                if constexpr (WF32) C[(size_t)row * 128 + col] = v;
                if constexpr (WBF) Ch[(size_t)row * 128 + col] = f2bf(v);
            }
        }
    }
}

// ---------------- fused out-block MLP: P (+)= silu(silu(hB@W0+b0)@W1+b1) . ow2 + ob2 ----------------
// LDS transpose between GEMMs (C-layout -> A-layout), wave-private 16x136 bf16 tiles.
template <int PACC>
__global__ __launch_bounds__(256, 4) void k_out_mlp(const unsigned short* __restrict__ hB,
                                                    const unsigned short* __restrict__ W0t, const float* __restrict__ b0,
                                                    const unsigned short* __restrict__ W1t, const float* __restrict__ b1,
                                                    const float* __restrict__ w2col, const float* __restrict__ ob2p,
                                                    float* __restrict__ Pout, int M) {
    __shared__ unsigned short lds[4][16 * 136];
    int tid = threadIdx.x;
    int wave = tid >> 6, lane = tid & 63;
    int m15 = lane & 15, quad = lane >> 4;
    int row0 = blockIdx.x * 64 + wave * 16;
    int arow = row0 + m15;
    if (arow > M - 1) arow = M - 1;
    unsigned short* L = lds[wave];

    f32x4 acc[8];
    #pragma unroll
    for (int nt = 0; nt < 8; ++nt) acc[nt] = (f32x4){0.f, 0.f, 0.f, 0.f};
    #pragma unroll
    for (int kt = 0; kt < 4; ++kt) {
        int ks = kt * 32 + quad * 8;
        bf16x8 av = *(const bf16x8*)(hB + (size_t)arow * 128 + ks);
        #pragma unroll
        for (int nt = 0; nt < 8; ++nt) {
            bf16x8 bf = *(const bf16x8*)(W0t + (size_t)(nt * 16 + m15) * 128 + ks);
            acc[nt] = __builtin_amdgcn_mfma_f32_16x16x32_bf16(av, bf, acc[nt], 0, 0, 0);
        }
    }
    #pragma unroll
    for (int nt = 0; nt < 8; ++nt) {
        int col = nt * 16 + m15;
        float bc = b0[col];
        #pragma unroll
        for (int reg = 0; reg < 4; ++reg)
            L[(quad * 4 + reg) * 136 + col] = f2bf(siluf(acc[nt][reg] + bc));
    }
    __syncthreads();

    #pragma unroll
    for (int nt = 0; nt < 8; ++nt) acc[nt] = (f32x4){0.f, 0.f, 0.f, 0.f};
    #pragma unroll
    for (int kt = 0; kt < 4; ++kt) {
        int ks = kt * 32 + quad * 8;
        bf16x8 av = *(const bf16x8*)(L + m15 * 136 + ks);
        #pragma unroll
        for (int nt = 0; nt < 8; ++nt) {
            bf16x8 bf = *(const bf16x8*)(W1t + (size_t)(nt * 16 + m15) * 128 + ks);
            acc[nt] = __builtin_amdgcn_mfma_f32_16x16x32_bf16(av, bf, acc[nt], 0, 0, 0);
        }
    }
    float w2c[8], pp[4];
    #pragma unroll
    for (int nt = 0; nt < 8; ++nt) w2c[nt] = w2col[nt * 16 + m15];
    #pragma unroll
    for (int reg = 0; reg < 4; ++reg) pp[reg] = 0.f;
    #pragma unroll
    for (int nt = 0; nt < 8; ++nt) {
        float bc = b1[nt * 16 + m15];
        #pragma unroll
        for (int reg = 0; reg < 4; ++reg)
            pp[reg] += siluf(acc[nt][reg] + bc) * w2c[nt];
    }
    #pragma unroll
    for (int reg = 0; reg < 4; ++reg) {
        float s = pp[reg];
        s += __shfl_xor(s, 1, 64);
        s += __shfl_xor(s, 2, 64);
        s += __shfl_xor(s, 4, 64);
        s += __shfl_xor(s, 8, 64);
        if (m15 == 0) {
            int row = row0 + quad * 4 + reg;
            if (row < M) {
                float r = s + ob2p[0];
                if constexpr (PACC == 2) r += Pout[row];
                Pout[row] = r;
            }
        }
    }
}

// ---------------- fused t-chain: Tm = silu(xh@Wd + bd)@Wt1 ... -> (@Wt2 + bt2), fp32 out ----------------
__global__ __launch_bounds__(256, 4) void k_t_mlp(const unsigned short* __restrict__ xh,
                                                  const unsigned short* __restrict__ Wd, const float* __restrict__ bd,
                                                  const unsigned short* __restrict__ Wt1,
                                                  const unsigned short* __restrict__ Wt2, const float* __restrict__ bt2,
                                                  float* __restrict__ Tm, int M) {
    __shared__ unsigned short lds[4][16 * 136];
    int tid = threadIdx.x;
    int wave = tid >> 6, lane = tid & 63;
    int m15 = lane & 15, quad = lane >> 4;
    int row0 = blockIdx.x * 64 + wave * 16;
    int arow = row0 + m15;
    if (arow > M - 1) arow = M - 1;
    unsigned short* L = lds[wave];

    f32x4 acc[8];
    // phase 1: xh @ Wd + bd  (no act) -> LDS
    #pragma unroll
    for (int nt = 0; nt < 8; ++nt) acc[nt] = (f32x4){0.f, 0.f, 0.f, 0.f};
    #pragma unroll
    for (int kt = 0; kt < 4; ++kt) {
        int ks = kt * 32 + quad * 8;
        bf16x8 av = *(const bf16x8*)(xh + (size_t)arow * 128 + ks);
        #pragma unroll
        for (int nt = 0; nt < 8; ++nt) {
            bf16x8 bf = *(const bf16x8*)(Wd + (size_t)(nt * 16 + m15) * 128 + ks);
            acc[nt] = __builtin_amdgcn_mfma_f32_16x16x32_bf16(av, bf, acc[nt], 0, 0, 0);
        }
    }
    #pragma unroll
    for (int nt = 0; nt < 8; ++nt) {
        int col = nt * 16 + m15;
        float bc = bd[col];
        #pragma unroll
        for (int reg = 0; reg < 4; ++reg)
            L[(quad * 4 + reg) * 136 + col] = f2bf(acc[nt][reg] + bc);
    }
    __syncthreads();

    // phase 2: silu(LDS @ Wt1) -> LDS
    #pragma unroll
    for (int nt = 0; nt < 8; ++nt) acc[nt] = (f32x4){0.f, 0.f, 0.f, 0.f};
    #pragma unroll
    for (int kt = 0; kt < 4; ++kt) {
        int ks = kt * 32 + quad * 8;
        bf16x8 av = *(const bf16x8*)(L + m15 * 136 + ks);
        #pragma unroll
        for (int nt = 0; nt < 8; ++nt) {
            bf16x8 bf = *(const bf16x8*)(Wt1 + (size_t)(nt * 16 + m15) * 128 + ks);
            acc[nt] = __builtin_amdgcn_mfma_f32_16x16x32_bf16(av, bf, acc[nt], 0, 0, 0);
        }
    }
    __syncthreads();
    #pragma unroll
    for (int nt = 0; nt < 8; ++nt) {
        int col = nt * 16 + m15;
        #pragma unroll
        for (int reg = 0; reg < 4; ++reg)
            L[(quad * 4 + reg) * 136 + col] = f2bf(siluf(acc[nt][reg]));
    }
    __syncthreads();

    // phase 3: LDS @ Wt2 + bt2 -> fp32 Tm
    #pragma unroll
    for (int nt = 0; nt < 8; ++nt) acc[nt] = (f32x4){0.f, 0.f, 0.f, 0.f};
    #pragma unroll
    for (int kt = 0; kt < 4; ++kt) {
        int ks = kt * 32 + quad * 8;
        bf16x8 av = *(const bf16x8*)(L + m15 * 136 + ks);
        #pragma unroll
        for (int nt = 0; nt < 8; ++nt) {
            bf16x8 bf = *(const bf16x8*)(Wt2 + (size_t)(nt * 16 + m15) * 128 + ks);
            acc[nt] = __builtin_amdgcn_mfma_f32_16x16x32_bf16(av, bf, acc[nt], 0, 0, 0);
        }
    }
    #pragma unroll
    for (int nt = 0; nt < 8; ++nt) {
        int col = nt * 16 + m15;
        float bc = bt2[col];
        #pragma unroll
        for (int reg = 0; reg < 4; ++reg) {
            int row = row0 + quad * 4 + reg;
            if (row < M) Tm[(size_t)row * 128 + col] = acc[nt][reg] + bc;
        }
    }
}

// ---------------- out_block gather -> bf16 h ----------------
__global__ __launch_bounds__(256) void k_out_gather(const int* __restrict__ rowptr, const int* __restrict__ slist,
                                                    const float* __restrict__ rbfS,
                                                    const unsigned short* __restrict__ xh,
                                                    const float* __restrict__ wrbf,
                                                    unsigned short* __restrict__ hB, int n) {
    int node = blockIdx.x * 4 + (threadIdx.x >> 6);
    int lane = threadIdx.x & 63;
    if (node >= n) return;
    int c = lane * 2;
    float wc0[6], wc1[6];
    #pragma unroll
    for (int r = 0; r < 6; ++r) { wc0[r] = wrbf[r * 128 + c]; wc1[r] = wrbf[r * 128 + c + 1]; }
    float a0 = 0.f, a1 = 0.f;
    int p0 = rowptr[node], p1 = rowptr[node + 1];
    int p = p0;
    for (; p + 4 <= p1; p += 4) {
        int s0 = slist[p], s1 = slist[p + 1], s2 = slist[p + 2], s3 = slist[p + 3];
        float2 rb[4][3];
        #pragma unroll
        for (int u = 0; u < 4; ++u) {
            const float2* r2 = (const float2*)&rbfS[(size_t)(p + u) * 6];
            rb[u][0] = r2[0]; rb[u][1] = r2[1]; rb[u][2] = r2[2];
        }
        unsigned int xv0 = *(const unsigned int*)&xh[(size_t)s0 * 128 + c];
        unsigned int xv1 = *(const unsigned int*)&xh[(size_t)s1 * 128 + c];
        unsigned int xv2 = *(const unsigned int*)&xh[(size_t)s2 * 128 + c];
        unsigned int xv3 = *(const unsigned int*)&xh[(size_t)s3 * 128 + c];
        #pragma unroll
        for (int u = 0; u < 4; ++u) {
            float e0 = rb[u][0].x * wc0[0] + rb[u][0].y * wc0[1] + rb[u][1].x * wc0[2] +
                       rb[u][1].y * wc0[3] + rb[u][2].x * wc0[4] + rb[u][2].y * wc0[5];
            float e1 = rb[u][0].x * wc1[0] + rb[u][0].y * wc1[1] + rb[u][1].x * wc1[2] +
                       rb[u][1].y * wc1[3] + rb[u][2].x * wc1[4] + rb[u][2].y * wc1[5];
            float2 xf = bf2x2((u == 0) ? xv0 : (u == 1) ? xv1 : (u == 2) ? xv2 : xv3);
            a0 += xf.x * e0;
            a1 += xf.y * e1;
        }
    }
    for (; p < p1; ++p) {
        int src = slist[p];
        const float2* r2 = (const float2*)&rbfS[(size_t)p * 6];
        float2 ra = r2[0], rbx = r2[1], rc = r2[2];
        float e0 = ra.x * wc0[0] + ra.y * wc0[1] + rbx.x * wc0[2] + rbx.y * wc0[3] + rc.x * wc0[4] + rc.y * wc0[5];
        float e1 = ra.x * wc1[0] + ra.y * wc1[1] + rbx.x * wc1[2] + rbx.y * wc1[3] + rc.x * wc1[4] + rc.y * wc1[5];
        float2 xf = bf2x2(*(const unsigned int*)&xh[(size_t)src * 128 + c]);
        a0 += xf.x * e0;
        a1 += xf.y * e1;
    }
    *(unsigned int*)&hB[(size_t)node * 128 + c] = f2bf2(a0, a1);
}

// ---------------- triplet SV via sorted CSR gather ----------------
__global__ __launch_bounds__(256) void k_trip_sv(const int* __restrict__ rowptrT, const float* __restrict__ dsort,
                                                 const float* __restrict__ asort, const float* __restrict__ sfreq,
                                                 const float* __restrict__ W1, float* __restrict__ SV, int n) {
    int grp = (blockIdx.x * 256 + threadIdx.x) >> 3;
    int k = threadIdx.x & 7;
    if (grp >= n) return;
    float w[24];
    #pragma unroll
    for (int i = 0; i < 24; ++i) w[i] = W1[i * 8 + k];
    float f0 = sfreq[0], f1 = sfreq[1], f2 = sfreq[2], f3 = sfreq[3], f4 = sfreq[4], f5 = sfreq[5];
    float acc = 0.f;
    int p0 = rowptrT[grp], p1 = rowptrT[grp + 1];
    for (int p = p0; p < p1; ++p) {
        float d = dsort[p] * 0.2f;
        float a = asort[p];
        float d2 = d * d, d4 = d2 * d2, d5 = d4 * d;
        float env = __fdividef(1.0f, d) - 28.0f * d5 + 48.0f * d5 * d - 21.0f * d5 * d2;
        float rb0 = env * __sinf(f0 * d), rb1 = env * __sinf(f1 * d), rb2 = env * __sinf(f2 * d);
        float rb3 = env * __sinf(f3 * d), rb4 = env * __sinf(f4 * d), rb5 = env * __sinf(f5 * d);
        float s1 = a, s2 = 1.5f * a * a - 0.5f, s3 = 2.5f * a * a * a - 1.5f * a;
        float u = rb0 * w[0] + rb1 * w[1] + rb2 * w[2] + rb3 * w[3] + rb4 * w[4] + rb5 * w[5];
        u += s1 * (rb0 * w[6] + rb1 * w[7] + rb2 * w[8] + rb3 * w[9] + rb4 * w[10] + rb5 * w[11]);
        u += s2 * (rb0 * w[12] + rb1 * w[13] + rb2 * w[14] + rb3 * w[15] + rb4 * w[16] + rb5 * w[17]);
        u += s3 * (rb0 * w[18] + rb1 * w[19] + rb2 * w[20] + rb3 * w[21] + rb4 * w[22] + rb5 * w[23]);
        acc += siluf(u);
    }
    SV[grp * 8 + k] = acc;
}

// ---------------- fused: extra[c] = sum_k W2[k][c] * (sum_n Tm[n][c]*SV[n][k]) ----------------
__global__ __launch_bounds__(256) void k_extra_fused(const float* __restrict__ Tm, const float* __restrict__ SV,
                                                     const float* __restrict__ W2, float* __restrict__ extra, int n) {
    int tid = threadIdx.x;
    int c = tid & 127, half = tid >> 7;
    float acc[8];
    #pragma unroll
    for (int k = 0; k < 8; ++k) acc[k] = 0.f;
    for (int nn = blockIdx.x * 2 + half; nn < n; nn += gridDim.x * 2) {
        const float4* sv4 = (const float4*)&SV[(size_t)nn * 8];
        float4 s0 = sv4[0], s1 = sv4[1];
        float t = Tm[(size_t)nn * 128 + c];
        acc[0] += t * s0.x; acc[1] += t * s0.y; acc[2] += t * s0.z; acc[3] += t * s0.w;
        acc[4] += t * s1.x; acc[5] += t * s1.y; acc[6] += t * s1.z; acc[7] += t * s1.w;
    }
    float e = 0.f;
    #pragma unroll
    for (int k = 0; k < 8; ++k) e += acc[k] * W2[k * 128 + c];
    __shared__ float red[256];
    red[tid] = e;
    __syncthreads();
    if (tid < 128) atomicAdd(&extra[c], red[tid] + red[tid + 128]);
}

// ---------------- interaction ----------------
__global__ __launch_bounds__(256) void k_interact(const int* __restrict__ rowptr, const int* __restrict__ slist,
                                                  const __half* __restrict__ s8, const float* __restrict__ W2,
                                                  const float* __restrict__ extra,
                                                  const unsigned short* __restrict__ xuph,
                                                  unsigned short* __restrict__ xh, int n) {
    int node = blockIdx.x * 4 + (threadIdx.x >> 6);
    int lane = threadIdx.x & 63;
    if (node >= n) return;
    int c = lane * 2;
    f16x2 w2a[4], w2b[4];
    #pragma unroll
    for (int j = 0; j < 4; ++j) {
        f16x2 wa, wb;
        wa.x = (_Float16)W2[(2 * j) * 128 + c];
        wa.y = (_Float16)W2[(2 * j + 1) * 128 + c];
        wb.x = (_Float16)W2[(2 * j) * 128 + c + 1];
        wb.y = (_Float16)W2[(2 * j + 1) * 128 + c + 1];
        w2a[j] = wa;
        w2b[j] = wb;
    }
    int p0 = rowptr[node], p1 = rowptr[node + 1];
    float cntf = (float)(p1 - p0);
    float a0 = cntf * extra[c], a1 = cntf * extra[c + 1];
    int p = p0;
    for (; p + 4 <= p1; p += 4) {
        int s0 = slist[p], s1 = slist[p + 1], s2 = slist[p + 2], s3 = slist[p + 3];
        uint4 sv[4];
        #pragma unroll
        for (int u = 0; u < 4; ++u) sv[u] = *(const uint4*)(s8 + (size_t)(p + u) * 8);
        unsigned int xv0 = *(const unsigned int*)&xuph[(size_t)s0 * 128 + c];
        unsigned int xv1 = *(const unsigned int*)&xuph[(size_t)s1 * 128 + c];
        unsigned int xv2 = *(const unsigned int*)&xuph[(size_t)s2 * 128 + c];
        unsigned int xv3 = *(const unsigned int*)&xuph[(size_t)s3 * 128 + c];
        #pragma unroll
        for (int u = 0; u < 4; ++u) {
            union { uint4 q; f16x2 h[4]; } s;
            s.q = sv[u];
            float e0 = fdot2f(s.h[0], w2a[0], 0.f);
            e0 = fdot2f(s.h[1], w2a[1], e0);
            e0 = fdot2f(s.h[2], w2a[2], e0);
            e0 = fdot2f(s.h[3], w2a[3], e0);
            float e1 = fdot2f(s.h[0], w2b[0], 0.f);
            e1 = fdot2f(s.h[1], w2b[1], e1);
            e1 = fdot2f(s.h[2], w2b[2], e1);
            e1 = fdot2f(s.h[3], w2b[3], e1);
            float2 xf = bf2x2((u == 0) ? xv0 : (u == 1) ? xv1 : (u == 2) ? xv2 : xv3);
            a0 += xf.x * e0;
            a1 += xf.y * e1;
        }
    }
    for (; p < p1; ++p) {
        int src = slist[p];
        float2 xf = bf2x2(*(const unsigned int*)&xuph[(size_t)src * 128 + c]);
        union { uint4 q; f16x2 h[4]; } s;
        s.q = *(const uint4*)(s8 + (size_t)p * 8);
        float e0 = fdot2f(s.h[0], w2a[0], 0.f);
        e0 = fdot2f(s.h[1], w2a[1], e0);
        e0 = fdot2f(s.h[2], w2a[2], e0);
        e0 = fdot2f(s.h[3], w2a[3], e0);
        float e1 = fdot2f(s.h[0], w2b[0], 0.f);
        e1 = fdot2f(s.h[1], w2b[1], e1);
        e1 = fdot2f(s.h[2], w2b[2], e1);
        e1 = fdot2f(s.h[3], w2b[3], e1);
        a0 += xf.x * e0;
        a1 += xf.y * e1;
    }
    unsigned int cur = *(unsigned int*)&xh[(size_t)node * 128 + c];
    float2 xc = bf2x2(cur);
    *(unsigned int*)&xh[(size_t)node * 128 + c] = f2bf2(xc.x + a0, xc.y + a1);
}

// ---------------- pooling ----------------
__global__ __launch_bounds__(256) void k_pool(const float* __restrict__ P, const int* __restrict__ batch,
                                              float* __restrict__ pool, float* __restrict__ cnt, int n) {
    int i = blockIdx.x * 256 + threadIdx.x;
    int lane = threadIdx.x & 63;
    int b = (i < n) ? batch[i] : -1;
    float p = (i < n) ? P[i] : 0.f;
    int b0 = __shfl(b, 0, 64);
    int b63 = __shfl(b, 63, 64);
    if (b0 == b63 && b0 >= 0) {
        float s = p;
        #pragma unroll
        for (int off = 32; off > 0; off >>= 1) s += __shfl_xor(s, off, 64);
        if (lane == 0) {
            atomicAdd(&pool[b0], s);
            atomicAdd(&cnt[b0], 64.0f);
        }
    } else {
        if (i < n) {
            atomicAdd(&pool[b], p);
            atomicAdd(&cnt[b], 1.0f);
        }
    }
}

__global__ __launch_bounds__(64) void k_final(const float* __restrict__ pool, const float* __restrict__ cnt,
                                              float* __restrict__ out) {
    int g = threadIdx.x;
    if (g < G_) out[g] = __fdividef(pool[g], fmaxf(cnt[g], 1.0f));
}

extern "C" void kernel_launch(void* const* d_in, const int* in_sizes, int n_in,
                              void* d_out, int out_size, void* d_ws, size_t ws_size,
                              hipStream_t stream) {
    (void)in_sizes; (void)n_in; (void)out_size; (void)ws_size;
    const int* z = (const int*)d_in[0];
    const float* dist = (const float*)d_in[1];
    const float* dist_trip = (const float*)d_in[2];
    const float* angle = (const float*)d_in[3];
    const int* edge_index = (const int*)d_in[4];
    const int* triplets = (const int*)d_in[5];
    const int* batch = (const int*)d_in[6];
    const float* atom_table = (const float*)d_in[7];
    const float* rbf_freq = (const float*)d_in[8];
    const float* sbf_freq = (const float*)d_in[9];
    const float* emb_w1 = (const float*)d_in[10];
    const float* emb_b1 = (const float*)d_in[11];
    const float* emb_w2 = (const float*)d_in[12];
    const float* emb_b2 = (const float*)d_in[13];
    const float* iw_rbf1 = (const float*)d_in[14];
    const float* iw_rbf2 = (const float*)d_in[15];
    const float* iw_sbf1 = (const float*)d_in[16];
    const float* iw_sbf2 = (const float*)d_in[17];
    const float* iw_t1 = (const float*)d_in[18];
    const float* iw_t2 = (const float*)d_in[19];
    const float* ib_t2 = (const float*)d_in[20];
    const float* iw_up = (const float*)d_in[21];
    const float* ib_up = (const float*)d_in[22];
    const float* iw_down = (const float*)d_in[23];
    const float* ib_down = (const float*)d_in[24];
    const float* ow_rbf = (const float*)d_in[25];
    const float* ow0 = (const float*)d_in[26];
    const float* ob0 = (const float*)d_in[27];
    const float* ow1 = (const float*)d_in[28];
    const float* ob1 = (const float*)d_in[29];
    const float* ow2 = (const float*)d_in[30];
    const float* ob2 = (const float*)d_in[31];

    const int* erow = edge_index;
    const int* ecol = edge_index + E_;

    // workspace layout
    float* ws = (float*)d_ws;
    float* bufA = ws;                          // N*128 (embS out; Tm)
    float* bufB = bufA + (size_t)N_ * H_;      // N*128 (only hB bf16 lives here now)
    float* P = bufB + (size_t)N_ * H_;         // N
    float* rbfS = P + N_;                      // E*6 (CSR order)
    float* SV = rbfS + (size_t)E_ * 6;         // N*8
    float* extra4 = SV + (size_t)N_ * 8;       // 4*128
    float* pool = extra4 + 512;                // G
    float* cnt = pool + G_;                    // G
    int* deg = (int*)(cnt + G_);               // N
    int* degT = deg + N_;                      // N
    int* rowptr = degT + N_;                   // N+1
    int* cur = rowptr + N_ + 1;                // N
    int* elist = cur + N_;                     // E
    int* slist = elist + E_;                   // E
    int* rowptrT = slist + E_;                 // N+1
    float* dsort = (float*)(rowptrT + N_ + 1); // T
    float* asort = dsort + T_;                 // T
    __half* s8all = (__half*)(asort + T_);     // 4*E*8 halves
    unsigned short* xh = (unsigned short*)(s8all + (size_t)4 * E_ * 8);  // N*128 bf16 node state
    unsigned short* xuph = xh + (size_t)N_ * H_;                          // N*128 bf16 x_up
    unsigned short* Wt = xuph + (size_t)N_ * H_;                          // 27*16384 bf16 weights
    unsigned short* hB = (unsigned short*)bufB;                           // N*128 bf16 gather out

    const int EG = (E_ + 255) / 256;
    const int TG = (T_ + 255) / 256;
    const int NG4 = (N_ + 3) / 4;
    const int GEMMG = (N_ + 63) / 64;

    hipMemsetAsync(deg, 0, 2 * N_ * sizeof(int), stream);
    hipMemsetAsync(extra4, 0, (512 + 2 * G_) * sizeof(float), stream);
    k_wprep<<<27 * 8, 256, 0, stream>>>(emb_w2, iw_down, iw_t1, iw_t2, iw_up, ow0, ow1, Wt);
    k_count<<<EG, 256, 0, stream>>>(ecol, deg, E_);
    k_countT<<<TG, 256, 0, stream>>>(triplets, degT, T_);
    k_scan<<<1, 1024, 0, stream>>>(deg, rowptr, cur, N_);
    k_fill<<<EG, 256, 0, stream>>>(ecol, erow, cur, elist, slist, E_);
    k_scan<<<1, 1024, 0, stream>>>(degT, rowptrT, cur, N_);
    k_fillT<<<TG, 256, 0, stream>>>(triplets, cur, dist_trip, angle, dsort, asort, T_);

    k_rbfS<<<EG, 256, 0, stream>>>(elist, dist, rbf_freq, rbfS, E_);
    k_s8h_all<<<EG, 256, 0, stream>>>(rbfS, iw_rbf1, s8all, E_);
    k_init_x<<<(N_ * 16 + 255) / 256, 256, 0, stream>>>(atom_table, z, xh, N_);

    // embedding: xh = bf16( xh + SS @ w2 + deg*b2 )
    k_embS<<<NG4, 256, 0, stream>>>(rowptr, rbfS, emb_w1, emb_b1, bufA, N_);
    k_gemm_mfma<2, false, true, false, false, true><<<GEMMG, 256, 0, stream>>>(
        bufA, Wt, emb_b2, deg, nullptr, xh, N_);

    auto out_block = [&](int k, bool first) {
        k_out_gather<<<NG4, 256, 0, stream>>>(rowptr, slist, rbfS, xh,
                                              ow_rbf + (size_t)k * 6 * 128, hB, N_);
        if (first)
            k_out_mlp<1><<<GEMMG, 256, 0, stream>>>(hB, Wt + (size_t)(17 + k) * 16384, ob0 + k * 128,
                                                    Wt + (size_t)(22 + k) * 16384, ob1 + k * 128,
                                                    ow2 + k * 128, ob2 + k, P, N_);
        else
            k_out_mlp<2><<<GEMMG, 256, 0, stream>>>(hB, Wt + (size_t)(17 + k) * 16384, ob0 + k * 128,
                                                    Wt + (size_t)(22 + k) * 16384, ob1 + k * 128,
                                                    ow2 + k * 128, ob2 + k, P, N_);
    };

    out_block(0, true);

    for (int b = 0; b < 4; ++b) {
        // fused t-chain -> Tm (bufA, fp32)
        k_t_mlp<<<GEMMG, 256, 0, stream>>>(xh, Wt + (size_t)(1 + b) * 16384, ib_down + b * 128,
                                           Wt + (size_t)(5 + b) * 16384,
                                           Wt + (size_t)(9 + b) * 16384, ib_t2 + b * 128, bufA, N_);
        k_trip_sv<<<(N_ * 8 + 255) / 256, 256, 0, stream>>>(rowptrT, dsort, asort, sbf_freq,
                                                            iw_sbf1 + (size_t)b * 192, SV, N_);
        k_extra_fused<<<256, 256, 0, stream>>>(bufA, SV, iw_sbf2 + (size_t)b * 1024, extra4 + b * 128, N_);
        // x_up: bf16 in, bf16 out
        k_gemm_mfma<1, false, false, true, false, true><<<GEMMG, 256, 0, stream>>>(
            xh, Wt + (size_t)(13 + b) * 16384, ib_up + b * 128, nullptr, nullptr, xuph, N_);
        k_interact<<<NG4, 256, 0, stream>>>(rowptr, slist, s8all + (size_t)b * E_ * 8,
                                            iw_rbf2 + (size_t)b * 1024, extra4 + b * 128,
                                            xuph, xh, N_);
        out_block(b + 1, false);
    }

    k_pool<<<(N_ + 255) / 256, 256, 0, stream>>>(P, batch, pool, cnt, N_);
    k_final<<<1, 64, 0, stream>>>(pool, cnt, (float*)d_out);
}

// Round 13
// 1750.007 us; speedup vs baseline: 1.4956x; 1.0941x over previous
//
#include <hip/hip_runtime.h>
#include <hip/hip_fp16.h>

#define N_ 50000
#define E_ 800000
#define T_ 800000
#define G_ 64
#define H_ 128

typedef __attribute__((ext_vector_type(8))) short bf16x8;
typedef __attribute__((ext_vector_type(4))) float f32x4;
typedef _Float16 f16x2 __attribute__((ext_vector_type(2)));

__device__ __forceinline__ float siluf(float v) {
    return __fdividef(v, 1.0f + __expf(-v));
}

__device__ __forceinline__ unsigned short f2bf(float f) {
    unsigned int u = __float_as_uint(f);
    u += 0x7fffu + ((u >> 16) & 1u);
    return (unsigned short)(u >> 16);
}
__device__ __forceinline__ unsigned int f2bf2(float a, float b) {
    return (unsigned int)f2bf(a) | ((unsigned int)f2bf(b) << 16);
}
__device__ __forceinline__ float bf2f(unsigned short h) {
    return __uint_as_float(((unsigned int)h) << 16);
}
__device__ __forceinline__ float2 bf2x2(unsigned int p) {
    return make_float2(__uint_as_float(p << 16), __uint_as_float(p & 0xffff0000u));
}
__device__ __forceinline__ float fdot2f(f16x2 a, f16x2 b, float c) {
    return __builtin_amdgcn_fdot2(a, b, c, false);
}

// ---------------- CSR build (merged) ----------------
__global__ __launch_bounds__(256) void k_count2(const int* __restrict__ ecol, const int* __restrict__ trip,
                                                int* degE, int* degT) {
    int i = blockIdx.x * 256 + threadIdx.x;
    if (i < E_) atomicAdd(&degE[ecol[i]], 1);
    int t = i - E_;
    if (t >= 0 && t < T_) atomicAdd(&degT[trip[3 * t + 1]], 1);
}

// gridDim=2: block 0 scans edge-CSR, block 1 triplet-CSR
__global__ __launch_bounds__(1024) void k_scan2(const int* __restrict__ degE, int* rowptrE, int* curE,
                                                const int* __restrict__ degT, int* rowptrT, int* curT, int n) {
    const int* deg = (blockIdx.x == 0) ? degE : degT;
    int* rowptr = (blockIdx.x == 0) ? rowptrE : rowptrT;
    int* cur = (blockIdx.x == 0) ? curE : curT;
    __shared__ int wsum[16];
    __shared__ int s_carry;
    int tid = threadIdx.x, lane = tid & 63, w = tid >> 6;
    if (tid == 0) s_carry = 0;
    __syncthreads();
    for (int base = 0; base < n; base += 1024) {
        int i = base + tid;
        int v = (i < n) ? deg[i] : 0;
        int incl = v;
        #pragma unroll
        for (int s = 1; s < 64; s <<= 1) {
            int t = __shfl_up(incl, (unsigned)s, 64);
            if (lane >= s) incl += t;
        }
        if (lane == 63) wsum[w] = incl;
        __syncthreads();
        int carry0 = s_carry;
        int wexcl = 0;
        for (int j = 0; j < w; ++j) wexcl += wsum[j];
        int excl = carry0 + wexcl + (incl - v);
        if (i < n) { rowptr[i] = excl; cur[i] = excl; }
        __syncthreads();
        if (tid == 1023) s_carry = carry0 + wexcl + incl;
        __syncthreads();
    }
    if (tid == 0) rowptr[n] = s_carry;
}

__global__ __launch_bounds__(256) void k_fill2(const int* __restrict__ ecol, const int* __restrict__ erow,
                                               int* curE, int* elist, int* slist,
                                               const int* __restrict__ trip, int* curT,
                                               const float* __restrict__ dist_trip, const float* __restrict__ angle,
                                               float* dsort, float* asort) {
    int i = blockIdx.x * 256 + threadIdx.x;
    if (i < E_) {
        int pos = atomicAdd(&curE[ecol[i]], 1);
        elist[pos] = i;
        slist[pos] = erow[i];
    }
    int t = i - E_;
    if (t >= 0 && t < T_) {
        int pos = atomicAdd(&curT[trip[3 * t + 1]], 1);
        dsort[pos] = dist_trip[t];
        asort[pos] = angle[t];
    }
}

// ---------------- weight prep ----------------
__global__ __launch_bounds__(256) void k_wprep(const float* __restrict__ emb_w2, const float* __restrict__ iw_down,
                                               const float* __restrict__ iw_t1, const float* __restrict__ iw_t2,
                                               const float* __restrict__ iw_up, const float* __restrict__ ow0,
                                               const float* __restrict__ ow1, unsigned short* __restrict__ Wt) {
    int mat = blockIdx.x >> 3;
    int part = blockIdx.x & 7;
    const float* src;
    if (mat == 0) src = emb_w2;
    else if (mat < 5) src = iw_down + (size_t)(mat - 1) * 16384;
    else if (mat < 9) src = iw_t1 + (size_t)(mat - 5) * 16384;
    else if (mat < 13) src = iw_t2 + (size_t)(mat - 9) * 16384;
    else if (mat < 17) src = iw_up + (size_t)(mat - 13) * 16384;
    else if (mat < 22) src = ow0 + (size_t)(mat - 17) * 16384;
    else src = ow1 + (size_t)(mat - 22) * 16384;
    unsigned short* dst = Wt + (size_t)mat * 16384;
    int base = part * 2048;
    for (int i = base + threadIdx.x; i < base + 2048; i += 256) {
        int k = i >> 7, n = i & 127;
        dst[n * 128 + k] = f2bf(src[i]);
    }
}

// ---------------- geometry: rbfS (fp32, CSR order) + s8 factors for all 4 blocks ----------------
__global__ __launch_bounds__(256) void k_geom(const int* __restrict__ elist, const float* __restrict__ dist,
                                              const float* __restrict__ freq, const float* __restrict__ iw_rbf1,
                                              float* __restrict__ rbfS, __half* __restrict__ s8all, int n) {
    __shared__ float W1s[4][48];
    int tid = threadIdx.x;
    if (tid < 192) W1s[tid / 48][tid % 48] = iw_rbf1[tid];
    __syncthreads();
    int p = blockIdx.x * 256 + tid;
    if (p >= n) return;
    int e = elist[p];
    float d = dist[e] * 0.2f;
    float d2 = d * d, d4 = d2 * d2, d5 = d4 * d;
    float env = __fdividef(1.0f, d) - 28.0f * d5 + 48.0f * d5 * d - 21.0f * d5 * d2;
    float rb[6];
    #pragma unroll
    for (int r = 0; r < 6; ++r) {
        rb[r] = env * __sinf(freq[r] * d);
        rbfS[(size_t)p * 6 + r] = rb[r];
    }
    #pragma unroll
    for (int b = 0; b < 4; ++b) {
        __half out[8];
        #pragma unroll
        for (int k = 0; k < 8; ++k) {
            float u = 0.f;
            #pragma unroll
            for (int r = 0; r < 6; ++r) u += rb[r] * W1s[b][r * 8 + k];
            out[k] = __float2half(siluf(u));
        }
        *(uint4*)&s8all[((size_t)b * n + p) * 8] = *(uint4*)out;
    }
}

// ---------------- triplet basis (fp16, segment order): basis[p][s*6+r] = rbf_t[r]*sph[s] ----------------
__global__ __launch_bounds__(256) void k_basis(const float* __restrict__ dsort, const float* __restrict__ asort,
                                               const float* __restrict__ sfreq, __half* __restrict__ basis, int n) {
    int t = blockIdx.x * 256 + threadIdx.x;
    if (t >= n) return;
    float d = dsort[t] * 0.2f;
    float a = asort[t];
    float d2 = d * d, d4 = d2 * d2, d5 = d4 * d;
    float env = __fdividef(1.0f, d) - 28.0f * d5 + 48.0f * d5 * d - 21.0f * d5 * d2;
    float rb[6];
    #pragma unroll
    for (int r = 0; r < 6; ++r) rb[r] = env * __sinf(sfreq[r] * d);
    float sph[4];
    sph[0] = 1.0f; sph[1] = a; sph[2] = 1.5f * a * a - 0.5f; sph[3] = 2.5f * a * a * a - 1.5f * a;
    __half out[24];
    #pragma unroll
    for (int s = 0; s < 4; ++s)
        #pragma unroll
        for (int r = 0; r < 6; ++r) out[s * 6 + r] = __float2half(sph[s] * rb[r]);
    uint4* dst = (uint4*)(basis + (size_t)t * 24);
    dst[0] = ((uint4*)out)[0];
    dst[1] = ((uint4*)out)[1];
    dst[2] = ((uint4*)out)[2];
}

// ---------------- SV for ALL 4 blocks in one pass: 32 lanes/node (4 blk x 8 ch) ----------------
__global__ __launch_bounds__(256) void k_sv4(const int* __restrict__ rowptrT, const __half* __restrict__ basis,
                                             const float* __restrict__ iw_sbf1, float* __restrict__ SV4, int n) {
    int wave = threadIdx.x >> 6, lane = threadIdx.x & 63;
    int node = blockIdx.x * 8 + wave * 2 + (lane >> 5);
    int sub = lane & 31;
    int blk = sub >> 3, k = sub & 7;
    if (node >= n) return;
    const float* W1 = iw_sbf1 + blk * 192;
    f16x2 w[12];
    #pragma unroll
    for (int j = 0; j < 12; ++j) {
        f16x2 t;
        t.x = (_Float16)W1[(2 * j) * 8 + k];
        t.y = (_Float16)W1[(2 * j + 1) * 8 + k];
        w[j] = t;
    }
    float acc = 0.f;
    int p0 = rowptrT[node], p1 = rowptrT[node + 1];
    for (int p = p0; p < p1; ++p) {
        union { uint4 q[3]; f16x2 h[12]; } bs;
        const uint4* bp = (const uint4*)(basis + (size_t)p * 24);
        bs.q[0] = bp[0]; bs.q[1] = bp[1]; bs.q[2] = bp[2];
        float u = 0.f;
        #pragma unroll
        for (int j = 0; j < 12; ++j) u = fdot2f(bs.h[j], w[j], u);
        acc += siluf(u);
    }
    SV4[((size_t)blk * n + node) * 8 + k] = acc;
}

// ---------------- xh = bf16(atom_table[z]) ----------------
__global__ __launch_bounds__(256) void k_init_x(const float* __restrict__ atab, const int* __restrict__ z,
                                                unsigned short* __restrict__ xh, int n) {
    int t = blockIdx.x * 256 + threadIdx.x;
    if (t >= n * 16) return;
    int node = t >> 4, q = t & 15;
    const float4* a4 = (const float4*)atab;
    float4 v0 = a4[(size_t)z[node] * 32 + q * 2];
    float4 v1 = a4[(size_t)z[node] * 32 + q * 2 + 1];
    uint4 pk;
    pk.x = f2bf2(v0.x, v0.y);
    pk.y = f2bf2(v0.z, v0.w);
    pk.z = f2bf2(v1.x, v1.y);
    pk.w = f2bf2(v1.z, v1.w);
    ((uint4*)xh)[t] = pk;
}

// ---------------- SS[n] = sum_{e in n} silu(rbf_e @ w1 + b1) ----------------
__global__ __launch_bounds__(256) void k_embS(const int* __restrict__ rowptr, const float* __restrict__ rbfS,
                                              const float* __restrict__ w1, const float* __restrict__ b1,
                                              float* __restrict__ SS, int n) {
    int node = blockIdx.x * 4 + (threadIdx.x >> 6);
    int lane = threadIdx.x & 63;
    if (node >= n) return;
    int c = lane * 2;
    float wc0[6], wc1[6];
    #pragma unroll
    for (int r = 0; r < 6; ++r) { wc0[r] = w1[r * 128 + c]; wc1[r] = w1[r * 128 + c + 1]; }
    float bb0 = b1[c], bb1 = b1[c + 1];
    float a0 = 0.f, a1 = 0.f;
    int p0 = rowptr[node], p1 = rowptr[node + 1];
    for (int p = p0; p < p1; ++p) {
        const float2* r2 = (const float2*)&rbfS[(size_t)p * 6];
        float2 ra = r2[0], rbx = r2[1], rc = r2[2];
        float u0 = bb0 + ra.x * wc0[0] + ra.y * wc0[1] + rbx.x * wc0[2] + rbx.y * wc0[3] + rc.x * wc0[4] + rc.y * wc0[5];
        float u1 = bb1 + ra.x * wc1[0] + ra.y * wc1[1] + rbx.x * wc1[2] + rbx.y * wc1[3] + rc.x * wc1[4] + rc.y * wc1[5];
        a0 += siluf(u0);
        a1 += siluf(u1);
    }
    SS[node * 128 + c] = a0;
    SS[node * 128 + c + 1] = a1;
}

// ---------------- MFMA GEMM (embedding path) ----------------
template <int BIAS_MODE, bool SILU, bool ACCBF, bool ABF, bool WF32, bool WBF>
__global__ __launch_bounds__(256, 4) void k_gemm_mfma(const void* __restrict__ Ap,
                                                      const unsigned short* __restrict__ Wt,
                                                      const float* __restrict__ bias, const int* __restrict__ deg,
                                                      float* __restrict__ C, unsigned short* __restrict__ Ch, int M) {
    int tid = threadIdx.x;
    int wave = tid >> 6, lane = tid & 63;
    int m15 = lane & 15, quad = lane >> 4;
    int row0 = blockIdx.x * 64 + wave * 16;
    int arow = row0 + m15;
    if (arow > M - 1) arow = M - 1;

    f32x4 acc[8];
    #pragma unroll
    for (int nt = 0; nt < 8; ++nt) acc[nt] = (f32x4){0.f, 0.f, 0.f, 0.f};

    #pragma unroll
    for (int kt = 0; kt < 4; ++kt) {
        int ks = kt * 32 + quad * 8;
        bf16x8 av;
        if constexpr (ABF) {
            av = *(const bf16x8*)((const unsigned short*)Ap + (size_t)arow * 128 + ks);
        } else {
            const float* Arow = (const float*)Ap + (size_t)arow * 128;
            float4 a0 = *(const float4*)(Arow + ks);
            float4 a1 = *(const float4*)(Arow + ks + 4);
            union { bf16x8 v; unsigned int u[4]; } af;
            af.u[0] = f2bf2(a0.x, a0.y);
            af.u[1] = f2bf2(a0.z, a0.w);
            af.u[2] = f2bf2(a1.x, a1.y);
            af.u[3] = f2bf2(a1.z, a1.w);
            av = af.v;
        }
        #pragma unroll
        for (int nt = 0; nt < 8; ++nt) {
            bf16x8 bf = *(const bf16x8*)(Wt + (size_t)(nt * 16 + m15) * 128 + ks);
            acc[nt] = __builtin_amdgcn_mfma_f32_16x16x32_bf16(av, bf, acc[nt], 0, 0, 0);
        }
    }

    #pragma unroll
    for (int nt = 0; nt < 8; ++nt) {
        int col = nt * 16 + m15;
        float bc = 0.f;
        if constexpr (BIAS_MODE != 0) bc = bias[col];
        #pragma unroll
        for (int reg = 0; reg < 4; ++reg) {
            int row = row0 + quad * 4 + reg;
            if (row < M) {
                float v = acc[nt][reg];
                if constexpr (BIAS_MODE == 1) v += bc;
                if constexpr (BIAS_MODE == 2) v += bc * (float)deg[row];
                if constexpr (SILU) v = siluf(v);
                if constexpr (ACCBF) v += bf2f(Ch[(size_t)row * 128 + col]);
                if constexpr (WF32) C[(size_t)row * 128 + col] = v;
                if constexpr (WBF) Ch[(size_t)row * 128 + col] = f2bf(v);
            }
        }
    }
}

// ---------------- fused out-block MLP ----------------
template <int PACC>
__global__ __launch_bounds__(256, 4) void k_out_mlp(const unsigned short* __restrict__ hB,
                                                    const unsigned short* __restrict__ W0t, const float* __restrict__ b0,
                                                    const unsigned short* __restrict__ W1t, const float* __restrict__ b1,
                                                    const float* __restrict__ w2col, const float* __restrict__ ob2p,
                                                    float* __restrict__ Pout, int M) {
    __shared__ unsigned short lds[4][16 * 136];
    int tid = threadIdx.x;
    int wave = tid >> 6, lane = tid & 63;
    int m15 = lane & 15, quad = lane >> 4;
    int row0 = blockIdx.x * 64 + wave * 16;
    int arow = row0 + m15;
    if (arow > M - 1) arow = M - 1;
    unsigned short* L = lds[wave];

    f32x4 acc[8];
    #pragma unroll
    for (int nt = 0; nt < 8; ++nt) acc[nt] = (f32x4){0.f, 0.f, 0.f, 0.f};
    #pragma unroll
    for (int kt = 0; kt < 4; ++kt) {
        int ks = kt * 32 + quad * 8;
        bf16x8 av = *(const bf16x8*)(hB + (size_t)arow * 128 + ks);
        #pragma unroll
        for (int nt = 0; nt < 8; ++nt) {
            bf16x8 bf = *(const bf16x8*)(W0t + (size_t)(nt * 16 + m15) * 128 + ks);
            acc[nt] = __builtin_amdgcn_mfma_f32_16x16x32_bf16(av, bf, acc[nt], 0, 0, 0);
        }
    }
    #pragma unroll
    for (int nt = 0; nt < 8; ++nt) {
        int col = nt * 16 + m15;
        float bc = b0[col];
        #pragma unroll
        for (int reg = 0; reg < 4; ++reg)
            L[(quad * 4 + reg) * 136 + col] = f2bf(siluf(acc[nt][reg] + bc));
    }
    __syncthreads();

    #pragma unroll
    for (int nt = 0; nt < 8; ++nt) acc[nt] = (f32x4){0.f, 0.f, 0.f, 0.f};
    #pragma unroll
    for (int kt = 0; kt < 4; ++kt) {
        int ks = kt * 32 + quad * 8;
        bf16x8 av = *(const bf16x8*)(L + m15 * 136 + ks);
        #pragma unroll
        for (int nt = 0; nt < 8; ++nt) {
            bf16x8 bf = *(const bf16x8*)(W1t + (size_t)(nt * 16 + m15) * 128 + ks);
            acc[nt] = __builtin_amdgcn_mfma_f32_16x16x32_bf16(av, bf, acc[nt], 0, 0, 0);
        }
    }
    float w2c[8], pp[4];
    #pragma unroll
    for (int nt = 0; nt < 8; ++nt) w2c[nt] = w2col[nt * 16 + m15];
    #pragma unroll
    for (int reg = 0; reg < 4; ++reg) pp[reg] = 0.f;
    #pragma unroll
    for (int nt = 0; nt < 8; ++nt) {
        float bc = b1[nt * 16 + m15];
        #pragma unroll
        for (int reg = 0; reg < 4; ++reg)
            pp[reg] += siluf(acc[nt][reg] + bc) * w2c[nt];
    }
    #pragma unroll
    for (int reg = 0; reg < 4; ++reg) {
        float s = pp[reg];
        s += __shfl_xor(s, 1, 64);
        s += __shfl_xor(s, 2, 64);
        s += __shfl_xor(s, 4, 64);
        s += __shfl_xor(s, 8, 64);
        if (m15 == 0) {
            int row = row0 + quad * 4 + reg;
            if (row < M) {
                float r = s + ob2p[0];
                if constexpr (PACC == 2) r += Pout[row];
                Pout[row] = r;
            }
        }
    }
}

// ---------------- fused per-block MLP: xuph = xh@Wup+bup ; Tm = (silu((xh@Wd+bd)@Wt1))@Wt2+bt2 ----------------
__global__ __launch_bounds__(256, 4) void k_block_mlp(const unsigned short* __restrict__ xh,
                                                      const unsigned short* __restrict__ Wd, const float* __restrict__ bd,
                                                      const unsigned short* __restrict__ Wt1,
                                                      const unsigned short* __restrict__ Wt2, const float* __restrict__ bt2,
                                                      const unsigned short* __restrict__ Wup, const float* __restrict__ bup,
                                                      float* __restrict__ Tm, unsigned short* __restrict__ xuph, int M) {
    __shared__ unsigned short lds[4][16 * 136];
    int tid = threadIdx.x;
    int wave = tid >> 6, lane = tid & 63;
    int m15 = lane & 15, quad = lane >> 4;
    int row0 = blockIdx.x * 64 + wave * 16;
    int arow = row0 + m15;
    if (arow > M - 1) arow = M - 1;
    unsigned short* L = lds[wave];

    f32x4 accD[8], accU[8];
    #pragma unroll
    for (int nt = 0; nt < 8; ++nt) { accD[nt] = (f32x4){0.f, 0.f, 0.f, 0.f}; accU[nt] = (f32x4){0.f, 0.f, 0.f, 0.f}; }
    #pragma unroll
    for (int kt = 0; kt < 4; ++kt) {
        int ks = kt * 32 + quad * 8;
        bf16x8 av = *(const bf16x8*)(xh + (size_t)arow * 128 + ks);
        #pragma unroll
        for (int nt = 0; nt < 8; ++nt) {
            bf16x8 bd_ = *(const bf16x8*)(Wd + (size_t)(nt * 16 + m15) * 128 + ks);
            accD[nt] = __builtin_amdgcn_mfma_f32_16x16x32_bf16(av, bd_, accD[nt], 0, 0, 0);
            bf16x8 bu_ = *(const bf16x8*)(Wup + (size_t)(nt * 16 + m15) * 128 + ks);
            accU[nt] = __builtin_amdgcn_mfma_f32_16x16x32_bf16(av, bu_, accU[nt], 0, 0, 0);
        }
    }
    #pragma unroll
    for (int nt = 0; nt < 8; ++nt) {
        int col = nt * 16 + m15;
        float bcu = bup[col], bcd = bd[col];
        #pragma unroll
        for (int reg = 0; reg < 4; ++reg) {
            int row = row0 + quad * 4 + reg;
            if (row < M) xuph[(size_t)row * 128 + col] = f2bf(accU[nt][reg] + bcu);
            L[(quad * 4 + reg) * 136 + col] = f2bf(accD[nt][reg] + bcd);
        }
    }
    __syncthreads();

    // phase 2: silu(LDS @ Wt1) -> LDS
    #pragma unroll
    for (int nt = 0; nt < 8; ++nt) accD[nt] = (f32x4){0.f, 0.f, 0.f, 0.f};
    #pragma unroll
    for (int kt = 0; kt < 4; ++kt) {
        int ks = kt * 32 + quad * 8;
        bf16x8 av = *(const bf16x8*)(L + m15 * 136 + ks);
        #pragma unroll
        for (int nt = 0; nt < 8; ++nt) {
            bf16x8 bf = *(const bf16x8*)(Wt1 + (size_t)(nt * 16 + m15) * 128 + ks);
            accD[nt] = __builtin_amdgcn_mfma_f32_16x16x32_bf16(av, bf, accD[nt], 0, 0, 0);
        }
    }
    __syncthreads();
    #pragma unroll
    for (int nt = 0; nt < 8; ++nt) {
        int col = nt * 16 + m15;
        #pragma unroll
        for (int reg = 0; reg < 4; ++reg)
            L[(quad * 4 + reg) * 136 + col] = f2bf(siluf(accD[nt][reg]));
    }
    __syncthreads();

    // phase 3: LDS @ Wt2 + bt2 -> fp32 Tm
    #pragma unroll
    for (int nt = 0; nt < 8; ++nt) accD[nt] = (f32x4){0.f, 0.f, 0.f, 0.f};
    #pragma unroll
    for (int kt = 0; kt < 4; ++kt) {
        int ks = kt * 32 + quad * 8;
        bf16x8 av = *(const bf16x8*)(L + m15 * 136 + ks);
        #pragma unroll
        for (int nt = 0; nt < 8; ++nt) {
            bf16x8 bf = *(const bf16x8*)(Wt2 + (size_t)(nt * 16 + m15) * 128 + ks);
            accD[nt] = __builtin_amdgcn_mfma_f32_16x16x32_bf16(av, bf, accD[nt], 0, 0, 0);
        }
    }
    #pragma unroll
    for (int nt = 0; nt < 8; ++nt) {
        int col = nt * 16 + m15;
        float bc = bt2[col];
        #pragma unroll
        for (int reg = 0; reg < 4; ++reg) {
            int row = row0 + quad * 4 + reg;
            if (row < M) Tm[(size_t)row * 128 + col] = accD[nt][reg] + bc;
        }
    }
}

// ---------------- out_block gather -> bf16 h ----------------
__global__ __launch_bounds__(256) void k_out_gather(const int* __restrict__ rowptr, const int* __restrict__ slist,
                                                    const float* __restrict__ rbfS,
                                                    const unsigned short* __restrict__ xh,
                                                    const float* __restrict__ wrbf,
                                                    unsigned short* __restrict__ hB, int n) {
    int node = blockIdx.x * 4 + (threadIdx.x >> 6);
    int lane = threadIdx.x & 63;
    if (node >= n) return;
    int c = lane * 2;
    float wc0[6], wc1[6];
    #pragma unroll
    for (int r = 0; r < 6; ++r) { wc0[r] = wrbf[r * 128 + c]; wc1[r] = wrbf[r * 128 + c + 1]; }
    float a0 = 0.f, a1 = 0.f;
    int p0 = rowptr[node], p1 = rowptr[node + 1];
    int p = p0;
    for (; p + 4 <= p1; p += 4) {
        int s0 = slist[p], s1 = slist[p + 1], s2 = slist[p + 2], s3 = slist[p + 3];
        float2 rb[4][3];
        #pragma unroll
        for (int u = 0; u < 4; ++u) {
            const float2* r2 = (const float2*)&rbfS[(size_t)(p + u) * 6];
            rb[u][0] = r2[0]; rb[u][1] = r2[1]; rb[u][2] = r2[2];
        }
        unsigned int xv0 = *(const unsigned int*)&xh[(size_t)s0 * 128 + c];
        unsigned int xv1 = *(const unsigned int*)&xh[(size_t)s1 * 128 + c];
        unsigned int xv2 = *(const unsigned int*)&xh[(size_t)s2 * 128 + c];
        unsigned int xv3 = *(const unsigned int*)&xh[(size_t)s3 * 128 + c];
        #pragma unroll
        for (int u = 0; u < 4; ++u) {
            float e0 = rb[u][0].x * wc0[0] + rb[u][0].y * wc0[1] + rb[u][1].x * wc0[2] +
                       rb[u][1].y * wc0[3] + rb[u][2].x * wc0[4] + rb[u][2].y * wc0[5];
            float e1 = rb[u][0].x * wc1[0] + rb[u][0].y * wc1[1] + rb[u][1].x * wc1[2] +
                       rb[u][1].y * wc1[3] + rb[u][2].x * wc1[4] + rb[u][2].y * wc1[5];
            float2 xf = bf2x2((u == 0) ? xv0 : (u == 1) ? xv1 : (u == 2) ? xv2 : xv3);
            a0 += xf.x * e0;
            a1 += xf.y * e1;
        }
    }
    for (; p < p1; ++p) {
        int src = slist[p];
        const float2* r2 = (const float2*)&rbfS[(size_t)p * 6];
        float2 ra = r2[0], rbx = r2[1], rc = r2[2];
        float e0 = ra.x * wc0[0] + ra.y * wc0[1] + rbx.x * wc0[2] + rbx.y * wc0[3] + rc.x * wc0[4] + rc.y * wc0[5];
        float e1 = ra.x * wc1[0] + ra.y * wc1[1] + rbx.x * wc1[2] + rbx.y * wc1[3] + rc.x * wc1[4] + rc.y * wc1[5];
        float2 xf = bf2x2(*(const unsigned int*)&xh[(size_t)src * 128 + c]);
        a0 += xf.x * e0;
        a1 += xf.y * e1;
    }
    *(unsigned int*)&hB[(size_t)node * 128 + c] = f2bf2(a0, a1);
}

// ---------------- fused: extra[c] = sum_k W2[k][c] * (sum_n Tm[n][c]*SV[n][k]) ----------------
__global__ __launch_bounds__(256) void k_extra_fused(const float* __restrict__ Tm, const float* __restrict__ SV,
                                                     const float* __restrict__ W2, float* __restrict__ extra, int n) {
    int tid = threadIdx.x;
    int c = tid & 127, half = tid >> 7;
    float acc[8];
    #pragma unroll
    for (int k = 0; k < 8; ++k) acc[k] = 0.f;
    for (int nn = blockIdx.x * 2 + half; nn < n; nn += gridDim.x * 2) {
        const float4* sv4 = (const float4*)&SV[(size_t)nn * 8];
        float4 s0 = sv4[0], s1 = sv4[1];
        float t = Tm[(size_t)nn * 128 + c];
        acc[0] += t * s0.x; acc[1] += t * s0.y; acc[2] += t * s0.z; acc[3] += t * s0.w;
        acc[4] += t * s1.x; acc[5] += t * s1.y; acc[6] += t * s1.z; acc[7] += t * s1.w;
    }
    float e = 0.f;
    #pragma unroll
    for (int k = 0; k < 8; ++k) e += acc[k] * W2[k * 128 + c];
    __shared__ float red[256];
    red[tid] = e;
    __syncthreads();
    if (tid < 128) atomicAdd(&extra[c], red[tid] + red[tid + 128]);
}

// ---------------- interaction ----------------
__global__ __launch_bounds__(256) void k_interact(const int* __restrict__ rowptr, const int* __restrict__ slist,
                                                  const __half* __restrict__ s8, const float* __restrict__ W2,
                                                  const float* __restrict__ extra,
                                                  const unsigned short* __restrict__ xuph,
                                                  unsigned short* __restrict__ xh, int n) {
    int node = blockIdx.x * 4 + (threadIdx.x >> 6);
    int lane = threadIdx.x & 63;
    if (node >= n) return;
    int c = lane * 2;
    f16x2 w2a[4], w2b[4];
    #pragma unroll
    for (int j = 0; j < 4; ++j) {
        f16x2 wa, wb;
        wa.x = (_Float16)W2[(2 * j) * 128 + c];
        wa.y = (_Float16)W2[(2 * j + 1) * 128 + c];
        wb.x = (_Float16)W2[(2 * j) * 128 + c + 1];
        wb.y = (_Float16)W2[(2 * j + 1) * 128 + c + 1];
        w2a[j] = wa;
        w2b[j] = wb;
    }
    int p0 = rowptr[node], p1 = rowptr[node + 1];
    float cntf = (float)(p1 - p0);
    float a0 = cntf * extra[c], a1 = cntf * extra[c + 1];
    int p = p0;
    for (; p + 4 <= p1; p += 4) {
        int s0 = slist[p], s1 = slist[p + 1], s2 = slist[p + 2], s3 = slist[p + 3];
        uint4 sv[4];
        #pragma unroll
        for (int u = 0; u < 4; ++u) sv[u] = *(const uint4*)(s8 + (size_t)(p + u) * 8);
        unsigned int xv0 = *(const unsigned int*)&xuph[(size_t)s0 * 128 + c];
        unsigned int xv1 = *(const unsigned int*)&xuph[(size_t)s1 * 128 + c];
        unsigned int xv2 = *(const unsigned int*)&xuph[(size_t)s2 * 128 + c];
        unsigned int xv3 = *(const unsigned int*)&xuph[(size_t)s3 * 128 + c];
        #pragma unroll
        for (int u = 0; u < 4; ++u) {
            union { uint4 q; f16x2 h[4]; } s;
            s.q = sv[u];
            float e0 = fdot2f(s.h[0], w2a[0], 0.f);
            e0 = fdot2f(s.h[1], w2a[1], e0);
            e0 = fdot2f(s.h[2], w2a[2], e0);
            e0 = fdot2f(s.h[3], w2a[3], e0);
            float e1 = fdot2f(s.h[0], w2b[0], 0.f);
            e1 = fdot2f(s.h[1], w2b[1], e1);
            e1 = fdot2f(s.h[2], w2b[2], e1);
            e1 = fdot2f(s.h[3], w2b[3], e1);
            float2 xf = bf2x2((u == 0) ? xv0 : (u == 1) ? xv1 : (u == 2) ? xv2 : xv3);
            a0 += xf.x * e0;
            a1 += xf.y * e1;
        }
    }
    for (; p < p1; ++p) {
        int src = slist[p];
        float2 xf = bf2x2(*(const unsigned int*)&xuph[(size_t)src * 128 + c]);
        union { uint4 q; f16x2 h[4]; } s;
        s.q = *(const uint4*)(s8 + (size_t)p * 8);
        float e0 = fdot2f(s.h[0], w2a[0], 0.f);
        e0 = fdot2f(s.h[1], w2a[1], e0);
        e0 = fdot2f(s.h[2], w2a[2], e0);
        e0 = fdot2f(s.h[3], w2a[3], e0);
        float e1 = fdot2f(s.h[0], w2b[0], 0.f);
        e1 = fdot2f(s.h[1], w2b[1], e1);
        e1 = fdot2f(s.h[2], w2b[2], e1);
        e1 = fdot2f(s.h[3], w2b[3], e1);
        a0 += xf.x * e0;
        a1 += xf.y * e1;
    }
    unsigned int cur = *(unsigned int*)&xh[(size_t)node * 128 + c];
    float2 xc = bf2x2(cur);
    *(unsigned int*)&xh[(size_t)node * 128 + c] = f2bf2(xc.x + a0, xc.y + a1);
}

// ---------------- pooling ----------------
__global__ __launch_bounds__(256) void k_pool(const float* __restrict__ P, const int* __restrict__ batch,
                                              float* __restrict__ pool, float* __restrict__ cnt, int n) {
    int i = blockIdx.x * 256 + threadIdx.x;
    int lane = threadIdx.x & 63;
    int b = (i < n) ? batch[i] : -1;
    float p = (i < n) ? P[i] : 0.f;
    int b0 = __shfl(b, 0, 64);
    int b63 = __shfl(b, 63, 64);
    if (b0 == b63 && b0 >= 0) {
        float s = p;
        #pragma unroll
        for (int off = 32; off > 0; off >>= 1) s += __shfl_xor(s, off, 64);
        if (lane == 0) {
            atomicAdd(&pool[b0], s);
            atomicAdd(&cnt[b0], 64.0f);
        }
    } else {
        if (i < n) {
            atomicAdd(&pool[b], p);
            atomicAdd(&cnt[b], 1.0f);
        }
    }
}

__global__ __launch_bounds__(64) void k_final(const float* __restrict__ pool, const float* __restrict__ cnt,
                                              float* __restrict__ out) {
    int g = threadIdx.x;
    if (g < G_) out[g] = __fdividef(pool[g], fmaxf(cnt[g], 1.0f));
}

extern "C" void kernel_launch(void* const* d_in, const int* in_sizes, int n_in,
                              void* d_out, int out_size, void* d_ws, size_t ws_size,
                              hipStream_t stream) {
    (void)in_sizes; (void)n_in; (void)out_size; (void)ws_size;
    const int* z = (const int*)d_in[0];
    const float* dist = (const float*)d_in[1];
    const float* dist_trip = (const float*)d_in[2];
    const float* angle = (const float*)d_in[3];
    const int* edge_index = (const int*)d_in[4];
    const int* triplets = (const int*)d_in[5];
    const int* batch = (const int*)d_in[6];
    const float* atom_table = (const float*)d_in[7];
    const float* rbf_freq = (const float*)d_in[8];
    const float* sbf_freq = (const float*)d_in[9];
    const float* emb_w1 = (const float*)d_in[10];
    const float* emb_b1 = (const float*)d_in[11];
    const float* emb_w2 = (const float*)d_in[12];
    const float* emb_b2 = (const float*)d_in[13];
    const float* iw_rbf1 = (const float*)d_in[14];
    const float* iw_rbf2 = (const float*)d_in[15];
    const float* iw_sbf1 = (const float*)d_in[16];
    const float* iw_sbf2 = (const float*)d_in[17];
    const float* iw_t1 = (const float*)d_in[18];
    const float* iw_t2 = (const float*)d_in[19];
    const float* ib_t2 = (const float*)d_in[20];
    const float* iw_up = (const float*)d_in[21];
    const float* ib_up = (const float*)d_in[22];
    const float* iw_down = (const float*)d_in[23];
    const float* ib_down = (const float*)d_in[24];
    const float* ow_rbf = (const float*)d_in[25];
    const float* ow0 = (const float*)d_in[26];
    const float* ob0 = (const float*)d_in[27];
    const float* ow1 = (const float*)d_in[28];
    const float* ob1 = (const float*)d_in[29];
    const float* ow2 = (const float*)d_in[30];
    const float* ob2 = (const float*)d_in[31];

    const int* erow = edge_index;
    const int* ecol = edge_index + E_;

    // workspace layout
    float* ws = (float*)d_ws;
    float* bufA = ws;                          // N*128 (embS out; Tm)
    float* bufB = bufA + (size_t)N_ * H_;      // N*128 (hB bf16)
    float* P = bufB + (size_t)N_ * H_;         // N
    float* rbfS = P + N_;                      // E*6 (CSR order)
    float* SV4 = rbfS + (size_t)E_ * 6;        // 4*N*8
    float* extra4 = SV4 + (size_t)4 * N_ * 8;  // 4*128
    float* pool = extra4 + 512;                // G
    float* cnt = pool + G_;                    // G
    int* deg = (int*)(cnt + G_);               // N (deg, degT adjacent for one memset)
    int* degT = deg + N_;                      // N
    int* rowptr = degT + N_;                   // N+1
    int* curE = rowptr + N_ + 1;               // N
    int* curT = curE + N_;                     // N
    int* elist = curT + N_;                    // E
    int* slist = elist + E_;                   // E
    int* rowptrT = slist + E_;                 // N+1
    float* dsort = (float*)(rowptrT + N_ + 1); // T
    float* asort = dsort + T_;                 // T
    __half* s8all = (__half*)(asort + T_);     // 4*E*8 halves
    __half* basis = s8all + (size_t)4 * E_ * 8;                          // T*24 halves
    unsigned short* xh = (unsigned short*)(basis + (size_t)T_ * 24);     // N*128 bf16 node state
    unsigned short* xuph = xh + (size_t)N_ * H_;                          // N*128 bf16 x_up
    unsigned short* Wt = xuph + (size_t)N_ * H_;                          // 27*16384 bf16 weights
    unsigned short* hB = (unsigned short*)bufB;

    const int EG = (E_ + 255) / 256;
    const int TG = (T_ + 255) / 256;
    const int ETG = (E_ + T_ + 255) / 256;
    const int NG4 = (N_ + 3) / 4;
    const int GEMMG = (N_ + 63) / 64;

    hipMemsetAsync(deg, 0, 2 * N_ * sizeof(int), stream);
    hipMemsetAsync(extra4, 0, (512 + 2 * G_) * sizeof(float), stream);
    k_wprep<<<27 * 8, 256, 0, stream>>>(emb_w2, iw_down, iw_t1, iw_t2, iw_up, ow0, ow1, Wt);
    k_count2<<<ETG, 256, 0, stream>>>(ecol, triplets, deg, degT);
    k_scan2<<<2, 1024, 0, stream>>>(deg, rowptr, curE, degT, rowptrT, curT, N_);
    k_fill2<<<ETG, 256, 0, stream>>>(ecol, erow, curE, elist, slist, triplets, curT, dist_trip, angle, dsort, asort);

    k_geom<<<EG, 256, 0, stream>>>(elist, dist, rbf_freq, iw_rbf1, rbfS, s8all, E_);
    k_basis<<<TG, 256, 0, stream>>>(dsort, asort, sbf_freq, basis, T_);
    k_sv4<<<(N_ + 7) / 8, 256, 0, stream>>>(rowptrT, basis, iw_sbf1, SV4, N_);
    k_init_x<<<(N_ * 16 + 255) / 256, 256, 0, stream>>>(atom_table, z, xh, N_);

    // embedding: xh = bf16( xh + SS @ w2 + deg*b2 )
    k_embS<<<NG4, 256, 0, stream>>>(rowptr, rbfS, emb_w1, emb_b1, bufA, N_);
    k_gemm_mfma<2, false, true, false, false, true><<<GEMMG, 256, 0, stream>>>(
        bufA, Wt, emb_b2, deg, nullptr, xh, N_);

    auto out_block = [&](int k, bool first) {
        k_out_gather<<<NG4, 256, 0, stream>>>(rowptr, slist, rbfS, xh,
                                              ow_rbf + (size_t)k * 6 * 128, hB, N_);
        if (first)
            k_out_mlp<1><<<GEMMG, 256, 0, stream>>>(hB, Wt + (size_t)(17 + k) * 16384, ob0 + k * 128,
                                                    Wt + (size_t)(22 + k) * 16384, ob1 + k * 128,
                                                    ow2 + k * 128, ob2 + k, P, N_);
        else
            k_out_mlp<2><<<GEMMG, 256, 0, stream>>>(hB, Wt + (size_t)(17 + k) * 16384, ob0 + k * 128,
                                                    Wt + (size_t)(22 + k) * 16384, ob1 + k * 128,
                                                    ow2 + k * 128, ob2 + k, P, N_);
    };

    out_block(0, true);

    for (int b = 0; b < 4; ++b) {
        // fused: xuph = xh@up+b ; Tm = t-chain(xh)
        k_block_mlp<<<GEMMG, 256, 0, stream>>>(xh,
                                               Wt + (size_t)(1 + b) * 16384, ib_down + b * 128,
                                               Wt + (size_t)(5 + b) * 16384,
                                               Wt + (size_t)(9 + b) * 16384, ib_t2 + b * 128,
                                               Wt + (size_t)(13 + b) * 16384, ib_up + b * 128,
                                               bufA, xuph, N_);
        k_extra_fused<<<256, 256, 0, stream>>>(bufA, SV4 + (size_t)b * N_ * 8,
                                               iw_sbf2 + (size_t)b * 1024, extra4 + b * 128, N_);
        k_interact<<<NG4, 256, 0, stream>>>(rowptr, slist, s8all + (size_t)b * E_ * 8,
                                            iw_rbf2 + (size_t)b * 1024, extra4 + b * 128,
                                            xuph, xh, N_);
        out_block(b + 1, false);
    }

    k_pool<<<(N_ + 255) / 256, 256, 0, stream>>>(P, batch, pool, cnt, N_);
    k_final<<<1, 64, 0, stream>>>(pool, cnt, (float*)d_out);
}

// Round 14
// 1741.686 us; speedup vs baseline: 1.5028x; 1.0048x over previous
//
#include <hip/hip_runtime.h>
#include <hip/hip_fp16.h>

#define N_ 50000
#define E_ 800000
#define T_ 800000
#define G_ 64
#define H_ 128

typedef __attribute__((ext_vector_type(8))) short bf16x8;
typedef __attribute__((ext_vector_type(4))) float f32x4;
typedef _Float16 f16x2 __attribute__((ext_vector_type(2)));

__device__ __forceinline__ float siluf(float v) {
    return __fdividef(v, 1.0f + __expf(-v));
}

__device__ __forceinline__ unsigned short f2bf(float f) {
    unsigned int u = __float_as_uint(f);
    u += 0x7fffu + ((u >> 16) & 1u);
    return (unsigned short)(u >> 16);
}
__device__ __forceinline__ unsigned int f2bf2(float a, float b) {
    return (unsigned int)f2bf(a) | ((unsigned int)f2bf(b) << 16);
}
__device__ __forceinline__ float bf2f(unsigned short h) {
    return __uint_as_float(((unsigned int)h) << 16);
}
__device__ __forceinline__ float2 bf2x2(unsigned int p) {
    return make_float2(__uint_as_float(p << 16), __uint_as_float(p & 0xffff0000u));
}
__device__ __forceinline__ float fdot2f(f16x2 a, f16x2 b, float c) {
    return __builtin_amdgcn_fdot2(a, b, c, false);
}

// ---------------- CSR build (merged, packed payloads) ----------------
__global__ __launch_bounds__(256) void k_count2(const int* __restrict__ ecol, const int* __restrict__ trip,
                                                int* degE, int* degT) {
    int i = blockIdx.x * 256 + threadIdx.x;
    if (i < E_) atomicAdd(&degE[ecol[i]], 1);
    int t = i - E_;
    if (t >= 0 && t < T_) atomicAdd(&degT[trip[3 * t + 1]], 1);
}

__global__ __launch_bounds__(1024) void k_scan2(const int* __restrict__ degE, int* rowptrE, int* curE,
                                                const int* __restrict__ degT, int* rowptrT, int* curT, int n) {
    const int* deg = (blockIdx.x == 0) ? degE : degT;
    int* rowptr = (blockIdx.x == 0) ? rowptrE : rowptrT;
    int* cur = (blockIdx.x == 0) ? curE : curT;
    __shared__ int wsum[16];
    __shared__ int s_carry;
    int tid = threadIdx.x, lane = tid & 63, w = tid >> 6;
    if (tid == 0) s_carry = 0;
    __syncthreads();
    for (int base = 0; base < n; base += 1024) {
        int i = base + tid;
        int v = (i < n) ? deg[i] : 0;
        int incl = v;
        #pragma unroll
        for (int s = 1; s < 64; s <<= 1) {
            int t = __shfl_up(incl, (unsigned)s, 64);
            if (lane >= s) incl += t;
        }
        if (lane == 63) wsum[w] = incl;
        __syncthreads();
        int carry0 = s_carry;
        int wexcl = 0;
        for (int j = 0; j < w; ++j) wexcl += wsum[j];
        int excl = carry0 + wexcl + (incl - v);
        if (i < n) { rowptr[i] = excl; cur[i] = excl; }
        __syncthreads();
        if (tid == 1023) s_carry = carry0 + wexcl + incl;
        __syncthreads();
    }
    if (tid == 0) rowptr[n] = s_carry;
}

// packed fill: one 8B scatter per element
__global__ __launch_bounds__(256) void k_fill2(const int* __restrict__ ecol, const int* __restrict__ erow,
                                               const float* __restrict__ dist, int* curE, int2* __restrict__ epay,
                                               const int* __restrict__ trip, int* curT,
                                               const float* __restrict__ dist_trip, const float* __restrict__ angle,
                                               float2* __restrict__ tpay) {
    int i = blockIdx.x * 256 + threadIdx.x;
    if (i < E_) {
        int pos = atomicAdd(&curE[ecol[i]], 1);
        epay[pos] = make_int2(erow[i], __float_as_int(dist[i]));
    }
    int t = i - E_;
    if (t >= 0 && t < T_) {
        int pos = atomicAdd(&curT[trip[3 * t + 1]], 1);
        tpay[pos] = make_float2(dist_trip[t], angle[t]);
    }
}

// dense slist stream for the gather kernels
__global__ __launch_bounds__(256) void k_unpack(const int2* __restrict__ epay, int* __restrict__ slist, int n) {
    int p = blockIdx.x * 256 + threadIdx.x;
    if (p < n) slist[p] = epay[p].x;
}

// ---------------- weight prep ----------------
__global__ __launch_bounds__(256) void k_wprep(const float* __restrict__ emb_w2, const float* __restrict__ iw_down,
                                               const float* __restrict__ iw_t1, const float* __restrict__ iw_t2,
                                               const float* __restrict__ iw_up, const float* __restrict__ ow0,
                                               const float* __restrict__ ow1, unsigned short* __restrict__ Wt) {
    int mat = blockIdx.x >> 3;
    int part = blockIdx.x & 7;
    const float* src;
    if (mat == 0) src = emb_w2;
    else if (mat < 5) src = iw_down + (size_t)(mat - 1) * 16384;
    else if (mat < 9) src = iw_t1 + (size_t)(mat - 5) * 16384;
    else if (mat < 13) src = iw_t2 + (size_t)(mat - 9) * 16384;
    else if (mat < 17) src = iw_up + (size_t)(mat - 13) * 16384;
    else if (mat < 22) src = ow0 + (size_t)(mat - 17) * 16384;
    else src = ow1 + (size_t)(mat - 22) * 16384;
    unsigned short* dst = Wt + (size_t)mat * 16384;
    int base = part * 2048;
    for (int i = base + threadIdx.x; i < base + 2048; i += 256) {
        int k = i >> 7, n = i & 127;
        dst[n * 128 + k] = f2bf(src[i]);
    }
}

// ---------------- geometry: rbfS (fp32, CSR order) + s8 factors, coalesced epay read ----------------
__global__ __launch_bounds__(256) void k_geom(const int2* __restrict__ epay,
                                              const float* __restrict__ freq, const float* __restrict__ iw_rbf1,
                                              float* __restrict__ rbfS, __half* __restrict__ s8all, int n) {
    __shared__ float W1s[4][48];
    int tid = threadIdx.x;
    if (tid < 192) W1s[tid / 48][tid % 48] = iw_rbf1[tid];
    __syncthreads();
    int p = blockIdx.x * 256 + tid;
    if (p >= n) return;
    float d = __int_as_float(epay[p].y) * 0.2f;
    float d2 = d * d, d4 = d2 * d2, d5 = d4 * d;
    float env = __fdividef(1.0f, d) - 28.0f * d5 + 48.0f * d5 * d - 21.0f * d5 * d2;
    float rb[6];
    #pragma unroll
    for (int r = 0; r < 6; ++r) {
        rb[r] = env * __sinf(freq[r] * d);
        rbfS[(size_t)p * 6 + r] = rb[r];
    }
    #pragma unroll
    for (int b = 0; b < 4; ++b) {
        __half out[8];
        #pragma unroll
        for (int k = 0; k < 8; ++k) {
            float u = 0.f;
            #pragma unroll
            for (int r = 0; r < 6; ++r) u += rb[r] * W1s[b][r * 8 + k];
            out[k] = __float2half(siluf(u));
        }
        *(uint4*)&s8all[((size_t)b * n + p) * 8] = *(uint4*)out;
    }
}

// ---------------- triplet basis (fp16, segment order) ----------------
__global__ __launch_bounds__(256) void k_basis(const float2* __restrict__ tpay,
                                               const float* __restrict__ sfreq, __half* __restrict__ basis, int n) {
    int t = blockIdx.x * 256 + threadIdx.x;
    if (t >= n) return;
    float2 da = tpay[t];
    float d = da.x * 0.2f;
    float a = da.y;
    float d2 = d * d, d4 = d2 * d2, d5 = d4 * d;
    float env = __fdividef(1.0f, d) - 28.0f * d5 + 48.0f * d5 * d - 21.0f * d5 * d2;
    float rb[6];
    #pragma unroll
    for (int r = 0; r < 6; ++r) rb[r] = env * __sinf(sfreq[r] * d);
    float sph[4];
    sph[0] = 1.0f; sph[1] = a; sph[2] = 1.5f * a * a - 0.5f; sph[3] = 2.5f * a * a * a - 1.5f * a;
    __half out[24];
    #pragma unroll
    for (int s = 0; s < 4; ++s)
        #pragma unroll
        for (int r = 0; r < 6; ++r) out[s * 6 + r] = __float2half(sph[s] * rb[r]);
    uint4* dst = (uint4*)(basis + (size_t)t * 24);
    dst[0] = ((uint4*)out)[0];
    dst[1] = ((uint4*)out)[1];
    dst[2] = ((uint4*)out)[2];
}

// ---------------- SV for ALL 4 blocks in one pass ----------------
__global__ __launch_bounds__(256) void k_sv4(const int* __restrict__ rowptrT, const __half* __restrict__ basis,
                                             const float* __restrict__ iw_sbf1, float* __restrict__ SV4, int n) {
    int wave = threadIdx.x >> 6, lane = threadIdx.x & 63;
    int node = blockIdx.x * 8 + wave * 2 + (lane >> 5);
    int sub = lane & 31;
    int blk = sub >> 3, k = sub & 7;
    if (node >= n) return;
    const float* W1 = iw_sbf1 + blk * 192;
    f16x2 w[12];
    #pragma unroll
    for (int j = 0; j < 12; ++j) {
        f16x2 t;
        t.x = (_Float16)W1[(2 * j) * 8 + k];
        t.y = (_Float16)W1[(2 * j + 1) * 8 + k];
        w[j] = t;
    }
    float acc = 0.f;
    int p0 = rowptrT[node], p1 = rowptrT[node + 1];
    for (int p = p0; p < p1; ++p) {
        union { uint4 q[3]; f16x2 h[12]; } bs;
        const uint4* bp = (const uint4*)(basis + (size_t)p * 24);
        bs.q[0] = bp[0]; bs.q[1] = bp[1]; bs.q[2] = bp[2];
        float u = 0.f;
        #pragma unroll
        for (int j = 0; j < 12; ++j) u = fdot2f(bs.h[j], w[j], u);
        acc += siluf(u);
    }
    SV4[((size_t)blk * n + node) * 8 + k] = acc;
}

// ---------------- xh = bf16(atom_table[z]) ----------------
__global__ __launch_bounds__(256) void k_init_x(const float* __restrict__ atab, const int* __restrict__ z,
                                                unsigned short* __restrict__ xh, int n) {
    int t = blockIdx.x * 256 + threadIdx.x;
    if (t >= n * 16) return;
    int node = t >> 4, q = t & 15;
    const float4* a4 = (const float4*)atab;
    float4 v0 = a4[(size_t)z[node] * 32 + q * 2];
    float4 v1 = a4[(size_t)z[node] * 32 + q * 2 + 1];
    uint4 pk;
    pk.x = f2bf2(v0.x, v0.y);
    pk.y = f2bf2(v0.z, v0.w);
    pk.z = f2bf2(v1.x, v1.y);
    pk.w = f2bf2(v1.z, v1.w);
    ((uint4*)xh)[t] = pk;
}

// ---------------- SS[n] = sum_{e in n} silu(rbf_e @ w1 + b1) ----------------
__global__ __launch_bounds__(256) void k_embS(const int* __restrict__ rowptr, const float* __restrict__ rbfS,
                                              const float* __restrict__ w1, const float* __restrict__ b1,
                                              float* __restrict__ SS, int n) {
    int node = blockIdx.x * 4 + (threadIdx.x >> 6);
    int lane = threadIdx.x & 63;
    if (node >= n) return;
    int c = lane * 2;
    float wc0[6], wc1[6];
    #pragma unroll
    for (int r = 0; r < 6; ++r) { wc0[r] = w1[r * 128 + c]; wc1[r] = w1[r * 128 + c + 1]; }
    float bb0 = b1[c], bb1 = b1[c + 1];
    float a0 = 0.f, a1 = 0.f;
    int p0 = rowptr[node], p1 = rowptr[node + 1];
    for (int p = p0; p < p1; ++p) {
        const float2* r2 = (const float2*)&rbfS[(size_t)p * 6];
        float2 ra = r2[0], rbx = r2[1], rc = r2[2];
        float u0 = bb0 + ra.x * wc0[0] + ra.y * wc0[1] + rbx.x * wc0[2] + rbx.y * wc0[3] + rc.x * wc0[4] + rc.y * wc0[5];
        float u1 = bb1 + ra.x * wc1[0] + ra.y * wc1[1] + rbx.x * wc1[2] + rbx.y * wc1[3] + rc.x * wc1[4] + rc.y * wc1[5];
        a0 += siluf(u0);
        a1 += siluf(u1);
    }
    SS[node * 128 + c] = a0;
    SS[node * 128 + c + 1] = a1;
}

// ---------------- MFMA GEMM (embedding path) ----------------
template <int BIAS_MODE, bool SILU, bool ACCBF, bool ABF, bool WF32, bool WBF>
__global__ __launch_bounds__(256, 4) void k_gemm_mfma(const void* __restrict__ Ap,
                                                      const unsigned short* __restrict__ Wt,
                                                      const float* __restrict__ bias, const int* __restrict__ deg,
                                                      float* __restrict__ C, unsigned short* __restrict__ Ch, int M) {
    int tid = threadIdx.x;
    int wave = tid >> 6, lane = tid & 63;
    int m15 = lane & 15, quad = lane >> 4;
    int row0 = blockIdx.x * 64 + wave * 16;
    int arow = row0 + m15;
    if (arow > M - 1) arow = M - 1;

    f32x4 acc[8];
    #pragma unroll
    for (int nt = 0; nt < 8; ++nt) acc[nt] = (f32x4){0.f, 0.f, 0.f, 0.f};

    #pragma unroll
    for (int kt = 0; kt < 4; ++kt) {
        int ks = kt * 32 + quad * 8;
        bf16x8 av;
        if constexpr (ABF) {
            av = *(const bf16x8*)((const unsigned short*)Ap + (size_t)arow * 128 + ks);
        } else {
            const float* Arow = (const float*)Ap + (size_t)arow * 128;
            float4 a0 = *(const float4*)(Arow + ks);
            float4 a1 = *(const float4*)(Arow + ks + 4);
            union { bf16x8 v; unsigned int u[4]; } af;
            af.u[0] = f2bf2(a0.x, a0.y);
            af.u[1] = f2bf2(a0.z, a0.w);
            af.u[2] = f2bf2(a1.x, a1.y);
            af.u[3] = f2bf2(a1.z, a1.w);
            av = af.v;
        }
        #pragma unroll
        for (int nt = 0; nt < 8; ++nt) {
            bf16x8 bf = *(const bf16x8*)(Wt + (size_t)(nt * 16 + m15) * 128 + ks);
            acc[nt] = __builtin_amdgcn_mfma_f32_16x16x32_bf16(av, bf, acc[nt], 0, 0, 0);
        }
    }

    #pragma unroll
    for (int nt = 0; nt < 8; ++nt) {
        int col = nt * 16 + m15;
        float bc = 0.f;
        if constexpr (BIAS_MODE != 0) bc = bias[col];
        #pragma unroll
        for (int reg = 0; reg < 4; ++reg) {
            int row = row0 + quad * 4 + reg;
            if (row < M) {
                float v = acc[nt][reg];
                if constexpr (BIAS_MODE == 1) v += bc;
                if constexpr (BIAS_MODE == 2) v += bc * (float)deg[row];
                if constexpr (SILU) v = siluf(v);
                if constexpr (ACCBF) v += bf2f(Ch[(size_t)row * 128 + col]);
                if constexpr (WF32) C[(size_t)row * 128 + col] = v;
                if constexpr (WBF) Ch[(size_t)row * 128 + col] = f2bf(v);
            }
        }
    }
}

// ---------------- fused out-block MLP ----------------
template <int PACC>
__global__ __launch_bounds__(256, 4) void k_out_mlp(const unsigned short* __restrict__ hB,
                                                    const unsigned short* __restrict__ W0t, const float* __restrict__ b0,
                                                    const unsigned short* __restrict__ W1t, const float* __restrict__ b1,
                                                    const float* __restrict__ w2col, const float* __restrict__ ob2p,
                                                    float* __restrict__ Pout, int M) {
    __shared__ unsigned short lds[4][16 * 136];
    int tid = threadIdx.x;
    int wave = tid >> 6, lane = tid & 63;
    int m15 = lane & 15, quad = lane >> 4;
    int row0 = blockIdx.x * 64 + wave * 16;
    int arow = row0 + m15;
    if (arow > M - 1) arow = M - 1;
    unsigned short* L = lds[wave];

    f32x4 acc[8];
    #pragma unroll
    for (int nt = 0; nt < 8; ++nt) acc[nt] = (f32x4){0.f, 0.f, 0.f, 0.f};
    #pragma unroll
    for (int kt = 0; kt < 4; ++kt) {
        int ks = kt * 32 + quad * 8;
        bf16x8 av = *(const bf16x8*)(hB + (size_t)arow * 128 + ks);
        #pragma unroll
        for (int nt = 0; nt < 8; ++nt) {
            bf16x8 bf = *(const bf16x8*)(W0t + (size_t)(nt * 16 + m15) * 128 + ks);
            acc[nt] = __builtin_amdgcn_mfma_f32_16x16x32_bf16(av, bf, acc[nt], 0, 0, 0);
        }
    }
    #pragma unroll
    for (int nt = 0; nt < 8; ++nt) {
        int col = nt * 16 + m15;
        float bc = b0[col];
        #pragma unroll
        for (int reg = 0; reg < 4; ++reg)
            L[(quad * 4 + reg) * 136 + col] = f2bf(siluf(acc[nt][reg] + bc));
    }
    __syncthreads();

    #pragma unroll
    for (int nt = 0; nt < 8; ++nt) acc[nt] = (f32x4){0.f, 0.f, 0.f, 0.f};
    #pragma unroll
    for (int kt = 0; kt < 4; ++kt) {
        int ks = kt * 32 + quad * 8;
        bf16x8 av = *(const bf16x8*)(L + m15 * 136 + ks);
        #pragma unroll
        for (int nt = 0; nt < 8; ++nt) {
            bf16x8 bf = *(const bf16x8*)(W1t + (size_t)(nt * 16 + m15) * 128 + ks);
            acc[nt] = __builtin_amdgcn_mfma_f32_16x16x32_bf16(av, bf, acc[nt], 0, 0, 0);
        }
    }
    float w2c[8], pp[4];
    #pragma unroll
    for (int nt = 0; nt < 8; ++nt) w2c[nt] = w2col[nt * 16 + m15];
    #pragma unroll
    for (int reg = 0; reg < 4; ++reg) pp[reg] = 0.f;
    #pragma unroll
    for (int nt = 0; nt < 8; ++nt) {
        float bc = b1[nt * 16 + m15];
        #pragma unroll
        for (int reg = 0; reg < 4; ++reg)
            pp[reg] += siluf(acc[nt][reg] + bc) * w2c[nt];
    }
    #pragma unroll
    for (int reg = 0; reg < 4; ++reg) {
        float s = pp[reg];
        s += __shfl_xor(s, 1, 64);
        s += __shfl_xor(s, 2, 64);
        s += __shfl_xor(s, 4, 64);
        s += __shfl_xor(s, 8, 64);
        if (m15 == 0) {
            int row = row0 + quad * 4 + reg;
            if (row < M) {
                float r = s + ob2p[0];
                if constexpr (PACC == 2) r += Pout[row];
                Pout[row] = r;
            }
        }
    }
}

// ---------------- fused per-block MLP ----------------
__global__ __launch_bounds__(256, 4) void k_block_mlp(const unsigned short* __restrict__ xh,
                                                      const unsigned short* __restrict__ Wd, const float* __restrict__ bd,
                                                      const unsigned short* __restrict__ Wt1,
                                                      const unsigned short* __restrict__ Wt2, const float* __restrict__ bt2,
                                                      const unsigned short* __restrict__ Wup, const float* __restrict__ bup,
                                                      float* __restrict__ Tm, unsigned short* __restrict__ xuph, int M) {
    __shared__ unsigned short lds[4][16 * 136];
    int tid = threadIdx.x;
    int wave = tid >> 6, lane = tid & 63;
    int m15 = lane & 15, quad = lane >> 4;
    int row0 = blockIdx.x * 64 + wave * 16;
    int arow = row0 + m15;
    if (arow > M - 1) arow = M - 1;
    unsigned short* L = lds[wave];

    f32x4 accD[8], accU[8];
    #pragma unroll
    for (int nt = 0; nt < 8; ++nt) { accD[nt] = (f32x4){0.f, 0.f, 0.f, 0.f}; accU[nt] = (f32x4){0.f, 0.f, 0.f, 0.f}; }
    #pragma unroll
    for (int kt = 0; kt < 4; ++kt) {
        int ks = kt * 32 + quad * 8;
        bf16x8 av = *(const bf16x8*)(xh + (size_t)arow * 128 + ks);
        #pragma unroll
        for (int nt = 0; nt < 8; ++nt) {
            bf16x8 bd_ = *(const bf16x8*)(Wd + (size_t)(nt * 16 + m15) * 128 + ks);
            accD[nt] = __builtin_amdgcn_mfma_f32_16x16x32_bf16(av, bd_, accD[nt], 0, 0, 0);
            bf16x8 bu_ = *(const bf16x8*)(Wup + (size_t)(nt * 16 + m15) * 128 + ks);
            accU[nt] = __builtin_amdgcn_mfma_f32_16x16x32_bf16(av, bu_, accU[nt], 0, 0, 0);
        }
    }
    #pragma unroll
    for (int nt = 0; nt < 8; ++nt) {
        int col = nt * 16 + m15;
        float bcu = bup[col], bcd = bd[col];
        #pragma unroll
        for (int reg = 0; reg < 4; ++reg) {
            int row = row0 + quad * 4 + reg;
            if (row < M) xuph[(size_t)row * 128 + col] = f2bf(accU[nt][reg] + bcu);
            L[(quad * 4 + reg) * 136 + col] = f2bf(accD[nt][reg] + bcd);
        }
    }
    __syncthreads();

    #pragma unroll
    for (int nt = 0; nt < 8; ++nt) accD[nt] = (f32x4){0.f, 0.f, 0.f, 0.f};
    #pragma unroll
    for (int kt = 0; kt < 4; ++kt) {
        int ks = kt * 32 + quad * 8;
        bf16x8 av = *(const bf16x8*)(L + m15 * 136 + ks);
        #pragma unroll
        for (int nt = 0; nt < 8; ++nt) {
            bf16x8 bf = *(const bf16x8*)(Wt1 + (size_t)(nt * 16 + m15) * 128 + ks);
            accD[nt] = __builtin_amdgcn_mfma_f32_16x16x32_bf16(av, bf, accD[nt], 0, 0, 0);
        }
    }
    __syncthreads();
    #pragma unroll
    for (int nt = 0; nt < 8; ++nt) {
        int col = nt * 16 + m15;
        #pragma unroll
        for (int reg = 0; reg < 4; ++reg)
            L[(quad * 4 + reg) * 136 + col] = f2bf(siluf(accD[nt][reg]));
    }
    __syncthreads();

    #pragma unroll
    for (int nt = 0; nt < 8; ++nt) accD[nt] = (f32x4){0.f, 0.f, 0.f, 0.f};
    #pragma unroll
    for (int kt = 0; kt < 4; ++kt) {
        int ks = kt * 32 + quad * 8;
        bf16x8 av = *(const bf16x8*)(L + m15 * 136 + ks);
        #pragma unroll
        for (int nt = 0; nt < 8; ++nt) {
            bf16x8 bf = *(const bf16x8*)(Wt2 + (size_t)(nt * 16 + m15) * 128 + ks);
            accD[nt] = __builtin_amdgcn_mfma_f32_16x16x32_bf16(av, bf, accD[nt], 0, 0, 0);
        }
    }
    #pragma unroll
    for (int nt = 0; nt < 8; ++nt) {
        int col = nt * 16 + m15;
        float bc = bt2[col];
        #pragma unroll
        for (int reg = 0; reg < 4; ++reg) {
            int row = row0 + quad * 4 + reg;
            if (row < M) Tm[(size_t)row * 128 + col] = accD[nt][reg] + bc;
        }
    }
}

// ---------------- out_block gather -> bf16 h ----------------
__global__ __launch_bounds__(256) void k_out_gather(const int* __restrict__ rowptr, const int* __restrict__ slist,
                                                    const float* __restrict__ rbfS,
                                                    const unsigned short* __restrict__ xh,
                                                    const float* __restrict__ wrbf,
                                                    unsigned short* __restrict__ hB, int n) {
    int node = blockIdx.x * 4 + (threadIdx.x >> 6);
    int lane = threadIdx.x & 63;
    if (node >= n) return;
    int c = lane * 2;
    float wc0[6], wc1[6];
    #pragma unroll
    for (int r = 0; r < 6; ++r) { wc0[r] = wrbf[r * 128 + c]; wc1[r] = wrbf[r * 128 + c + 1]; }
    float a0 = 0.f, a1 = 0.f;
    int p0 = rowptr[node], p1 = rowptr[node + 1];
    int p = p0;
    for (; p + 4 <= p1; p += 4) {
        int s0 = slist[p], s1 = slist[p + 1], s2 = slist[p + 2], s3 = slist[p + 3];
        float2 rb[4][3];
        #pragma unroll
        for (int u = 0; u < 4; ++u) {
            const float2* r2 = (const float2*)&rbfS[(size_t)(p + u) * 6];
            rb[u][0] = r2[0]; rb[u][1] = r2[1]; rb[u][2] = r2[2];
        }
        unsigned int xv0 = *(const unsigned int*)&xh[(size_t)s0 * 128 + c];
        unsigned int xv1 = *(const unsigned int*)&xh[(size_t)s1 * 128 + c];
        unsigned int xv2 = *(const unsigned int*)&xh[(size_t)s2 * 128 + c];
        unsigned int xv3 = *(const unsigned int*)&xh[(size_t)s3 * 128 + c];
        #pragma unroll
        for (int u = 0; u < 4; ++u) {
            float e0 = rb[u][0].x * wc0[0] + rb[u][0].y * wc0[1] + rb[u][1].x * wc0[2] +
                       rb[u][1].y * wc0[3] + rb[u][2].x * wc0[4] + rb[u][2].y * wc0[5];
            float e1 = rb[u][0].x * wc1[0] + rb[u][0].y * wc1[1] + rb[u][1].x * wc1[2] +
                       rb[u][1].y * wc1[3] + rb[u][2].x * wc1[4] + rb[u][2].y * wc1[5];
            float2 xf = bf2x2((u == 0) ? xv0 : (u == 1) ? xv1 : (u == 2) ? xv2 : xv3);
            a0 += xf.x * e0;
            a1 += xf.y * e1;
        }
    }
    for (; p < p1; ++p) {
        int src = slist[p];
        const float2* r2 = (const float2*)&rbfS[(size_t)p * 6];
        float2 ra = r2[0], rbx = r2[1], rc = r2[2];
        float e0 = ra.x * wc0[0] + ra.y * wc0[1] + rbx.x * wc0[2] + rbx.y * wc0[3] + rc.x * wc0[4] + rc.y * wc0[5];
        float e1 = ra.x * wc1[0] + ra.y * wc1[1] + rbx.x * wc1[2] + rbx.y * wc1[3] + rc.x * wc1[4] + rc.y * wc1[5];
        float2 xf = bf2x2(*(const unsigned int*)&xh[(size_t)src * 128 + c]);
        a0 += xf.x * e0;
        a1 += xf.y * e1;
    }
    *(unsigned int*)&hB[(size_t)node * 128 + c] = f2bf2(a0, a1);
}

// ---------------- fused: extra[c] = sum_k W2[k][c] * (sum_n Tm[n][c]*SV[n][k]) ----------------
__global__ __launch_bounds__(256) void k_extra_fused(const float* __restrict__ Tm, const float* __restrict__ SV,
                                                     const float* __restrict__ W2, float* __restrict__ extra, int n) {
    int tid = threadIdx.x;
    int c = tid & 127, half = tid >> 7;
    float acc[8];
    #pragma unroll
    for (int k = 0; k < 8; ++k) acc[k] = 0.f;
    for (int nn = blockIdx.x * 2 + half; nn < n; nn += gridDim.x * 2) {
        const float4* sv4 = (const float4*)&SV[(size_t)nn * 8];
        float4 s0 = sv4[0], s1 = sv4[1];
        float t = Tm[(size_t)nn * 128 + c];
        acc[0] += t * s0.x; acc[1] += t * s0.y; acc[2] += t * s0.z; acc[3] += t * s0.w;
        acc[4] += t * s1.x; acc[5] += t * s1.y; acc[6] += t * s1.z; acc[7] += t * s1.w;
    }
    float e = 0.f;
    #pragma unroll
    for (int k = 0; k < 8; ++k) e += acc[k] * W2[k * 128 + c];
    __shared__ float red[256];
    red[tid] = e;
    __syncthreads();
    if (tid < 128) atomicAdd(&extra[c], red[tid] + red[tid + 128]);
}

// ---------------- interaction ----------------
__global__ __launch_bounds__(256) void k_interact(const int* __restrict__ rowptr, const int* __restrict__ slist,
                                                  const __half* __restrict__ s8, const float* __restrict__ W2,
                                                  const float* __restrict__ extra,
                                                  const unsigned short* __restrict__ xuph,
                                                  unsigned short* __restrict__ xh, int n) {
    int node = blockIdx.x * 4 + (threadIdx.x >> 6);
    int lane = threadIdx.x & 63;
    if (node >= n) return;
    int c = lane * 2;
    f16x2 w2a[4], w2b[4];
    #pragma unroll
    for (int j = 0; j < 4; ++j) {
        f16x2 wa, wb;
        wa.x = (_Float16)W2[(2 * j) * 128 + c];
        wa.y = (_Float16)W2[(2 * j + 1) * 128 + c];
        wb.x = (_Float16)W2[(2 * j) * 128 + c + 1];
        wb.y = (_Float16)W2[(2 * j + 1) * 128 + c + 1];
        w2a[j] = wa;
        w2b[j] = wb;
    }
    int p0 = rowptr[node], p1 = rowptr[node + 1];
    float cntf = (float)(p1 - p0);
    float a0 = cntf * extra[c], a1 = cntf * extra[c + 1];
    int p = p0;
    for (; p + 4 <= p1; p += 4) {
        int s0 = slist[p], s1 = slist[p + 1], s2 = slist[p + 2], s3 = slist[p + 3];
        uint4 sv[4];
        #pragma unroll
        for (int u = 0; u < 4; ++u) sv[u] = *(const uint4*)(s8 + (size_t)(p + u) * 8);
        unsigned int xv0 = *(const unsigned int*)&xuph[(size_t)s0 * 128 + c];
        unsigned int xv1 = *(const unsigned int*)&xuph[(size_t)s1 * 128 + c];
        unsigned int xv2 = *(const unsigned int*)&xuph[(size_t)s2 * 128 + c];
        unsigned int xv3 = *(const unsigned int*)&xuph[(size_t)s3 * 128 + c];
        #pragma unroll
        for (int u = 0; u < 4; ++u) {
            union { uint4 q; f16x2 h[4]; } s;
            s.q = sv[u];
            float e0 = fdot2f(s.h[0], w2a[0], 0.f);
            e0 = fdot2f(s.h[1], w2a[1], e0);
            e0 = fdot2f(s.h[2], w2a[2], e0);
            e0 = fdot2f(s.h[3], w2a[3], e0);
            float e1 = fdot2f(s.h[0], w2b[0], 0.f);
            e1 = fdot2f(s.h[1], w2b[1], e1);
            e1 = fdot2f(s.h[2], w2b[2], e1);
            e1 = fdot2f(s.h[3], w2b[3], e1);
            float2 xf = bf2x2((u == 0) ? xv0 : (u == 1) ? xv1 : (u == 2) ? xv2 : xv3);
            a0 += xf.x * e0;
            a1 += xf.y * e1;
        }
    }
    for (; p < p1; ++p) {
        int src = slist[p];
        float2 xf = bf2x2(*(const unsigned int*)&xuph[(size_t)src * 128 + c]);
        union { uint4 q; f16x2 h[4]; } s;
        s.q = *(const uint4*)(s8 + (size_t)p * 8);
        float e0 = fdot2f(s.h[0], w2a[0], 0.f);
        e0 = fdot2f(s.h[1], w2a[1], e0);
        e0 = fdot2f(s.h[2], w2a[2], e0);
        e0 = fdot2f(s.h[3], w2a[3], e0);
        float e1 = fdot2f(s.h[0], w2b[0], 0.f);
        e1 = fdot2f(s.h[1], w2b[1], e1);
        e1 = fdot2f(s.h[2], w2b[2], e1);
        e1 = fdot2f(s.h[3], w2b[3], e1);
        a0 += xf.x * e0;
        a1 += xf.y * e1;
    }
    unsigned int cur = *(unsigned int*)&xh[(size_t)node * 128 + c];
    float2 xc = bf2x2(cur);
    *(unsigned int*)&xh[(size_t)node * 128 + c] = f2bf2(xc.x + a0, xc.y + a1);
}

// ---------------- pooling ----------------
__global__ __launch_bounds__(256) void k_pool(const float* __restrict__ P, const int* __restrict__ batch,
                                              float* __restrict__ pool, float* __restrict__ cnt, int n) {
    int i = blockIdx.x * 256 + threadIdx.x;
    int lane = threadIdx.x & 63;
    int b = (i < n) ? batch[i] : -1;
    float p = (i < n) ? P[i] : 0.f;
    int b0 = __shfl(b, 0, 64);
    int b63 = __shfl(b, 63, 64);
    if (b0 == b63 && b0 >= 0) {
        float s = p;
        #pragma unroll
        for (int off = 32; off > 0; off >>= 1) s += __shfl_xor(s, off, 64);
        if (lane == 0) {
            atomicAdd(&pool[b0], s);
            atomicAdd(&cnt[b0], 64.0f);
        }
    } else {
        if (i < n) {
            atomicAdd(&pool[b], p);
            atomicAdd(&cnt[b], 1.0f);
        }
    }
}

__global__ __launch_bounds__(64) void k_final(const float* __restrict__ pool, const float* __restrict__ cnt,
                                              float* __restrict__ out) {
    int g = threadIdx.x;
    if (g < G_) out[g] = __fdividef(pool[g], fmaxf(cnt[g], 1.0f));
}

extern "C" void kernel_launch(void* const* d_in, const int* in_sizes, int n_in,
                              void* d_out, int out_size, void* d_ws, size_t ws_size,
                              hipStream_t stream) {
    (void)in_sizes; (void)n_in; (void)out_size; (void)ws_size;
    const int* z = (const int*)d_in[0];
    const float* dist = (const float*)d_in[1];
    const float* dist_trip = (const float*)d_in[2];
    const float* angle = (const float*)d_in[3];
    const int* edge_index = (const int*)d_in[4];
    const int* triplets = (const int*)d_in[5];
    const int* batch = (const int*)d_in[6];
    const float* atom_table = (const float*)d_in[7];
    const float* rbf_freq = (const float*)d_in[8];
    const float* sbf_freq = (const float*)d_in[9];
    const float* emb_w1 = (const float*)d_in[10];
    const float* emb_b1 = (const float*)d_in[11];
    const float* emb_w2 = (const float*)d_in[12];
    const float* emb_b2 = (const float*)d_in[13];
    const float* iw_rbf1 = (const float*)d_in[14];
    const float* iw_rbf2 = (const float*)d_in[15];
    const float* iw_sbf1 = (const float*)d_in[16];
    const float* iw_sbf2 = (const float*)d_in[17];
    const float* iw_t1 = (const float*)d_in[18];
    const float* iw_t2 = (const float*)d_in[19];
    const float* ib_t2 = (const float*)d_in[20];
    const float* iw_up = (const float*)d_in[21];
    const float* ib_up = (const float*)d_in[22];
    const float* iw_down = (const float*)d_in[23];
    const float* ib_down = (const float*)d_in[24];
    const float* ow_rbf = (const float*)d_in[25];
    const float* ow0 = (const float*)d_in[26];
    const float* ob0 = (const float*)d_in[27];
    const float* ow1 = (const float*)d_in[28];
    const float* ob1 = (const float*)d_in[29];
    const float* ow2 = (const float*)d_in[30];
    const float* ob2 = (const float*)d_in[31];

    const int* erow = edge_index;
    const int* ecol = edge_index + E_;

    // workspace layout
    float* ws = (float*)d_ws;
    float* bufA = ws;                          // N*128 (embS out; Tm)
    float* bufB = bufA + (size_t)N_ * H_;      // N*128 (hB bf16)
    float* P = bufB + (size_t)N_ * H_;         // N
    float* rbfS = P + N_;                      // E*6 (CSR order)
    float* SV4 = rbfS + (size_t)E_ * 6;        // 4*N*8
    float* extra4 = SV4 + (size_t)4 * N_ * 8;  // 4*128
    float* pool = extra4 + 512;                // G
    float* cnt = pool + G_;                    // G
    int* deg = (int*)(cnt + G_);               // N (deg, degT adjacent for one memset)
    int* degT = deg + N_;                      // N
    int* rowptr = degT + N_;                   // N+1
    int* curE = rowptr + N_ + 1;               // N
    int* curT = curE + N_;                     // N
    int* slist = curT + N_;                    // E
    int* rowptrT = slist + E_;                 // N+1
    int2* epay = (int2*)(rowptrT + N_ + 1);    // E int2 (packed {row, dist-bits})
    float2* tpay = (float2*)(epay + E_);       // T float2 (packed {dist_trip, angle})
    __half* s8all = (__half*)(tpay + T_);      // 4*E*8 halves
    __half* basis = s8all + (size_t)4 * E_ * 8;                          // T*24 halves
    unsigned short* xh = (unsigned short*)(basis + (size_t)T_ * 24);     // N*128 bf16 node state
    unsigned short* xuph = xh + (size_t)N_ * H_;                          // N*128 bf16 x_up
    unsigned short* Wt = xuph + (size_t)N_ * H_;                          // 27*16384 bf16 weights
    unsigned short* hB = (unsigned short*)bufB;

    const int EG = (E_ + 255) / 256;
    const int TG = (T_ + 255) / 256;
    const int ETG = (E_ + T_ + 255) / 256;
    const int NG4 = (N_ + 3) / 4;
    const int GEMMG = (N_ + 63) / 64;

    hipMemsetAsync(deg, 0, 2 * N_ * sizeof(int), stream);
    hipMemsetAsync(extra4, 0, (512 + 2 * G_) * sizeof(float), stream);
    k_wprep<<<27 * 8, 256, 0, stream>>>(emb_w2, iw_down, iw_t1, iw_t2, iw_up, ow0, ow1, Wt);
    k_count2<<<ETG, 256, 0, stream>>>(ecol, triplets, deg, degT);
    k_scan2<<<2, 1024, 0, stream>>>(deg, rowptr, curE, degT, rowptrT, curT, N_);
    k_fill2<<<ETG, 256, 0, stream>>>(ecol, erow, dist, curE, epay, triplets, curT, dist_trip, angle, tpay);
    k_unpack<<<EG, 256, 0, stream>>>(epay, slist, E_);

    k_geom<<<EG, 256, 0, stream>>>(epay, rbf_freq, iw_rbf1, rbfS, s8all, E_);
    k_basis<<<TG, 256, 0, stream>>>(tpay, sbf_freq, basis, T_);
    k_sv4<<<(N_ + 7) / 8, 256, 0, stream>>>(rowptrT, basis, iw_sbf1, SV4, N_);
    k_init_x<<<(N_ * 16 + 255) / 256, 256, 0, stream>>>(atom_table, z, xh, N_);

    // embedding: xh = bf16( xh + SS @ w2 + deg*b2 )
    k_embS<<<NG4, 256, 0, stream>>>(rowptr, rbfS, emb_w1, emb_b1, bufA, N_);
    k_gemm_mfma<2, false, true, false, false, true><<<GEMMG, 256, 0, stream>>>(
        bufA, Wt, emb_b2, deg, nullptr, xh, N_);

    auto out_block = [&](int k, bool first) {
        k_out_gather<<<NG4, 256, 0, stream>>>(rowptr, slist, rbfS, xh,
                                              ow_rbf + (size_t)k * 6 * 128, hB, N_);
        if (first)
            k_out_mlp<1><<<GEMMG, 256, 0, stream>>>(hB, Wt + (size_t)(17 + k) * 16384, ob0 + k * 128,
                                                    Wt + (size_t)(22 + k) * 16384, ob1 + k * 128,
                                                    ow2 + k * 128, ob2 + k, P, N_);
        else
            k_out_mlp<2><<<GEMMG, 256, 0, stream>>>(hB, Wt + (size_t)(17 + k) * 16384, ob0 + k * 128,
                                                    Wt + (size_t)(22 + k) * 16384, ob1 + k * 128,
                                                    ow2 + k * 128, ob2 + k, P, N_);
    };

    out_block(0, true);

    for (int b = 0; b < 4; ++b) {
        k_block_mlp<<<GEMMG, 256, 0, stream>>>(xh,
                                               Wt + (size_t)(1 + b) * 16384, ib_down + b * 128,
                                               Wt + (size_t)(5 + b) * 16384,
                                               Wt + (size_t)(9 + b) * 16384, ib_t2 + b * 128,
                                               Wt + (size_t)(13 + b) * 16384, ib_up + b * 128,
                                               bufA, xuph, N_);
        k_extra_fused<<<256, 256, 0, stream>>>(bufA, SV4 + (size_t)b * N_ * 8,
                                               iw_sbf2 + (size_t)b * 1024, extra4 + b * 128, N_);
        k_interact<<<NG4, 256, 0, stream>>>(rowptr, slist, s8all + (size_t)b * E_ * 8,
                                            iw_rbf2 + (size_t)b * 1024, extra4 + b * 128,
                                            xuph, xh, N_);
        out_block(b + 1, false);
    }

    k_pool<<<(N_ + 255) / 256, 256, 0, stream>>>(P, batch, pool, cnt, N_);
    k_final<<<1, 64, 0, stream>>>(pool, cnt, (float*)d_out);
}

// Round 15
// 1702.441 us; speedup vs baseline: 1.5374x; 1.0231x over previous
//
#include <hip/hip_runtime.h>
#include <hip/hip_fp16.h>

#define N_ 50000
#define E_ 800000
#define T_ 800000
#define G_ 64
#define H_ 128

// bucket sort geometry: 64 cols per bucket, 8 XCD-affine sub-buckets each
#define NBK 782            // ceil(N/64)
#define NSB (NBK * 8)      // 6256 sub-buckets
#define CAPS 512           // entries per sub-bucket (mean ~128)

typedef __attribute__((ext_vector_type(8))) short bf16x8;
typedef __attribute__((ext_vector_type(4))) float f32x4;
typedef _Float16 f16x2 __attribute__((ext_vector_type(2)));

__device__ __forceinline__ float siluf(float v) {
    return __fdividef(v, 1.0f + __expf(-v));
}

__device__ __forceinline__ unsigned short f2bf(float f) {
    unsigned int u = __float_as_uint(f);
    u += 0x7fffu + ((u >> 16) & 1u);
    return (unsigned short)(u >> 16);
}
__device__ __forceinline__ unsigned int f2bf2(float a, float b) {
    return (unsigned int)f2bf(a) | ((unsigned int)f2bf(b) << 16);
}
__device__ __forceinline__ float bf2f(unsigned short h) {
    return __uint_as_float(((unsigned int)h) << 16);
}
__device__ __forceinline__ float2 bf2x2(unsigned int p) {
    return make_float2(__uint_as_float(p << 16), __uint_as_float(p & 0xffff0000u));
}
__device__ __forceinline__ float fdot2f(f16x2 a, f16x2 b, float c) {
    return __builtin_amdgcn_fdot2(a, b, c, false);
}

// ---------------- pass 1: bucket append (XCD-affine sub-buckets, merged writes) ----------------
__global__ __launch_bounds__(256) void k_bucket(const int* __restrict__ ecol, const int* __restrict__ erow,
                                                const float* __restrict__ dist,
                                                const int* __restrict__ trip,
                                                const float* __restrict__ dist_trip, const float* __restrict__ angle,
                                                int* bcntE, int2* __restrict__ ebktP, unsigned char* __restrict__ ebktC,
                                                int* bcntT, float2* __restrict__ tbktP, unsigned char* __restrict__ tbktC) {
    int i = blockIdx.x * 256 + threadIdx.x;
    int r = blockIdx.x & 7;
    if (i < E_) {
        int col = ecol[i];
        int sb = (col >> 6) * 8 + r;
        int pos = atomicAdd(&bcntE[sb], 1);
        if (pos < CAPS) {
            ebktP[(size_t)sb * CAPS + pos] = make_int2(erow[i], __float_as_int(dist[i]));
            ebktC[(size_t)sb * CAPS + pos] = (unsigned char)(col & 63);
        }
    }
    int t = i - E_;
    if (t >= 0 && t < T_) {
        int j = trip[3 * t + 1];
        int sb = (j >> 6) * 8 + r;
        int pos = atomicAdd(&bcntT[sb], 1);
        if (pos < CAPS) {
            tbktP[(size_t)sb * CAPS + pos] = make_float2(dist_trip[t], angle[t]);
            tbktC[(size_t)sb * CAPS + pos] = (unsigned char)(j & 63);
        }
    }
}

// ---------------- pass 1.5: per-bucket LDS count -> dense deg ----------------
__global__ __launch_bounds__(256) void k_cnt(const int* __restrict__ bcntE, const unsigned char* __restrict__ ebktC,
                                             const int* __restrict__ bcntT, const unsigned char* __restrict__ tbktC,
                                             int* __restrict__ degE, int* __restrict__ degT) {
    int b = blockIdx.x;
    bool isE = b < NBK;
    if (!isE) b -= NBK;
    __shared__ int c[64];
    int tid = threadIdx.x;
    if (tid < 64) c[tid] = 0;
    __syncthreads();
    const int* bcnt = isE ? bcntE : bcntT;
    const unsigned char* bc = isE ? ebktC : tbktC;
    for (int s = 0; s < 8; ++s) {
        int sb = b * 8 + s;
        int nb = min(bcnt[sb], CAPS);
        for (int i = tid; i < nb; i += 256) atomicAdd(&c[bc[(size_t)sb * CAPS + i]], 1);
    }
    __syncthreads();
    if (tid < 64) {
        int col = b * 64 + tid;
        if (col < N_) (isE ? degE : degT)[col] = c[tid];
    }
}

// ---------------- scan (2 blocks: edge CSR, triplet CSR) ----------------
__global__ __launch_bounds__(1024) void k_scan2(const int* __restrict__ degE, int* rowptrE, int* curE,
                                                const int* __restrict__ degT, int* rowptrT, int* curT, int n) {
    const int* deg = (blockIdx.x == 0) ? degE : degT;
    int* rowptr = (blockIdx.x == 0) ? rowptrE : rowptrT;
    int* cur = (blockIdx.x == 0) ? curE : curT;
    __shared__ int wsum[16];
    __shared__ int s_carry;
    int tid = threadIdx.x, lane = tid & 63, w = tid >> 6;
    if (tid == 0) s_carry = 0;
    __syncthreads();
    for (int base = 0; base < n; base += 1024) {
        int i = base + tid;
        int v = (i < n) ? deg[i] : 0;
        int incl = v;
        #pragma unroll
        for (int s = 1; s < 64; s <<= 1) {
            int t = __shfl_up(incl, (unsigned)s, 64);
            if (lane >= s) incl += t;
        }
        if (lane == 63) wsum[w] = incl;
        __syncthreads();
        int carry0 = s_carry;
        int wexcl = 0;
        for (int j = 0; j < w; ++j) wexcl += wsum[j];
        int excl = carry0 + wexcl + (incl - v);
        if (i < n) { rowptr[i] = excl; cur[i] = excl; }
        __syncthreads();
        if (tid == 1023) s_carry = carry0 + wexcl + incl;
        __syncthreads();
    }
    if (tid == 0) rowptr[n] = s_carry;
}

// ---------------- pass 2: place into CSR (per-bucket 8KB window, cache-local) ----------------
__global__ __launch_bounds__(256) void k_place(const int* __restrict__ bcntE, const int2* __restrict__ ebktP,
                                               const unsigned char* __restrict__ ebktC, int* curE,
                                               int* __restrict__ slist, float* __restrict__ distS,
                                               const int* __restrict__ bcntT, const float2* __restrict__ tbktP,
                                               const unsigned char* __restrict__ tbktC, int* curT,
                                               float2* __restrict__ tpay) {
    int b = blockIdx.x;
    bool isE = b < NBK;
    if (!isE) b -= NBK;
    int tid = threadIdx.x;
    if (isE) {
        for (int s = 0; s < 8; ++s) {
            int sb = b * 8 + s;
            int nb = min(bcntE[sb], CAPS);
            for (int i = tid; i < nb; i += 256) {
                size_t idx = (size_t)sb * CAPS + i;
                int col = b * 64 + ebktC[idx];
                int2 pr = ebktP[idx];
                int pos = atomicAdd(&curE[col], 1);
                slist[pos] = pr.x;
                distS[pos] = __int_as_float(pr.y);
            }
        }
    } else {
        for (int s = 0; s < 8; ++s) {
            int sb = b * 8 + s;
            int nb = min(bcntT[sb], CAPS);
            for (int i = tid; i < nb; i += 256) {
                size_t idx = (size_t)sb * CAPS + i;
                int col = b * 64 + tbktC[idx];
                float2 pr = tbktP[idx];
                int pos = atomicAdd(&curT[col], 1);
                tpay[pos] = pr;
            }
        }
    }
}

// ---------------- weight prep ----------------
__global__ __launch_bounds__(256) void k_wprep(const float* __restrict__ emb_w2, const float* __restrict__ iw_down,
                                               const float* __restrict__ iw_t1, const float* __restrict__ iw_t2,
                                               const float* __restrict__ iw_up, const float* __restrict__ ow0,
                                               const float* __restrict__ ow1, unsigned short* __restrict__ Wt) {
    int mat = blockIdx.x >> 3;
    int part = blockIdx.x & 7;
    const float* src;
    if (mat == 0) src = emb_w2;
    else if (mat < 5) src = iw_down + (size_t)(mat - 1) * 16384;
    else if (mat < 9) src = iw_t1 + (size_t)(mat - 5) * 16384;
    else if (mat < 13) src = iw_t2 + (size_t)(mat - 9) * 16384;
    else if (mat < 17) src = iw_up + (size_t)(mat - 13) * 16384;
    else if (mat < 22) src = ow0 + (size_t)(mat - 17) * 16384;
    else src = ow1 + (size_t)(mat - 22) * 16384;
    unsigned short* dst = Wt + (size_t)mat * 16384;
    int base = part * 2048;
    for (int i = base + threadIdx.x; i < base + 2048; i += 256) {
        int k = i >> 7, n = i & 127;
        dst[n * 128 + k] = f2bf(src[i]);
    }
}

// ---------------- geometry: rbfS (fp32, CSR order) + s8 factors ----------------
__global__ __launch_bounds__(256) void k_geom(const float* __restrict__ distS,
                                              const float* __restrict__ freq, const float* __restrict__ iw_rbf1,
                                              float* __restrict__ rbfS, __half* __restrict__ s8all, int n) {
    __shared__ float W1s[4][48];
    int tid = threadIdx.x;
    if (tid < 192) W1s[tid / 48][tid % 48] = iw_rbf1[tid];
    __syncthreads();
    int p = blockIdx.x * 256 + tid;
    if (p >= n) return;
    float d = distS[p] * 0.2f;
    float d2 = d * d, d4 = d2 * d2, d5 = d4 * d;
    float env = __fdividef(1.0f, d) - 28.0f * d5 + 48.0f * d5 * d - 21.0f * d5 * d2;
    float rb[6];
    #pragma unroll
    for (int r = 0; r < 6; ++r) {
        rb[r] = env * __sinf(freq[r] * d);
        rbfS[(size_t)p * 6 + r] = rb[r];
    }
    #pragma unroll
    for (int b = 0; b < 4; ++b) {
        __half out[8];
        #pragma unroll
        for (int k = 0; k < 8; ++k) {
            float u = 0.f;
            #pragma unroll
            for (int r = 0; r < 6; ++r) u += rb[r] * W1s[b][r * 8 + k];
            out[k] = __float2half(siluf(u));
        }
        *(uint4*)&s8all[((size_t)b * n + p) * 8] = *(uint4*)out;
    }
}

// ---------------- triplet basis (fp16, segment order) ----------------
__global__ __launch_bounds__(256) void k_basis(const float2* __restrict__ tpay,
                                               const float* __restrict__ sfreq, __half* __restrict__ basis, int n) {
    int t = blockIdx.x * 256 + threadIdx.x;
    if (t >= n) return;
    float2 da = tpay[t];
    float d = da.x * 0.2f;
    float a = da.y;
    float d2 = d * d, d4 = d2 * d2, d5 = d4 * d;
    float env = __fdividef(1.0f, d) - 28.0f * d5 + 48.0f * d5 * d - 21.0f * d5 * d2;
    float rb[6];
    #pragma unroll
    for (int r = 0; r < 6; ++r) rb[r] = env * __sinf(sfreq[r] * d);
    float sph[4];
    sph[0] = 1.0f; sph[1] = a; sph[2] = 1.5f * a * a - 0.5f; sph[3] = 2.5f * a * a * a - 1.5f * a;
    __half out[24];
    #pragma unroll
    for (int s = 0; s < 4; ++s)
        #pragma unroll
        for (int r = 0; r < 6; ++r) out[s * 6 + r] = __float2half(sph[s] * rb[r]);
    uint4* dst = (uint4*)(basis + (size_t)t * 24);
    dst[0] = ((uint4*)out)[0];
    dst[1] = ((uint4*)out)[1];
    dst[2] = ((uint4*)out)[2];
}

// ---------------- SV for ALL 4 blocks in one pass ----------------
__global__ __launch_bounds__(256) void k_sv4(const int* __restrict__ rowptrT, const __half* __restrict__ basis,
                                             const float* __restrict__ iw_sbf1, float* __restrict__ SV4, int n) {
    int wave = threadIdx.x >> 6, lane = threadIdx.x & 63;
    int node = blockIdx.x * 8 + wave * 2 + (lane >> 5);
    int sub = lane & 31;
    int blk = sub >> 3, k = sub & 7;
    if (node >= n) return;
    const float* W1 = iw_sbf1 + blk * 192;
    f16x2 w[12];
    #pragma unroll
    for (int j = 0; j < 12; ++j) {
        f16x2 t;
        t.x = (_Float16)W1[(2 * j) * 8 + k];
        t.y = (_Float16)W1[(2 * j + 1) * 8 + k];
        w[j] = t;
    }
    float acc = 0.f;
    int p0 = rowptrT[node], p1 = rowptrT[node + 1];
    for (int p = p0; p < p1; ++p) {
        union { uint4 q[3]; f16x2 h[12]; } bs;
        const uint4* bp = (const uint4*)(basis + (size_t)p * 24);
        bs.q[0] = bp[0]; bs.q[1] = bp[1]; bs.q[2] = bp[2];
        float u = 0.f;
        #pragma unroll
        for (int j = 0; j < 12; ++j) u = fdot2f(bs.h[j], w[j], u);
        acc += siluf(u);
    }
    SV4[((size_t)blk * n + node) * 8 + k] = acc;
}

// ---------------- xh = bf16(atom_table[z]) ----------------
__global__ __launch_bounds__(256) void k_init_x(const float* __restrict__ atab, const int* __restrict__ z,
                                                unsigned short* __restrict__ xh, int n) {
    int t = blockIdx.x * 256 + threadIdx.x;
    if (t >= n * 16) return;
    int node = t >> 4, q = t & 15;
    const float4* a4 = (const float4*)atab;
    float4 v0 = a4[(size_t)z[node] * 32 + q * 2];
    float4 v1 = a4[(size_t)z[node] * 32 + q * 2 + 1];
    uint4 pk;
    pk.x = f2bf2(v0.x, v0.y);
    pk.y = f2bf2(v0.z, v0.w);
    pk.z = f2bf2(v1.x, v1.y);
    pk.w = f2bf2(v1.z, v1.w);
    ((uint4*)xh)[t] = pk;
}

// ---------------- SS[n] = sum_{e in n} silu(rbf_e @ w1 + b1) ----------------
__global__ __launch_bounds__(256) void k_embS(const int* __restrict__ rowptr, const float* __restrict__ rbfS,
                                              const float* __restrict__ w1, const float* __restrict__ b1,
                                              float* __restrict__ SS, int n) {
    int node = blockIdx.x * 4 + (threadIdx.x >> 6);
    int lane = threadIdx.x & 63;
    if (node >= n) return;
    int c = lane * 2;
    float wc0[6], wc1[6];
    #pragma unroll
    for (int r = 0; r < 6; ++r) { wc0[r] = w1[r * 128 + c]; wc1[r] = w1[r * 128 + c + 1]; }
    float bb0 = b1[c], bb1 = b1[c + 1];
    float a0 = 0.f, a1 = 0.f;
    int p0 = rowptr[node], p1 = rowptr[node + 1];
    for (int p = p0; p < p1; ++p) {
        const float2* r2 = (const float2*)&rbfS[(size_t)p * 6];
        float2 ra = r2[0], rbx = r2[1], rc = r2[2];
        float u0 = bb0 + ra.x * wc0[0] + ra.y * wc0[1] + rbx.x * wc0[2] + rbx.y * wc0[3] + rc.x * wc0[4] + rc.y * wc0[5];
        float u1 = bb1 + ra.x * wc1[0] + ra.y * wc1[1] + rbx.x * wc1[2] + rbx.y * wc1[3] + rc.x * wc1[4] + rc.y * wc1[5];
        a0 += siluf(u0);
        a1 += siluf(u1);
    }
    SS[node * 128 + c] = a0;
    SS[node * 128 + c + 1] = a1;
}

// ---------------- MFMA GEMM (embedding path) ----------------
template <int BIAS_MODE, bool SILU, bool ACCBF, bool ABF, bool WF32, bool WBF>
__global__ __launch_bounds__(256, 4) void k_gemm_mfma(const void* __restrict__ Ap,
                                                      const unsigned short* __restrict__ Wt,
                                                      const float* __restrict__ bias, const int* __restrict__ deg,
                                                      float* __restrict__ C, unsigned short* __restrict__ Ch, int M) {
    int tid = threadIdx.x;
    int wave = tid >> 6, lane = tid & 63;
    int m15 = lane & 15, quad = lane >> 4;
    int row0 = blockIdx.x * 64 + wave * 16;
    int arow = row0 + m15;
    if (arow > M - 1) arow = M - 1;

    f32x4 acc[8];
    #pragma unroll
    for (int nt = 0; nt < 8; ++nt) acc[nt] = (f32x4){0.f, 0.f, 0.f, 0.f};

    #pragma unroll
    for (int kt = 0; kt < 4; ++kt) {
        int ks = kt * 32 + quad * 8;
        bf16x8 av;
        if constexpr (ABF) {
            av = *(const bf16x8*)((const unsigned short*)Ap + (size_t)arow * 128 + ks);
        } else {
            const float* Arow = (const float*)Ap + (size_t)arow * 128;
            float4 a0 = *(const float4*)(Arow + ks);
            float4 a1 = *(const float4*)(Arow + ks + 4);
            union { bf16x8 v; unsigned int u[4]; } af;
            af.u[0] = f2bf2(a0.x, a0.y);
            af.u[1] = f2bf2(a0.z, a0.w);
            af.u[2] = f2bf2(a1.x, a1.y);
            af.u[3] = f2bf2(a1.z, a1.w);
            av = af.v;
        }
        #pragma unroll
        for (int nt = 0; nt < 8; ++nt) {
            bf16x8 bf = *(const bf16x8*)(Wt + (size_t)(nt * 16 + m15) * 128 + ks);
            acc[nt] = __builtin_amdgcn_mfma_f32_16x16x32_bf16(av, bf, acc[nt], 0, 0, 0);
        }
    }

    #pragma unroll
    for (int nt = 0; nt < 8; ++nt) {
        int col = nt * 16 + m15;
        float bc = 0.f;
        if constexpr (BIAS_MODE != 0) bc = bias[col];
        #pragma unroll
        for (int reg = 0; reg < 4; ++reg) {
            int row = row0 + quad * 4 + reg;
            if (row < M) {
                float v = acc[nt][reg];
                if constexpr (BIAS_MODE == 1) v += bc;
                if constexpr (BIAS_MODE == 2) v += bc * (float)deg[row];
                if constexpr (SILU) v = siluf(v);
                if constexpr (ACCBF) v += bf2f(Ch[(size_t)row * 128 + col]);
                if constexpr (WF32) C[(size_t)row * 128 + col] = v;
                if constexpr (WBF) Ch[(size_t)row * 128 + col] = f2bf(v);
            }
        }
    }
}

// ---------------- fused out-block MLP ----------------
template <int PACC>
__global__ __launch_bounds__(256, 4) void k_out_mlp(const unsigned short* __restrict__ hB,
                                                    const unsigned short* __restrict__ W0t, const float* __restrict__ b0,
                                                    const unsigned short* __restrict__ W1t, const float* __restrict__ b1,
                                                    const float* __restrict__ w2col, const float* __restrict__ ob2p,
                                                    float* __restrict__ Pout, int M) {
    __shared__ unsigned short lds[4][16 * 136];
    int tid = threadIdx.x;
    int wave = tid >> 6, lane = tid & 63;
    int m15 = lane & 15, quad = lane >> 4;
    int row0 = blockIdx.x * 64 + wave * 16;
    int arow = row0 + m15;
    if (arow > M - 1) arow = M - 1;
    unsigned short* L = lds[wave];

    f32x4 acc[8];
    #pragma unroll
    for (int nt = 0; nt < 8; ++nt) acc[nt] = (f32x4){0.f, 0.f, 0.f, 0.f};
    #pragma unroll
    for (int kt = 0; kt < 4; ++kt) {
        int ks = kt * 32 + quad * 8;
        bf16x8 av = *(const bf16x8*)(hB + (size_t)arow * 128 + ks);
        #pragma unroll
        for (int nt = 0; nt < 8; ++nt) {
            bf16x8 bf = *(const bf16x8*)(W0t + (size_t)(nt * 16 + m15) * 128 + ks);
            acc[nt] = __builtin_amdgcn_mfma_f32_16x16x32_bf16(av, bf, acc[nt], 0, 0, 0);
        }
    }
    #pragma unroll
    for (int nt = 0; nt < 8; ++nt) {
        int col = nt * 16 + m15;
        float bc = b0[col];
        #pragma unroll
        for (int reg = 0; reg < 4; ++reg)
            L[(quad * 4 + reg) * 136 + col] = f2bf(siluf(acc[nt][reg] + bc));
    }
    __syncthreads();

    #pragma unroll
    for (int nt = 0; nt < 8; ++nt) acc[nt] = (f32x4){0.f, 0.f, 0.f, 0.f};
    #pragma unroll
    for (int kt = 0; kt < 4; ++kt) {
        int ks = kt * 32 + quad * 8;
        bf16x8 av = *(const bf16x8*)(L + m15 * 136 + ks);
        #pragma unroll
        for (int nt = 0; nt < 8; ++nt) {
            bf16x8 bf = *(const bf16x8*)(W1t + (size_t)(nt * 16 + m15) * 128 + ks);
            acc[nt] = __builtin_amdgcn_mfma_f32_16x16x32_bf16(av, bf, acc[nt], 0, 0, 0);
        }
    }
    float w2c[8], pp[4];
    #pragma unroll
    for (int nt = 0; nt < 8; ++nt) w2c[nt] = w2col[nt * 16 + m15];
    #pragma unroll
    for (int reg = 0; reg < 4; ++reg) pp[reg] = 0.f;
    #pragma unroll
    for (int nt = 0; nt < 8; ++nt) {
        float bc = b1[nt * 16 + m15];
        #pragma unroll
        for (int reg = 0; reg < 4; ++reg)
            pp[reg] += siluf(acc[nt][reg] + bc) * w2c[nt];
    }
    #pragma unroll
    for (int reg = 0; reg < 4; ++reg) {
        float s = pp[reg];
        s += __shfl_xor(s, 1, 64);
        s += __shfl_xor(s, 2, 64);
        s += __shfl_xor(s, 4, 64);
        s += __shfl_xor(s, 8, 64);
        if (m15 == 0) {
            int row = row0 + quad * 4 + reg;
            if (row < M) {
                float r = s + ob2p[0];
                if constexpr (PACC == 2) r += Pout[row];
                Pout[row] = r;
            }
        }
    }
}

// ---------------- fused per-block MLP ----------------
__global__ __launch_bounds__(256, 4) void k_block_mlp(const unsigned short* __restrict__ xh,
                                                      const unsigned short* __restrict__ Wd, const float* __restrict__ bd,
                                                      const unsigned short* __restrict__ Wt1,
                                                      const unsigned short* __restrict__ Wt2, const float* __restrict__ bt2,
                                                      const unsigned short* __restrict__ Wup, const float* __restrict__ bup,
                                                      float* __restrict__ Tm, unsigned short* __restrict__ xuph, int M) {
    __shared__ unsigned short lds[4][16 * 136];
    int tid = threadIdx.x;
    int wave = tid >> 6, lane = tid & 63;
    int m15 = lane & 15, quad = lane >> 4;
    int row0 = blockIdx.x * 64 + wave * 16;
    int arow = row0 + m15;
    if (arow > M - 1) arow = M - 1;
    unsigned short* L = lds[wave];

    f32x4 accD[8], accU[8];
    #pragma unroll
    for (int nt = 0; nt < 8; ++nt) { accD[nt] = (f32x4){0.f, 0.f, 0.f, 0.f}; accU[nt] = (f32x4){0.f, 0.f, 0.f, 0.f}; }
    #pragma unroll
    for (int kt = 0; kt < 4; ++kt) {
        int ks = kt * 32 + quad * 8;
        bf16x8 av = *(const bf16x8*)(xh + (size_t)arow * 128 + ks);
        #pragma unroll
        for (int nt = 0; nt < 8; ++nt) {
            bf16x8 bd_ = *(const bf16x8*)(Wd + (size_t)(nt * 16 + m15) * 128 + ks);
            accD[nt] = __builtin_amdgcn_mfma_f32_16x16x32_bf16(av, bd_, accD[nt], 0, 0, 0);
            bf16x8 bu_ = *(const bf16x8*)(Wup + (size_t)(nt * 16 + m15) * 128 + ks);
            accU[nt] = __builtin_amdgcn_mfma_f32_16x16x32_bf16(av, bu_, accU[nt], 0, 0, 0);
        }
    }
    #pragma unroll
    for (int nt = 0; nt < 8; ++nt) {
        int col = nt * 16 + m15;
        float bcu = bup[col], bcd = bd[col];
        #pragma unroll
        for (int reg = 0; reg < 4; ++reg) {
            int row = row0 + quad * 4 + reg;
            if (row < M) xuph[(size_t)row * 128 + col] = f2bf(accU[nt][reg] + bcu);
            L[(quad * 4 + reg) * 136 + col] = f2bf(accD[nt][reg] + bcd);
        }
    }
    __syncthreads();

    #pragma unroll
    for (int nt = 0; nt < 8; ++nt) accD[nt] = (f32x4){0.f, 0.f, 0.f, 0.f};
    #pragma unroll
    for (int kt = 0; kt < 4; ++kt) {
        int ks = kt * 32 + quad * 8;
        bf16x8 av = *(const bf16x8*)(L + m15 * 136 + ks);
        #pragma unroll
        for (int nt = 0; nt < 8; ++nt) {
            bf16x8 bf = *(const bf16x8*)(Wt1 + (size_t)(nt * 16 + m15) * 128 + ks);
            accD[nt] = __builtin_amdgcn_mfma_f32_16x16x32_bf16(av, bf, accD[nt], 0, 0, 0);
        }
    }
    __syncthreads();
    #pragma unroll
    for (int nt = 0; nt < 8; ++nt) {
        int col = nt * 16 + m15;
        #pragma unroll
        for (int reg = 0; reg < 4; ++reg)
            L[(quad * 4 + reg) * 136 + col] = f2bf(siluf(accD[nt][reg]));
    }
    __syncthreads();

    #pragma unroll
    for (int nt = 0; nt < 8; ++nt) accD[nt] = (f32x4){0.f, 0.f, 0.f, 0.f};
    #pragma unroll
    for (int kt = 0; kt < 4; ++kt) {
        int ks = kt * 32 + quad * 8;
        bf16x8 av = *(const bf16x8*)(L + m15 * 136 + ks);
        #pragma unroll
        for (int nt = 0; nt < 8; ++nt) {
            bf16x8 bf = *(const bf16x8*)(Wt2 + (size_t)(nt * 16 + m15) * 128 + ks);
            accD[nt] = __builtin_amdgcn_mfma_f32_16x16x32_bf16(av, bf, accD[nt], 0, 0, 0);
        }
    }
    #pragma unroll
    for (int nt = 0; nt < 8; ++nt) {
        int col = nt * 16 + m15;
        float bc = bt2[col];
        #pragma unroll
        for (int reg = 0; reg < 4; ++reg) {
            int row = row0 + quad * 4 + reg;
            if (row < M) Tm[(size_t)row * 128 + col] = accD[nt][reg] + bc;
        }
    }
}

// ---------------- out_block gather -> bf16 h ----------------
__global__ __launch_bounds__(256) void k_out_gather(const int* __restrict__ rowptr, const int* __restrict__ slist,
                                                    const float* __restrict__ rbfS,
                                                    const unsigned short* __restrict__ xh,
                                                    const float* __restrict__ wrbf,
                                                    unsigned short* __restrict__ hB, int n) {
    int node = blockIdx.x * 4 + (threadIdx.x >> 6);
    int lane = threadIdx.x & 63;
    if (node >= n) return;
    int c = lane * 2;
    float wc0[6], wc1[6];
    #pragma unroll
    for (int r = 0; r < 6; ++r) { wc0[r] = wrbf[r * 128 + c]; wc1[r] = wrbf[r * 128 + c + 1]; }
    float a0 = 0.f, a1 = 0.f;
    int p0 = rowptr[node], p1 = rowptr[node + 1];
    int p = p0;
    for (; p + 4 <= p1; p += 4) {
        int s0 = slist[p], s1 = slist[p + 1], s2 = slist[p + 2], s3 = slist[p + 3];
        float2 rb[4][3];
        #pragma unroll
        for (int u = 0; u < 4; ++u) {
            const float2* r2 = (const float2*)&rbfS[(size_t)(p + u) * 6];
            rb[u][0] = r2[0]; rb[u][1] = r2[1]; rb[u][2] = r2[2];
        }
        unsigned int xv0 = *(const unsigned int*)&xh[(size_t)s0 * 128 + c];
        unsigned int xv1 = *(const unsigned int*)&xh[(size_t)s1 * 128 + c];
        unsigned int xv2 = *(const unsigned int*)&xh[(size_t)s2 * 128 + c];
        unsigned int xv3 = *(const unsigned int*)&xh[(size_t)s3 * 128 + c];
        #pragma unroll
        for (int u = 0; u < 4; ++u) {
            float e0 = rb[u][0].x * wc0[0] + rb[u][0].y * wc0[1] + rb[u][1].x * wc0[2] +
                       rb[u][1].y * wc0[3] + rb[u][2].x * wc0[4] + rb[u][2].y * wc0[5];
            float e1 = rb[u][0].x * wc1[0] + rb[u][0].y * wc1[1] + rb[u][1].x * wc1[2] +
                       rb[u][1].y * wc1[3] + rb[u][2].x * wc1[4] + rb[u][2].y * wc1[5];
            float2 xf = bf2x2((u == 0) ? xv0 : (u == 1) ? xv1 : (u == 2) ? xv2 : xv3);
            a0 += xf.x * e0;
            a1 += xf.y * e1;
        }
    }
    for (; p < p1; ++p) {
        int src = slist[p];
        const float2* r2 = (const float2*)&rbfS[(size_t)p * 6];
        float2 ra = r2[0], rbx = r2[1], rc = r2[2];
        float e0 = ra.x * wc0[0] + ra.y * wc0[1] + rbx.x * wc0[2] + rbx.y * wc0[3] + rc.x * wc0[4] + rc.y * wc0[5];
        float e1 = ra.x * wc1[0] + ra.y * wc1[1] + rbx.x * wc1[2] + rbx.y * wc1[3] + rc.x * wc1[4] + rc.y * wc1[5];
        float2 xf = bf2x2(*(const unsigned int*)&xh[(size_t)src * 128 + c]);
        a0 += xf.x * e0;
        a1 += xf.y * e1;
    }
    *(unsigned int*)&hB[(size_t)node * 128 + c] = f2bf2(a0, a1);
}

// ---------------- fused: extra[c] = sum_k W2[k][c] * (sum_n Tm[n][c]*SV[n][k]) ----------------
__global__ __launch_bounds__(256) void k_extra_fused(const float* __restrict__ Tm, const float* __restrict__ SV,
                                                     const float* __restrict__ W2, float* __restrict__ extra, int n) {
    int tid = threadIdx.x;
    int c = tid & 127, half = tid >> 7;
    float acc[8];
    #pragma unroll
    for (int k = 0; k < 8; ++k) acc[k] = 0.f;
    for (int nn = blockIdx.x * 2 + half; nn < n; nn += gridDim.x * 2) {
        const float4* sv4 = (const float4*)&SV[(size_t)nn * 8];
        float4 s0 = sv4[0], s1 = sv4[1];
        float t = Tm[(size_t)nn * 128 + c];
        acc[0] += t * s0.x; acc[1] += t * s0.y; acc[2] += t * s0.z; acc[3] += t * s0.w;
        acc[4] += t * s1.x; acc[5] += t * s1.y; acc[6] += t * s1.z; acc[7] += t * s1.w;
    }
    float e = 0.f;
    #pragma unroll
    for (int k = 0; k < 8; ++k) e += acc[k] * W2[k * 128 + c];
    __shared__ float red[256];
    red[tid] = e;
    __syncthreads();
    if (tid < 128) atomicAdd(&extra[c], red[tid] + red[tid + 128]);
}

// ---------------- interaction ----------------
__global__ __launch_bounds__(256) void k_interact(const int* __restrict__ rowptr, const int* __restrict__ slist,
                                                  const __half* __restrict__ s8, const float* __restrict__ W2,
                                                  const float* __restrict__ extra,
                                                  const unsigned short* __restrict__ xuph,
                                                  unsigned short* __restrict__ xh, int n) {
    int node = blockIdx.x * 4 + (threadIdx.x >> 6);
    int lane = threadIdx.x & 63;
    if (node >= n) return;
    int c = lane * 2;
    f16x2 w2a[4], w2b[4];
    #pragma unroll
    for (int j = 0; j < 4; ++j) {
        f16x2 wa, wb;
        wa.x = (_Float16)W2[(2 * j) * 128 + c];
        wa.y = (_Float16)W2[(2 * j + 1) * 128 + c];
        wb.x = (_Float16)W2[(2 * j) * 128 + c + 1];
        wb.y = (_Float16)W2[(2 * j + 1) * 128 + c + 1];
        w2a[j] = wa;
        w2b[j] = wb;
    }
    int p0 = rowptr[node], p1 = rowptr[node + 1];
    float cntf = (float)(p1 - p0);
    float a0 = cntf * extra[c], a1 = cntf * extra[c + 1];
    int p = p0;
    for (; p + 4 <= p1; p += 4) {
        int s0 = slist[p], s1 = slist[p + 1], s2 = slist[p + 2], s3 = slist[p + 3];
        uint4 sv[4];
        #pragma unroll
        for (int u = 0; u < 4; ++u) sv[u] = *(const uint4*)(s8 + (size_t)(p + u) * 8);
        unsigned int xv0 = *(const unsigned int*)&xuph[(size_t)s0 * 128 + c];
        unsigned int xv1 = *(const unsigned int*)&xuph[(size_t)s1 * 128 + c];
        unsigned int xv2 = *(const unsigned int*)&xuph[(size_t)s2 * 128 + c];
        unsigned int xv3 = *(const unsigned int*)&xuph[(size_t)s3 * 128 + c];
        #pragma unroll
        for (int u = 0; u < 4; ++u) {
            union { uint4 q; f16x2 h[4]; } s;
            s.q = sv[u];
            float e0 = fdot2f(s.h[0], w2a[0], 0.f);
            e0 = fdot2f(s.h[1], w2a[1], e0);
            e0 = fdot2f(s.h[2], w2a[2], e0);
            e0 = fdot2f(s.h[3], w2a[3], e0);
            float e1 = fdot2f(s.h[0], w2b[0], 0.f);
            e1 = fdot2f(s.h[1], w2b[1], e1);
            e1 = fdot2f(s.h[2], w2b[2], e1);
            e1 = fdot2f(s.h[3], w2b[3], e1);
            float2 xf = bf2x2((u == 0) ? xv0 : (u == 1) ? xv1 : (u == 2) ? xv2 : xv3);
            a0 += xf.x * e0;
            a1 += xf.y * e1;
        }
    }
    for (; p < p1; ++p) {
        int src = slist[p];
        float2 xf = bf2x2(*(const unsigned int*)&xuph[(size_t)src * 128 + c]);
        union { uint4 q; f16x2 h[4]; } s;
        s.q = *(const uint4*)(s8 + (size_t)p * 8);
        float e0 = fdot2f(s.h[0], w2a[0], 0.f);
        e0 = fdot2f(s.h[1], w2a[1], e0);
        e0 = fdot2f(s.h[2], w2a[2], e0);
        e0 = fdot2f(s.h[3], w2a[3], e0);
        float e1 = fdot2f(s.h[0], w2b[0], 0.f);
        e1 = fdot2f(s.h[1], w2b[1], e1);
        e1 = fdot2f(s.h[2], w2b[2], e1);
        e1 = fdot2f(s.h[3], w2b[3], e1);
        a0 += xf.x * e0;
        a1 += xf.y * e1;
    }
    unsigned int cur = *(unsigned int*)&xh[(size_t)node * 128 + c];
    float2 xc = bf2x2(cur);
    *(unsigned int*)&xh[(size_t)node * 128 + c] = f2bf2(xc.x + a0, xc.y + a1);
}

// ---------------- pooling ----------------
__global__ __launch_bounds__(256) void k_pool(const float* __restrict__ P, const int* __restrict__ batch,
                                              float* __restrict__ pool, float* __restrict__ cnt, int n) {
    int i = blockIdx.x * 256 + threadIdx.x;
    int lane = threadIdx.x & 63;
    int b = (i < n) ? batch[i] : -1;
    float p = (i < n) ? P[i] : 0.f;
    int b0 = __shfl(b, 0, 64);
    int b63 = __shfl(b, 63, 64);
    if (b0 == b63 && b0 >= 0) {
        float s = p;
        #pragma unroll
        for (int off = 32; off > 0; off >>= 1) s += __shfl_xor(s, off, 64);
        if (lane == 0) {
            atomicAdd(&pool[b0], s);
            atomicAdd(&cnt[b0], 64.0f);
        }
    } else {
        if (i < n) {
            atomicAdd(&pool[b], p);
            atomicAdd(&cnt[b], 1.0f);
        }
    }
}

__global__ __launch_bounds__(64) void k_final(const float* __restrict__ pool, const float* __restrict__ cnt,
                                              float* __restrict__ out) {
    int g = threadIdx.x;
    if (g < G_) out[g] = __fdividef(pool[g], fmaxf(cnt[g], 1.0f));
}

extern "C" void kernel_launch(void* const* d_in, const int* in_sizes, int n_in,
                              void* d_out, int out_size, void* d_ws, size_t ws_size,
                              hipStream_t stream) {
    (void)in_sizes; (void)n_in; (void)out_size; (void)ws_size;
    const int* z = (const int*)d_in[0];
    const float* dist = (const float*)d_in[1];
    const float* dist_trip = (const float*)d_in[2];
    const float* angle = (const float*)d_in[3];
    const int* edge_index = (const int*)d_in[4];
    const int* triplets = (const int*)d_in[5];
    const int* batch = (const int*)d_in[6];
    const float* atom_table = (const float*)d_in[7];
    const float* rbf_freq = (const float*)d_in[8];
    const float* sbf_freq = (const float*)d_in[9];
    const float* emb_w1 = (const float*)d_in[10];
    const float* emb_b1 = (const float*)d_in[11];
    const float* emb_w2 = (const float*)d_in[12];
    const float* emb_b2 = (const float*)d_in[13];
    const float* iw_rbf1 = (const float*)d_in[14];
    const float* iw_rbf2 = (const float*)d_in[15];
    const float* iw_sbf1 = (const float*)d_in[16];
    const float* iw_sbf2 = (const float*)d_in[17];
    const float* iw_t1 = (const float*)d_in[18];
    const float* iw_t2 = (const float*)d_in[19];
    const float* ib_t2 = (const float*)d_in[20];
    const float* iw_up = (const float*)d_in[21];
    const float* ib_up = (const float*)d_in[22];
    const float* iw_down = (const float*)d_in[23];
    const float* ib_down = (const float*)d_in[24];
    const float* ow_rbf = (const float*)d_in[25];
    const float* ow0 = (const float*)d_in[26];
    const float* ob0 = (const float*)d_in[27];
    const float* ow1 = (const float*)d_in[28];
    const float* ob1 = (const float*)d_in[29];
    const float* ow2 = (const float*)d_in[30];
    const float* ob2 = (const float*)d_in[31];

    const int* erow = edge_index;
    const int* ecol = edge_index + E_;

    // workspace layout
    float* ws = (float*)d_ws;
    float* bufA = ws;                          // N*128 (embS out; Tm)
    float* bufB = bufA + (size_t)N_ * H_;      // N*128 (hB bf16)
    float* P = bufB + (size_t)N_ * H_;         // N
    float* rbfS = P + N_;                      // E*6 (CSR order)
    float* SV4 = rbfS + (size_t)E_ * 6;        // 4*N*8
    float* extra4 = SV4 + (size_t)4 * N_ * 8;  // 4*128
    float* pool = extra4 + 512;                // G
    float* cnt = pool + G_;                    // G
    int* bcntE = (int*)(cnt + G_);             // NSB
    int* bcntT = bcntE + NSB;                  // NSB
    int* degE = bcntT + NSB;                   // N
    int* degT = degE + N_;                     // N
    int* rowptr = degT + N_;                   // N+1
    int* curE = rowptr + N_ + 1;               // N
    int* curT = curE + N_;                     // N
    int* slist = curT + N_;                    // E
    int* rowptrT = slist + E_;                 // N+1
    float* distS = (float*)(rowptrT + N_ + 1); // E
    // align to 8B for float2
    uintptr_t tp = (uintptr_t)(distS + E_);
    tp = (tp + 7) & ~(uintptr_t)7;
    float2* tpay = (float2*)tp;                // T float2
    __half* s8all = (__half*)(tpay + T_);      // 4*E*8 halves
    __half* basis = s8all + (size_t)4 * E_ * 8;                          // T*24 halves
    unsigned short* xh = (unsigned short*)(basis + (size_t)T_ * 24);     // N*128 bf16 node state
    unsigned short* xuph = xh + (size_t)N_ * H_;                          // N*128 bf16 x_up
    unsigned short* Wt = xuph + (size_t)N_ * H_;                          // 27*16384 bf16 weights
    unsigned short* hB = (unsigned short*)bufB;

    // bucket arrays alias s8all/basis region (written later by k_geom/k_basis)
    int2* ebktP = (int2*)s8all;                                 // NSB*CAPS int2  = 25.6MB
    unsigned char* ebktC = (unsigned char*)(ebktP + (size_t)NSB * CAPS);  // 3.2MB
    float2* tbktP = (float2*)(ebktC + (size_t)NSB * CAPS);      // 25.6MB
    unsigned char* tbktC = (unsigned char*)(tbktP + (size_t)NSB * CAPS);  // 3.2MB

    const int EG = (E_ + 255) / 256;
    const int TG = (T_ + 255) / 256;
    const int ETG = (E_ + T_ + 255) / 256;
    const int NG4 = (N_ + 3) / 4;
    const int GEMMG = (N_ + 63) / 64;

    // zero: extra4 + pool + cnt + bcntE + bcntT (contiguous)
    hipMemsetAsync(extra4, 0, (512 + 2 * G_ + 2 * NSB) * sizeof(float), stream);
    k_wprep<<<27 * 8, 256, 0, stream>>>(emb_w2, iw_down, iw_t1, iw_t2, iw_up, ow0, ow1, Wt);
    k_bucket<<<ETG, 256, 0, stream>>>(ecol, erow, dist, triplets, dist_trip, angle,
                                      bcntE, ebktP, ebktC, bcntT, tbktP, tbktC);
    k_cnt<<<2 * NBK, 256, 0, stream>>>(bcntE, ebktC, bcntT, tbktC, degE, degT);
    k_scan2<<<2, 1024, 0, stream>>>(degE, rowptr, curE, degT, rowptrT, curT, N_);
    k_place<<<2 * NBK, 256, 0, stream>>>(bcntE, ebktP, ebktC, curE, slist, distS,
                                         bcntT, tbktP, tbktC, curT, tpay);

    k_geom<<<EG, 256, 0, stream>>>(distS, rbf_freq, iw_rbf1, rbfS, s8all, E_);
    k_basis<<<TG, 256, 0, stream>>>(tpay, sbf_freq, basis, T_);
    k_sv4<<<(N_ + 7) / 8, 256, 0, stream>>>(rowptrT, basis, iw_sbf1, SV4, N_);
    k_init_x<<<(N_ * 16 + 255) / 256, 256, 0, stream>>>(atom_table, z, xh, N_);

    // embedding: xh = bf16( xh + SS @ w2 + deg*b2 )
    k_embS<<<NG4, 256, 0, stream>>>(rowptr, rbfS, emb_w1, emb_b1, bufA, N_);
    k_gemm_mfma<2, false, true, false, false, true><<<GEMMG, 256, 0, stream>>>(
        bufA, Wt, emb_b2, degE, nullptr, xh, N_);

    auto out_block = [&](int k, bool first) {
        k_out_gather<<<NG4, 256, 0, stream>>>(rowptr, slist, rbfS, xh,
                                              ow_rbf + (size_t)k * 6 * 128, hB, N_);
        if (first)
            k_out_mlp<1><<<GEMMG, 256, 0, stream>>>(hB, Wt + (size_t)(17 + k) * 16384, ob0 + k * 128,
                                                    Wt + (size_t)(22 + k) * 16384, ob1 + k * 128,
                                                    ow2 + k * 128, ob2 + k, P, N_);
        else
            k_out_mlp<2><<<GEMMG, 256, 0, stream>>>(hB, Wt + (size_t)(17 + k) * 16384, ob0 + k * 128,
                                                    Wt + (size_t)(22 + k) * 16384, ob1 + k * 128,
                                                    ow2 + k * 128, ob2 + k, P, N_);
    };

    out_block(0, true);

    for (int b = 0; b < 4; ++b) {
        k_block_mlp<<<GEMMG, 256, 0, stream>>>(xh,
                                               Wt + (size_t)(1 + b) * 16384, ib_down + b * 128,
                                               Wt + (size_t)(5 + b) * 16384,
                                               Wt + (size_t)(9 + b) * 16384, ib_t2 + b * 128,
                                               Wt + (size_t)(13 + b) * 16384, ib_up + b * 128,
                                               bufA, xuph, N_);
        k_extra_fused<<<256, 256, 0, stream>>>(bufA, SV4 + (size_t)b * N_ * 8,
                                               iw_sbf2 + (size_t)b * 1024, extra4 + b * 128, N_);
        k_interact<<<NG4, 256, 0, stream>>>(rowptr, slist, s8all + (size_t)b * E_ * 8,
                                            iw_rbf2 + (size_t)b * 1024, extra4 + b * 128,
                                            xuph, xh, N_);
        out_block(b + 1, false);
    }

    k_pool<<<(N_ + 255) / 256, 256, 0, stream>>>(P, batch, pool, cnt, N_);
    k_final<<<1, 64, 0, stream>>>(pool, cnt, (float*)d_out);
}